// Round 1
// baseline (8985.596 us; speedup 1.0000x reference)
//
#include <hip/hip_runtime.h>
#include <algorithm>

#define DT_F 0.02f
#define RADIUS_F 0.1125f           // 0.5 * 1.5 * 6 * 0.025
#define INV_R (1.0f / RADIUS_F)

__device__ __forceinline__ float sgnf(float v) {
    return (v > 0.f) ? 1.f : ((v < 0.f) ? -1.f : 0.f);
}

// Exact port of reference ball_to_cube (f32).
__device__ __forceinline__ void ball_to_cube_dev(float x, float y, float z,
                                                 float& ox, float& oy, float& oz) {
    const float eps = 1e-12f;
    float sq = x * x + y * y + z * z;
    float nrm = sqrtf(sq + eps);
    float xy2 = x * x + y * y;
    bool cap = 1.25f * z * z > xy2;
    float s_cap = sqrtf(3.f * nrm / (nrm + fabsf(z) + eps));
    float s_side = nrm / sqrtf(xy2 + eps);
    float s = cap ? s_cap : s_side;
    float xc = x * s, yc = y * s;
    float zc = cap ? sgnf(z) * nrm : 1.5f * z;
    if (!(sq > eps)) { xc = 0.f; yc = 0.f; zc = 0.f; }
    float rxy = sqrtf(xc * xc + yc * yc + eps);
    bool xbig = fabsf(yc) <= fabsf(xc);
    float dx = (fabsf(xc) > eps) ? xc : 1.f;
    float dy = (fabsf(yc) > eps) ? yc : 1.f;
    const float c4pi = 1.27323954473516276f;  // 4/pi
    float tx = sgnf(xc) * rxy, ty = sgnf(yc) * rxy;
    float xq = xbig ? tx : ty * c4pi * atanf(xc / dy);
    float yq = xbig ? tx * c4pi * atanf(yc / dx) : ty;
    if (!(xc * xc + yc * yc > eps)) { xq = 0.f; yq = 0.f; }
    ox = xq; oy = yq; oz = zc;
}

// pos2 = pos + dt*(vel2+vel)/2 ; fl = [1, vel2]
__global__ void prep_kernel(const float* __restrict__ pos, const float* __restrict__ vel,
                            int n, float* __restrict__ pos2, float* __restrict__ fl) {
    int i = blockIdx.x * blockDim.x + threadIdx.x;
    if (i >= n) return;
    float v0 = vel[i * 3 + 0], v1 = vel[i * 3 + 1], v2 = vel[i * 3 + 2];
    float u0 = v0, u1 = v1 + DT_F * (-9.81f), u2 = v2;
    pos2[i * 3 + 0] = pos[i * 3 + 0] + DT_F * (u0 + v0) * 0.5f;
    pos2[i * 3 + 1] = pos[i * 3 + 1] + DT_F * (u1 + v1) * 0.5f;
    pos2[i * 3 + 2] = pos[i * 3 + 2] + DT_F * (u2 + v2) * 0.5f;
    fl[i * 4 + 0] = 1.f;
    fl[i * 4 + 1] = u0;
    fl[i * 4 + 2] = u1;
    fl[i * 4 + 3] = u2;
}

// row_ptr[q] = lower_bound(q_idx, q). Edge lists are sorted by query (np.nonzero order).
__global__ void row_ptr_kernel(const int* __restrict__ q_idx, int E, int nq,
                               int* __restrict__ row_ptr) {
    int q = blockIdx.x * blockDim.x + threadIdx.x;
    if (q > nq) return;
    int lo = 0, hi = E;
    while (lo < hi) {
        int mid = (lo + hi) >> 1;
        if (q_idx[mid] < q) lo = mid + 1; else hi = mid;
    }
    row_ptr[q] = lo;
}

// a_df = fl @ w_d0 + b_d0 -> x96[:, 64:96]
__global__ void dense0_kernel(const float* __restrict__ fl, const float* __restrict__ w,
                              const float* __restrict__ b, int n, float* __restrict__ x96) {
    int i = blockIdx.x * blockDim.x + threadIdx.x;
    if (i >= n * 32) return;
    int q = i >> 5, o = i & 31;
    float acc = b[o];
#pragma unroll
    for (int c = 0; c < 4; c++) acc += fl[q * 4 + c] * w[c * 32 + o];
    x96[(size_t)q * 96 + 64 + o] = acc;
}

__global__ void relu_kernel(const float* __restrict__ x, int n, float* __restrict__ h) {
    int i = blockIdx.x * blockDim.x + threadIdx.x;
    if (i < n) h[i] = fmaxf(x[i], 0.f);
}

// One block per query: gather edges, build G[64][cin] in LDS, store to global.
// G layout per query: [slots][cin], slots = 64 (+1 when the dense term is folded: slot 64 = featq[q]).
__global__ void build_G_kernel(const float* __restrict__ feat, int cin, int slots,
                               const float* __restrict__ posq, const float* __restrict__ poss,
                               const int* __restrict__ s_idx, const int* __restrict__ row_ptr,
                               const float* __restrict__ featq, int q0,
                               float* __restrict__ G) {
    extern __shared__ float Gs[];
    int lq = blockIdx.x;
    int q = q0 + lq;
    int t = threadIdx.x;
    int tot = 64 * cin;
    for (int i = t; i < tot; i += blockDim.x) Gs[i] = 0.f;
    __syncthreads();

    float qx = posq[q * 3 + 0], qy = posq[q * 3 + 1], qz = posq[q * 3 + 2];
    int e0 = row_ptr[q], e1 = row_ptr[q + 1];
    for (int e = e0; e < e1; e++) {
        int s = s_idx[e];
        float dx = (poss[s * 3 + 0] - qx) * INV_R;
        float dy = (poss[s * 3 + 1] - qy) * INV_R;
        float dz = (poss[s * 3 + 2] - qz) * INV_R;
        float r2 = dx * dx + dy * dy + dz * dz;
        float w1 = 1.f - r2;
        float win = w1 * w1 * w1;
        win = fminf(fmaxf(win, 0.f), 1.f);
        float gx, gy, gz;
        ball_to_cube_dev(dx, dy, dz, gx, gy, gz);
        gx = (gx + 1.f) * 1.5f;
        gy = (gy + 1.f) * 1.5f;
        gz = (gz + 1.f) * 1.5f;
        float fx0 = floorf(gx), fy0 = floorf(gy), fz0 = floorf(gz);
        float fx = gx - fx0, fy = gy - fy0, fz = gz - fz0;
        int ix = (int)fx0, iy = (int)fy0, iz = (int)fz0;
        int cell[8];
        float wc[8];
#pragma unroll
        for (int c = 0; c < 8; c++) {
            int bx = (c >> 2) & 1, by = (c >> 1) & 1, bz = c & 1;
            int jx = min(max(ix + bx, 0), 3);
            int jy = min(max(iy + by, 0), 3);
            int jz = min(max(iz + bz, 0), 3);
            cell[c] = (jx * 4 + jy) * 4 + jz;
            wc[c] = (bx ? fx : 1.f - fx) * (by ? fy : 1.f - fy) * (bz ? fz : 1.f - fz);
        }
        if (t < cin) {
            float fv = feat[(size_t)s * cin + t] * win;
#pragma unroll
            for (int c = 0; c < 8; c++) Gs[cell[c] * cin + t] += wc[c] * fv;
        }
    }
    __syncthreads();
    size_t base = (size_t)lq * slots * cin;
    for (int i = t; i < tot; i += blockDim.x) G[base + i] = Gs[i];
    if (slots > 64) {
        for (int i = t; i < cin; i += blockDim.x) G[base + tot + i] = featq[(size_t)q * cin + i];
    }
}

// C[m, coff+n] = sum_k A[m,k]*B[k,n] (+bias[n]) (+resid[m,coff+n]); A row-major lda=K, B row-major ldb=N.
template <int BM, int BN, int BK, int TM, int TN>
__global__ void gemm_kernel(const float* __restrict__ A, const float* __restrict__ B,
                            float* __restrict__ C, const float* __restrict__ bias,
                            const float* __restrict__ resid,
                            int M, int N, int K, int ldc, int coff) {
    constexpr int THREADS = (BM / TM) * (BN / TN);
    __shared__ float As[BK][BM + 1];
    __shared__ float Bs[BK][BN + 1];
    int tx = threadIdx.x;
    int tcols = BN / TN;
    int tcol = tx % tcols, trow = tx / tcols;
    int m0 = blockIdx.x * BM;
    float acc[TM][TN];
#pragma unroll
    for (int i = 0; i < TM; i++)
#pragma unroll
        for (int j = 0; j < TN; j++) acc[i][j] = 0.f;

    for (int k0 = 0; k0 < K; k0 += BK) {
        for (int i = tx; i < BM * BK; i += THREADS) {
            int kk = i % BK, mm = i / BK;
            int m = m0 + mm, k = k0 + kk;
            As[kk][mm] = (m < M && k < K) ? A[(size_t)m * K + k] : 0.f;
        }
        for (int i = tx; i < BN * BK; i += THREADS) {
            int nn = i % BN, kk = i / BN;
            int k = k0 + kk;
            Bs[kk][nn] = (k < K && nn < N) ? B[(size_t)k * N + nn] : 0.f;
        }
        __syncthreads();
#pragma unroll
        for (int kk = 0; kk < BK; kk++) {
            float a[TM], b[TN];
#pragma unroll
            for (int i = 0; i < TM; i++) a[i] = As[kk][trow * TM + i];
#pragma unroll
            for (int j = 0; j < TN; j++) b[j] = Bs[kk][tcol * TN + j];
#pragma unroll
            for (int i = 0; i < TM; i++)
#pragma unroll
                for (int j = 0; j < TN; j++) acc[i][j] += a[i] * b[j];
        }
        __syncthreads();
    }
    for (int i = 0; i < TM; i++) {
        int m = m0 + trow * TM + i;
        if (m >= M) continue;
        for (int j = 0; j < TN; j++) {
            int nn = tcol * TN + j;
            if (nn >= N) continue;
            float v = acc[i][j];
            if (bias) v += bias[nn];
            if (resid) v += resid[(size_t)m * ldc + coff + nn];
            C[(size_t)m * ldc + coff + nn] = v;
        }
    }
}

// Layer-3 GEMM: N=3. One block (256 thr) per row, block-reduce 3 outputs.
__global__ void rowdot3_kernel(const float* __restrict__ A, const float* __restrict__ B,
                               const float* __restrict__ bias, int K, float* __restrict__ C) {
    int m = blockIdx.x;
    int t = threadIdx.x;
    const float* a = A + (size_t)m * K;
    float a0 = 0.f, a1 = 0.f, a2 = 0.f;
    for (int k = t; k < K; k += 256) {
        float av = a[k];
        a0 += av * B[k * 3 + 0];
        a1 += av * B[k * 3 + 1];
        a2 += av * B[k * 3 + 2];
    }
    __shared__ float red[3][256];
    red[0][t] = a0; red[1][t] = a1; red[2][t] = a2;
    __syncthreads();
    for (int s2 = 128; s2 > 0; s2 >>= 1) {
        if (t < s2) {
            red[0][t] += red[0][t + s2];
            red[1][t] += red[1][t + s2];
            red[2][t] += red[2][t + s2];
        }
        __syncthreads();
    }
    if (t < 3) C[(size_t)m * 3 + t] = red[t][0] + bias[t];
}

// pos_new = pos2 + y3/128 ; vel_new = (pos_new - pos)/dt
__global__ void final_kernel(const float* __restrict__ pos, const float* __restrict__ pos2,
                             const float* __restrict__ y3, int n, float* __restrict__ out) {
    int i = blockIdx.x * blockDim.x + threadIdx.x;
    if (i >= n * 3) return;
    float pn = pos2[i] + y3[i] * (1.f / 128.f);
    out[i] = pn;
    out[n * 3 + i] = (pn - pos[i]) * (1.f / DT_F);
}

static inline int cdiv(int a, int b) { return (a + b - 1) / b; }

extern "C" void kernel_launch(void* const* d_in, const int* in_sizes, int n_in,
                              void* d_out, int out_size, void* d_ws, size_t ws_size,
                              hipStream_t stream) {
    const float* pos       = (const float*)d_in[0];
    const float* vel       = (const float*)d_in[1];
    const float* box       = (const float*)d_in[2];
    const float* box_feats = (const float*)d_in[3];
    const int*   ff_q      = (const int*)d_in[4];
    const int*   ff_s      = (const int*)d_in[5];
    const int*   fo_q      = (const int*)d_in[6];
    const int*   fo_s      = (const int*)d_in[7];
    const float* w_cf0     = (const float*)d_in[8];
    const float* w_co0     = (const float*)d_in[9];
    const float* w_d0      = (const float*)d_in[10];
    const float* b_d0      = (const float*)d_in[11];
    const float* w_c1      = (const float*)d_in[12];
    const float* w_d1      = (const float*)d_in[13];
    const float* b_d1      = (const float*)d_in[14];
    const float* w_c2      = (const float*)d_in[15];
    const float* w_d2      = (const float*)d_in[16];
    const float* b_d2      = (const float*)d_in[17];
    const float* w_c3      = (const float*)d_in[18];
    const float* w_d3      = (const float*)d_in[19];
    const float* b_d3      = (const float*)d_in[20];
    float* out = (float*)d_out;

    int n   = in_sizes[0] / 3;
    int Eff = in_sizes[4];
    int Efo = in_sizes[6];

    float* base = (float*)d_ws;
    size_t off = 0;
    auto alloc = [&](size_t nf) { float* p = base + off; off += (nf + 3) & ~(size_t)3; return p; };
    float* pos2 = alloc((size_t)n * 3);
    float* fl   = alloc((size_t)n * 4);
    float* x96  = alloc((size_t)n * 96);
    float* hbuf = alloc((size_t)n * 96);
    float* x64a = alloc((size_t)n * 64);
    float* x64b = alloc((size_t)n * 64);
    float* y3   = alloc((size_t)n * 3);
    int* rp_ff  = (int*)alloc((size_t)n + 1);
    int* rp_fo  = (int*)alloc((size_t)n + 1);
    float* Wc   = alloc((size_t)65 * 96 * 64);
    float* G    = base + off;

    size_t totalFloats = ws_size / sizeof(float);
    long avail = (long)totalFloats - (long)off;
    if (avail < 65 * 96) avail = 65 * 96;  // best effort
    int Q = (int)std::max<long>(1L, std::min<long>((long)n, avail / (65 * 96)));

    // --- prep + CSR ---
    prep_kernel<<<cdiv(n, 256), 256, 0, stream>>>(pos, vel, n, pos2, fl);
    row_ptr_kernel<<<cdiv(n + 1, 256), 256, 0, stream>>>(ff_q, Eff, n, rp_ff);
    row_ptr_kernel<<<cdiv(n + 1, 256), 256, 0, stream>>>(fo_q, Efo, n, rp_fo);
    dense0_kernel<<<cdiv(n * 32, 256), 256, 0, stream>>>(fl, w_d0, b_d0, n, x96);

    // --- layer 0: a_co -> x96[:,0:32], a_cf -> x96[:,32:64] ---
    for (int q0 = 0; q0 < n; q0 += Q) {
        int mc = std::min(Q, n - q0);
        build_G_kernel<<<mc, 128, 64 * 4 * sizeof(float), stream>>>(
            fl, 4, 64, pos2, pos2, ff_s, rp_ff, nullptr, q0, G);
        gemm_kernel<64, 32, 16, 4, 2><<<cdiv(mc, 64), 256, 0, stream>>>(
            G, w_cf0, x96 + (size_t)q0 * 96, nullptr, nullptr, mc, 32, 64 * 4, 96, 32);
        build_G_kernel<<<mc, 128, 64 * 3 * sizeof(float), stream>>>(
            box_feats, 3, 64, pos2, box, fo_s, rp_fo, nullptr, q0, G);
        gemm_kernel<64, 32, 16, 4, 2><<<cdiv(mc, 64), 256, 0, stream>>>(
            G, w_co0, x96 + (size_t)q0 * 96, nullptr, nullptr, mc, 32, 64 * 3, 96, 0);
    }

    // --- layer 1: 96 -> 64, no residual ---
    relu_kernel<<<cdiv(n * 96, 256), 256, 0, stream>>>(x96, n * 96, hbuf);
    hipMemcpyAsync(Wc, w_c1, sizeof(float) * 64 * 96 * 64, hipMemcpyDeviceToDevice, stream);
    hipMemcpyAsync(Wc + 64 * 96 * 64, w_d1, sizeof(float) * 96 * 64, hipMemcpyDeviceToDevice, stream);
    for (int q0 = 0; q0 < n; q0 += Q) {
        int mc = std::min(Q, n - q0);
        build_G_kernel<<<mc, 128, 64 * 96 * sizeof(float), stream>>>(
            hbuf, 96, 65, pos2, pos2, ff_s, rp_ff, hbuf, q0, G);
        gemm_kernel<64, 64, 16, 4, 4><<<cdiv(mc, 64), 256, 0, stream>>>(
            G, Wc, x64a + (size_t)q0 * 64, b_d1, nullptr, mc, 64, 65 * 96, 64, 0);
    }

    // --- layer 2: 64 -> 64, residual ---
    relu_kernel<<<cdiv(n * 64, 256), 256, 0, stream>>>(x64a, n * 64, hbuf);
    hipMemcpyAsync(Wc, w_c2, sizeof(float) * 64 * 64 * 64, hipMemcpyDeviceToDevice, stream);
    hipMemcpyAsync(Wc + 64 * 64 * 64, w_d2, sizeof(float) * 64 * 64, hipMemcpyDeviceToDevice, stream);
    for (int q0 = 0; q0 < n; q0 += Q) {
        int mc = std::min(Q, n - q0);
        build_G_kernel<<<mc, 128, 64 * 64 * sizeof(float), stream>>>(
            hbuf, 64, 65, pos2, pos2, ff_s, rp_ff, hbuf, q0, G);
        gemm_kernel<64, 64, 16, 4, 4><<<cdiv(mc, 64), 256, 0, stream>>>(
            G, Wc, x64b + (size_t)q0 * 64, b_d2, x64a + (size_t)q0 * 64, mc, 64, 65 * 64, 64, 0);
    }

    // --- layer 3: 64 -> 3, no residual ---
    relu_kernel<<<cdiv(n * 64, 256), 256, 0, stream>>>(x64b, n * 64, hbuf);
    hipMemcpyAsync(Wc, w_c3, sizeof(float) * 64 * 64 * 3, hipMemcpyDeviceToDevice, stream);
    hipMemcpyAsync(Wc + 64 * 64 * 3, w_d3, sizeof(float) * 64 * 3, hipMemcpyDeviceToDevice, stream);
    for (int q0 = 0; q0 < n; q0 += Q) {
        int mc = std::min(Q, n - q0);
        build_G_kernel<<<mc, 128, 64 * 64 * sizeof(float), stream>>>(
            hbuf, 64, 65, pos2, pos2, ff_s, rp_ff, hbuf, q0, G);
        rowdot3_kernel<<<mc, 256, 0, stream>>>(G, Wc, b_d3, 65 * 64, y3 + (size_t)q0 * 3);
    }

    final_kernel<<<cdiv(n * 3, 256), 256, 0, stream>>>(pos, pos2, y3, n, out);
}

// Round 2
// 2810.327 us; speedup vs baseline: 3.1973x; 3.1973x over previous
//
#include <hip/hip_runtime.h>
#include <algorithm>

#define DT_F 0.02f
#define INV_R (1.0f / 0.1125f)

static inline int cdiv(int a, int b) { return (a + b - 1) / b; }

__device__ __forceinline__ float sgnf(float v) {
    return (v > 0.f) ? 1.f : ((v < 0.f) ? -1.f : 0.f);
}

// Exact port of reference ball_to_cube (f32).
__device__ __forceinline__ void ball_to_cube_dev(float x, float y, float z,
                                                 float& ox, float& oy, float& oz) {
    const float eps = 1e-12f;
    float sq = x * x + y * y + z * z;
    float nrm = sqrtf(sq + eps);
    float xy2 = x * x + y * y;
    bool cap = 1.25f * z * z > xy2;
    float s_cap = sqrtf(3.f * nrm / (nrm + fabsf(z) + eps));
    float s_side = nrm / sqrtf(xy2 + eps);
    float s = cap ? s_cap : s_side;
    float xc = x * s, yc = y * s;
    float zc = cap ? sgnf(z) * nrm : 1.5f * z;
    if (!(sq > eps)) { xc = 0.f; yc = 0.f; zc = 0.f; }
    float rxy = sqrtf(xc * xc + yc * yc + eps);
    bool xbig = fabsf(yc) <= fabsf(xc);
    float dx = (fabsf(xc) > eps) ? xc : 1.f;
    float dy = (fabsf(yc) > eps) ? yc : 1.f;
    const float c4pi = 1.27323954473516276f;  // 4/pi
    float tx = sgnf(xc) * rxy, ty = sgnf(yc) * rxy;
    float xq = xbig ? tx : ty * c4pi * atanf(xc / dy);
    float yq = xbig ? tx * c4pi * atanf(yc / dx) : ty;
    if (!(xc * xc + yc * yc > eps)) { xq = 0.f; yq = 0.f; }
    ox = xq; oy = yq; oz = zc;
}

// pos2 = pos + dt*(vel2+vel)/2 ; fl = [1, vel2]
__global__ void prep_kernel(const float* __restrict__ pos, const float* __restrict__ vel,
                            int n, float* __restrict__ pos2, float* __restrict__ fl) {
    int i = blockIdx.x * blockDim.x + threadIdx.x;
    if (i >= n) return;
    float v0 = vel[i * 3 + 0], v1 = vel[i * 3 + 1], v2 = vel[i * 3 + 2];
    float u0 = v0, u1 = v1 + DT_F * (-9.81f), u2 = v2;
    pos2[i * 3 + 0] = pos[i * 3 + 0] + DT_F * (u0 + v0) * 0.5f;
    pos2[i * 3 + 1] = pos[i * 3 + 1] + DT_F * (u1 + v1) * 0.5f;
    pos2[i * 3 + 2] = pos[i * 3 + 2] + DT_F * (u2 + v2) * 0.5f;
    fl[i * 4 + 0] = 1.f;
    fl[i * 4 + 1] = u0;
    fl[i * 4 + 2] = u1;
    fl[i * 4 + 3] = u2;
}

// row_ptr[q] = lower_bound(q_idx, q). Edge lists are sorted by query.
__global__ void row_ptr_kernel(const int* __restrict__ q_idx, int E, int nq,
                               int* __restrict__ row_ptr) {
    int q = blockIdx.x * blockDim.x + threadIdx.x;
    if (q > nq) return;
    int lo = 0, hi = E;
    while (lo < hi) {
        int mid = (lo + hi) >> 1;
        if (q_idx[mid] < q) lo = mid + 1; else hi = mid;
    }
    row_ptr[q] = lo;
}

// Per-edge geometry, computed ONCE. wgt[e*8+c] = win * trilinear(c); cells packed 8x u8.
// ix clamped to [0,2] with f recomputed => 8 corners always distinct (no scatter aliasing).
__global__ void edge_geom_kernel(const float* __restrict__ posq, const float* __restrict__ poss,
                                 const int* __restrict__ q_idx, const int* __restrict__ s_idx,
                                 int E, float* __restrict__ wgt, uint2* __restrict__ cells) {
    int e = blockIdx.x * blockDim.x + threadIdx.x;
    if (e >= E) return;
    int q = q_idx[e], s = s_idx[e];
    float dx = (poss[s * 3 + 0] - posq[q * 3 + 0]) * INV_R;
    float dy = (poss[s * 3 + 1] - posq[q * 3 + 1]) * INV_R;
    float dz = (poss[s * 3 + 2] - posq[q * 3 + 2]) * INV_R;
    float r2 = dx * dx + dy * dy + dz * dz;
    float w1 = 1.f - r2;
    float win = fminf(fmaxf(w1 * w1 * w1, 0.f), 1.f);
    float bx, by, bz;
    ball_to_cube_dev(dx, dy, dz, bx, by, bz);
    float gx = (bx + 1.f) * 1.5f, gy = (by + 1.f) * 1.5f, gz = (bz + 1.f) * 1.5f;
    int ix = min(max((int)floorf(gx), 0), 2);
    int iy = min(max((int)floorf(gy), 0), 2);
    int iz = min(max((int)floorf(gz), 0), 2);
    float fx = gx - (float)ix, fy = gy - (float)iy, fz = gz - (float)iz;
    float wv[8];
    unsigned int cl[8];
#pragma unroll
    for (int c = 0; c < 8; c++) {
        int cbx = (c >> 2) & 1, cby = (c >> 1) & 1, cbz = c & 1;
        int jx = ix + cbx, jy = iy + cby, jz = iz + cbz;
        cl[c] = (unsigned int)((jx * 4 + jy) * 4 + jz);
        wv[c] = win * (cbx ? fx : 1.f - fx) * (cby ? fy : 1.f - fy) * (cbz ? fz : 1.f - fz);
    }
    float4* wp = (float4*)(wgt + (size_t)e * 8);
    wp[0] = make_float4(wv[0], wv[1], wv[2], wv[3]);
    wp[1] = make_float4(wv[4], wv[5], wv[6], wv[7]);
    uint2 cp;
    cp.x = cl[0] | (cl[1] << 8) | (cl[2] << 16) | (cl[3] << 24);
    cp.y = cl[4] | (cl[5] << 8) | (cl[6] << 16) | (cl[7] << 24);
    cells[e] = cp;
}

// a_df = fl @ w_d0 + b_d0 -> x96[:, 64:96]
__global__ void dense0_kernel(const float* __restrict__ fl, const float* __restrict__ w,
                              const float* __restrict__ b, int n, float* __restrict__ x96) {
    int i = blockIdx.x * blockDim.x + threadIdx.x;
    if (i >= n * 32) return;
    int q = i >> 5, o = i & 31;
    float acc = b[o];
#pragma unroll
    for (int c = 0; c < 4; c++) acc += fl[q * 4 + c] * w[c * 32 + o];
    x96[(size_t)q * 96 + 64 + o] = acc;
}

__global__ void relu_kernel(const float* __restrict__ x, int n, float* __restrict__ h) {
    int i = blockIdx.x * blockDim.x + threadIdx.x;
    if (i < n) h[i] = fmaxf(x[i], 0.f);
}

// C[q, o] = bias[o] (+resid[q,o]); zero if bias null. Used before atomic split-K GEMM.
__global__ void init_out_kernel(float* __restrict__ C, const float* __restrict__ bias,
                                const float* __restrict__ resid, int n, int co, int ldc) {
    int i = blockIdx.x * blockDim.x + threadIdx.x;
    if (i >= n * co) return;
    int q = i / co, o = i - q * co;
    float v = bias ? bias[o] : 0.f;
    if (resid) v += resid[(size_t)q * ldc + o];
    C[(size_t)q * ldc + o] = v;
}

// Small-cin (layer 0) G build: 1 wave/query, 8 corner-replicas in LDS (no per-corner serialization).
// lane = (corner r)*8 + ch. G out: [Q][64][cin].
__global__ __launch_bounds__(64) void build_G_small(
    const float* __restrict__ feat, int cin,
    const float* __restrict__ wgt, const uint2* __restrict__ cells,
    const int* __restrict__ s_idx, const int* __restrict__ row_ptr, int q0,
    float* __restrict__ G) {
    __shared__ float Gs[8 * 64 * 8];  // [replica r][cell][8ch] = 16 KB
    int lq = blockIdx.x, q = q0 + lq, t = threadIdx.x;
    int r = t >> 3, ch = t & 7;
    for (int i = t; i < 4096; i += 64) Gs[i] = 0.f;
    __syncthreads();
    int e0 = row_ptr[q], e1 = row_ptr[q + 1];
    for (int e = e0; e < e1; e++) {
        int s = s_idx[e];
        float w = wgt[(size_t)e * 8 + r];
        uint2 cp = cells[e];
        unsigned int word = (r < 4) ? cp.x : cp.y;
        int cell = (int)((word >> ((r & 3) * 8)) & 255u);
        float fv = (ch < cin) ? feat[(size_t)s * cin + ch] : 0.f;
        Gs[(r * 64 + cell) * 8 + ch] += w * fv;
    }
    __syncthreads();
    size_t base = (size_t)lq * 64 * cin;
    for (int i = t; i < 64 * cin; i += 64) {
        int cell = i / cin, c = i - cell * cin;
        float acc = 0.f;
#pragma unroll
        for (int rr = 0; rr < 8; rr++) acc += Gs[(rr * 64 + cell) * 8 + c];
        G[base + i] = acc;
    }
}

// Big-cin G build: 1 wave/query, lane = channel-pair (float2). 8 distinct corners =>
// grouped 8 LDS reads -> 8 FMAs -> 8 LDS writes per edge (no RMW aliasing).
// G out: [Q][65][cin]; slot 64 = featq[q] (folds dense layer into the GEMM).
__global__ __launch_bounds__(64) void build_G_big(
    const float* __restrict__ feat, int pairs,  // pairs = cin/2
    const float* __restrict__ wgt, const uint2* __restrict__ cells,
    const int* __restrict__ s_idx, const int* __restrict__ row_ptr,
    const float* __restrict__ featq, int q0, float* __restrict__ G) {
    extern __shared__ float2 Gs[];  // [64][pairs]
    int lq = blockIdx.x, q = q0 + lq, t = threadIdx.x;
    int cin = pairs * 2;
    for (int i = t; i < 64 * pairs; i += 64) Gs[i] = make_float2(0.f, 0.f);
    __syncthreads();
    const float2* feat2 = (const float2*)feat;
    bool act = t < pairs;
    int e0 = row_ptr[q], e1 = row_ptr[q + 1];
    for (int e = e0; e < e1; e++) {
        int s = s_idx[e];
        const float4* wp = (const float4*)(wgt + (size_t)e * 8);
        float4 wa = wp[0], wb = wp[1];
        uint2 cp = cells[e];
        if (act) {
            float2 fv = feat2[(size_t)s * pairs + t];
            int c0 = (int)(cp.x & 255u), c1 = (int)((cp.x >> 8) & 255u);
            int c2 = (int)((cp.x >> 16) & 255u), c3 = (int)((cp.x >> 24) & 255u);
            int c4 = (int)(cp.y & 255u), c5 = (int)((cp.y >> 8) & 255u);
            int c6 = (int)((cp.y >> 16) & 255u), c7 = (int)((cp.y >> 24) & 255u);
            float2 g0 = Gs[c0 * pairs + t], g1 = Gs[c1 * pairs + t];
            float2 g2 = Gs[c2 * pairs + t], g3 = Gs[c3 * pairs + t];
            float2 g4 = Gs[c4 * pairs + t], g5 = Gs[c5 * pairs + t];
            float2 g6 = Gs[c6 * pairs + t], g7 = Gs[c7 * pairs + t];
            g0.x += wa.x * fv.x; g0.y += wa.x * fv.y;
            g1.x += wa.y * fv.x; g1.y += wa.y * fv.y;
            g2.x += wa.z * fv.x; g2.y += wa.z * fv.y;
            g3.x += wa.w * fv.x; g3.y += wa.w * fv.y;
            g4.x += wb.x * fv.x; g4.y += wb.x * fv.y;
            g5.x += wb.y * fv.x; g5.y += wb.y * fv.y;
            g6.x += wb.z * fv.x; g6.y += wb.z * fv.y;
            g7.x += wb.w * fv.x; g7.y += wb.w * fv.y;
            Gs[c0 * pairs + t] = g0; Gs[c1 * pairs + t] = g1;
            Gs[c2 * pairs + t] = g2; Gs[c3 * pairs + t] = g3;
            Gs[c4 * pairs + t] = g4; Gs[c5 * pairs + t] = g5;
            Gs[c6 * pairs + t] = g6; Gs[c7 * pairs + t] = g7;
        }
    }
    __syncthreads();
    size_t base = (size_t)lq * (size_t)(65 * cin);
    float2* Go = (float2*)(G + base);
    for (int i = t; i < 64 * pairs; i += 64) Go[i] = Gs[i];
    if (act) Go[64 * pairs + t] = feat2[(size_t)q * pairs + t];
}

// Split-K tiled GEMM, atomics into pre-initialized C (bias/resid folded by init kernel).
template <int BM, int BN, int BK, int TM, int TN>
__global__ void gemm_atomic(const float* __restrict__ A, const float* __restrict__ B,
                            float* __restrict__ C, int M, int N, int K,
                            int ldc, int coff, int kpb) {
    constexpr int THREADS = (BM / TM) * (BN / TN);
    __shared__ float As[BK][BM + 1];
    __shared__ float Bs[BK][BN + 1];
    int tx = threadIdx.x;
    int tcols = BN / TN;
    int tcol = tx % tcols, trow = tx / tcols;
    int m0 = blockIdx.x * BM;
    int kbeg = blockIdx.y * kpb;
    int kend = min(K, kbeg + kpb);
    float acc[TM][TN];
#pragma unroll
    for (int i = 0; i < TM; i++)
#pragma unroll
        for (int j = 0; j < TN; j++) acc[i][j] = 0.f;

    for (int k0 = kbeg; k0 < kend; k0 += BK) {
        for (int i = tx; i < BM * BK; i += THREADS) {
            int kk = i % BK, mm = i / BK;
            int m = m0 + mm, k = k0 + kk;
            As[kk][mm] = (m < M && k < K) ? A[(size_t)m * K + k] : 0.f;
        }
        for (int i = tx; i < BN * BK; i += THREADS) {
            int nn = i % BN, kk = i / BN;
            int k = k0 + kk;
            Bs[kk][nn] = (k < K && nn < N) ? B[(size_t)k * N + nn] : 0.f;
        }
        __syncthreads();
#pragma unroll
        for (int kk = 0; kk < BK; kk++) {
            float a[TM], b[TN];
#pragma unroll
            for (int i = 0; i < TM; i++) a[i] = As[kk][trow * TM + i];
#pragma unroll
            for (int j = 0; j < TN; j++) b[j] = Bs[kk][tcol * TN + j];
#pragma unroll
            for (int i = 0; i < TM; i++)
#pragma unroll
                for (int j = 0; j < TN; j++) acc[i][j] += a[i] * b[j];
        }
        __syncthreads();
    }
    for (int i = 0; i < TM; i++) {
        int m = m0 + trow * TM + i;
        if (m >= M) continue;
        for (int j = 0; j < TN; j++) {
            int nn = tcol * TN + j;
            if (nn >= N) continue;
            atomicAdd(&C[(size_t)m * ldc + coff + nn], acc[i][j]);
        }
    }
}

// Layer-3 GEMM: N=3. One block (256 thr) per row.
__global__ void rowdot3_kernel(const float* __restrict__ A, const float* __restrict__ B,
                               const float* __restrict__ bias, int K, float* __restrict__ C) {
    int m = blockIdx.x;
    int t = threadIdx.x;
    const float* a = A + (size_t)m * K;
    float a0 = 0.f, a1 = 0.f, a2 = 0.f;
    for (int k = t; k < K; k += 256) {
        float av = a[k];
        a0 += av * B[k * 3 + 0];
        a1 += av * B[k * 3 + 1];
        a2 += av * B[k * 3 + 2];
    }
    __shared__ float red[3][256];
    red[0][t] = a0; red[1][t] = a1; red[2][t] = a2;
    __syncthreads();
    for (int s2 = 128; s2 > 0; s2 >>= 1) {
        if (t < s2) {
            red[0][t] += red[0][t + s2];
            red[1][t] += red[1][t + s2];
            red[2][t] += red[2][t + s2];
        }
        __syncthreads();
    }
    if (t < 3) C[(size_t)m * 3 + t] = red[t][0] + bias[t];
}

// pos_new = pos2 + y3/128 ; vel_new = (pos_new - pos)/dt
__global__ void final_kernel(const float* __restrict__ pos, const float* __restrict__ pos2,
                             const float* __restrict__ y3, int n, float* __restrict__ out) {
    int i = blockIdx.x * blockDim.x + threadIdx.x;
    if (i >= n * 3) return;
    float pn = pos2[i] + y3[i] * (1.f / 128.f);
    out[i] = pn;
    out[n * 3 + i] = (pn - pos[i]) * (1.f / DT_F);
}

extern "C" void kernel_launch(void* const* d_in, const int* in_sizes, int n_in,
                              void* d_out, int out_size, void* d_ws, size_t ws_size,
                              hipStream_t stream) {
    const float* pos       = (const float*)d_in[0];
    const float* vel       = (const float*)d_in[1];
    const float* box       = (const float*)d_in[2];
    const float* box_feats = (const float*)d_in[3];
    const int*   ff_q      = (const int*)d_in[4];
    const int*   ff_s      = (const int*)d_in[5];
    const int*   fo_q      = (const int*)d_in[6];
    const int*   fo_s      = (const int*)d_in[7];
    const float* w_cf0     = (const float*)d_in[8];
    const float* w_co0     = (const float*)d_in[9];
    const float* w_d0      = (const float*)d_in[10];
    const float* b_d0      = (const float*)d_in[11];
    const float* w_c1      = (const float*)d_in[12];
    const float* w_d1      = (const float*)d_in[13];
    const float* b_d1      = (const float*)d_in[14];
    const float* w_c2      = (const float*)d_in[15];
    const float* w_d2      = (const float*)d_in[16];
    const float* b_d2      = (const float*)d_in[17];
    const float* w_c3      = (const float*)d_in[18];
    const float* w_d3      = (const float*)d_in[19];
    const float* b_d3      = (const float*)d_in[20];
    float* out = (float*)d_out;

    int n   = in_sizes[0] / 3;
    int Eff = in_sizes[4];
    int Efo = in_sizes[6];

    float* base = (float*)d_ws;
    size_t off = 0;
    auto alloc = [&](size_t nf) { float* p = base + off; off += (nf + 3) & ~(size_t)3; return p; };
    float* pos2  = alloc((size_t)n * 3);
    float* fl    = alloc((size_t)n * 4);
    float* x96   = alloc((size_t)n * 96);
    float* hbuf  = alloc((size_t)n * 96);
    float* x64a  = alloc((size_t)n * 64);
    float* x64b  = alloc((size_t)n * 64);
    float* y3    = alloc((size_t)n * 3);
    int* rp_ff   = (int*)alloc((size_t)n + 1);
    int* rp_fo   = (int*)alloc((size_t)n + 1);
    float* Wc    = alloc((size_t)65 * 96 * 64);
    float* wgt_ff = alloc((size_t)Eff * 8);
    uint2* cl_ff  = (uint2*)alloc((size_t)Eff * 2);
    float* wgt_fo = alloc((size_t)Efo * 8);
    uint2* cl_fo  = (uint2*)alloc((size_t)Efo * 2);
    float* G = base + off;

    size_t totalF = ws_size / sizeof(float);
    size_t availF = (totalF > off) ? (totalF - off) : 0;
    auto chunkQ = [&](int Kl) {
        long q = (long)(availF / (size_t)Kl);
        if (q < 1) q = 1;
        if (q > n) q = n;
        return (int)q;
    };

    // --- prep, CSR, edge geometry (once) ---
    prep_kernel<<<cdiv(n, 256), 256, 0, stream>>>(pos, vel, n, pos2, fl);
    row_ptr_kernel<<<cdiv(n + 1, 256), 256, 0, stream>>>(ff_q, Eff, n, rp_ff);
    row_ptr_kernel<<<cdiv(n + 1, 256), 256, 0, stream>>>(fo_q, Efo, n, rp_fo);
    edge_geom_kernel<<<cdiv(Eff, 256), 256, 0, stream>>>(pos2, pos2, ff_q, ff_s, Eff, wgt_ff, cl_ff);
    edge_geom_kernel<<<cdiv(Efo, 256), 256, 0, stream>>>(pos2, box, fo_q, fo_s, Efo, wgt_fo, cl_fo);

    // --- layer 0 ---
    init_out_kernel<<<cdiv(n * 64, 256), 256, 0, stream>>>(x96, nullptr, nullptr, n, 64, 96);
    dense0_kernel<<<cdiv(n * 32, 256), 256, 0, stream>>>(fl, w_d0, b_d0, n, x96);
    {
        int Q = chunkQ(64 * 4);
        for (int q0 = 0; q0 < n; q0 += Q) {
            int mc = std::min(Q, n - q0);
            build_G_small<<<mc, 64, 0, stream>>>(fl, 4, wgt_ff, cl_ff, ff_s, rp_ff, q0, G);
            gemm_atomic<64, 32, 16, 4, 2><<<dim3(cdiv(mc, 64), 2), 256, 0, stream>>>(
                G, w_cf0, x96 + (size_t)q0 * 96, mc, 32, 256, 96, 32, 8 * 16);
        }
    }
    {
        int Q = chunkQ(64 * 3);
        for (int q0 = 0; q0 < n; q0 += Q) {
            int mc = std::min(Q, n - q0);
            build_G_small<<<mc, 64, 0, stream>>>(box_feats, 3, wgt_fo, cl_fo, fo_s, rp_fo, q0, G);
            gemm_atomic<64, 32, 16, 4, 2><<<dim3(cdiv(mc, 64), 2), 256, 0, stream>>>(
                G, w_co0, x96 + (size_t)q0 * 96, mc, 32, 192, 96, 0, 6 * 16);
        }
    }

    // --- layer 1: 96 -> 64 ---
    relu_kernel<<<cdiv(n * 96, 256), 256, 0, stream>>>(x96, n * 96, hbuf);
    init_out_kernel<<<cdiv(n * 64, 256), 256, 0, stream>>>(x64a, b_d1, nullptr, n, 64, 64);
    hipMemcpyAsync(Wc, w_c1, sizeof(float) * 64 * 96 * 64, hipMemcpyDeviceToDevice, stream);
    hipMemcpyAsync(Wc + 64 * 96 * 64, w_d1, sizeof(float) * 96 * 64, hipMemcpyDeviceToDevice, stream);
    {
        int Q = chunkQ(65 * 96);
        for (int q0 = 0; q0 < n; q0 += Q) {
            int mc = std::min(Q, n - q0);
            build_G_big<<<mc, 64, 64 * 48 * 8, stream>>>(hbuf, 48, wgt_ff, cl_ff, ff_s, rp_ff, hbuf, q0, G);
            gemm_atomic<64, 64, 16, 4, 4><<<dim3(cdiv(mc, 64), 4), 256, 0, stream>>>(
                G, Wc, x64a + (size_t)q0 * 64, mc, 64, 65 * 96, 64, 0, cdiv(390, 4) * 16);
        }
    }

    // --- layer 2: 64 -> 64, residual ---
    relu_kernel<<<cdiv(n * 64, 256), 256, 0, stream>>>(x64a, n * 64, hbuf);
    init_out_kernel<<<cdiv(n * 64, 256), 256, 0, stream>>>(x64b, b_d2, x64a, n, 64, 64);
    hipMemcpyAsync(Wc, w_c2, sizeof(float) * 64 * 64 * 64, hipMemcpyDeviceToDevice, stream);
    hipMemcpyAsync(Wc + 64 * 64 * 64, w_d2, sizeof(float) * 64 * 64, hipMemcpyDeviceToDevice, stream);
    {
        int Q = chunkQ(65 * 64);
        for (int q0 = 0; q0 < n; q0 += Q) {
            int mc = std::min(Q, n - q0);
            build_G_big<<<mc, 64, 64 * 32 * 8, stream>>>(hbuf, 32, wgt_ff, cl_ff, ff_s, rp_ff, hbuf, q0, G);
            gemm_atomic<64, 64, 16, 4, 4><<<dim3(cdiv(mc, 64), 4), 256, 0, stream>>>(
                G, Wc, x64b + (size_t)q0 * 64, mc, 64, 65 * 64, 64, 0, cdiv(260, 4) * 16);
        }
    }

    // --- layer 3: 64 -> 3 ---
    relu_kernel<<<cdiv(n * 64, 256), 256, 0, stream>>>(x64b, n * 64, hbuf);
    hipMemcpyAsync(Wc, w_c3, sizeof(float) * 64 * 64 * 3, hipMemcpyDeviceToDevice, stream);
    hipMemcpyAsync(Wc + 64 * 64 * 3, w_d3, sizeof(float) * 64 * 3, hipMemcpyDeviceToDevice, stream);
    {
        int Q = chunkQ(65 * 64);
        for (int q0 = 0; q0 < n; q0 += Q) {
            int mc = std::min(Q, n - q0);
            build_G_big<<<mc, 64, 64 * 32 * 8, stream>>>(hbuf, 32, wgt_ff, cl_ff, ff_s, rp_ff, hbuf, q0, G);
            rowdot3_kernel<<<mc, 256, 0, stream>>>(G, Wc, b_d3, 65 * 64, y3 + (size_t)q0 * 3);
        }
    }

    final_kernel<<<cdiv(n * 3, 256), 256, 0, stream>>>(pos, pos2, y3, n, out);
}

// Round 3
// 1616.555 us; speedup vs baseline: 5.5585x; 1.7385x over previous
//
#include <hip/hip_runtime.h>
#include <algorithm>

#define DT_F 0.02f
#define INV_R (1.0f / 0.1125f)

typedef __attribute__((ext_vector_type(8))) short short8;
typedef __attribute__((ext_vector_type(4))) float float4v;

static inline int cdiv(int a, int b) { return (a + b - 1) / b; }

__device__ __forceinline__ float sgnf(float v) {
    return (v > 0.f) ? 1.f : ((v < 0.f) ? -1.f : 0.f);
}

__device__ __forceinline__ unsigned short f2bf(float f) {
    union { float f; unsigned u; } v; v.f = f;
    return (unsigned short)((v.u + 0x7fffu + ((v.u >> 16) & 1u)) >> 16);
}
__device__ __forceinline__ float bf2f(unsigned short h) {
    union { unsigned u; float f; } v; v.u = ((unsigned)h) << 16;
    return v.f;
}

// Exact port of reference ball_to_cube (f32).
__device__ __forceinline__ void ball_to_cube_dev(float x, float y, float z,
                                                 float& ox, float& oy, float& oz) {
    const float eps = 1e-12f;
    float sq = x * x + y * y + z * z;
    float nrm = sqrtf(sq + eps);
    float xy2 = x * x + y * y;
    bool cap = 1.25f * z * z > xy2;
    float s_cap = sqrtf(3.f * nrm / (nrm + fabsf(z) + eps));
    float s_side = nrm / sqrtf(xy2 + eps);
    float s = cap ? s_cap : s_side;
    float xc = x * s, yc = y * s;
    float zc = cap ? sgnf(z) * nrm : 1.5f * z;
    if (!(sq > eps)) { xc = 0.f; yc = 0.f; zc = 0.f; }
    float rxy = sqrtf(xc * xc + yc * yc + eps);
    bool xbig = fabsf(yc) <= fabsf(xc);
    float dx = (fabsf(xc) > eps) ? xc : 1.f;
    float dy = (fabsf(yc) > eps) ? yc : 1.f;
    const float c4pi = 1.27323954473516276f;  // 4/pi
    float tx = sgnf(xc) * rxy, ty = sgnf(yc) * rxy;
    float xq = xbig ? tx : ty * c4pi * atanf(xc / dy);
    float yq = xbig ? tx * c4pi * atanf(yc / dx) : ty;
    if (!(xc * xc + yc * yc > eps)) { xq = 0.f; yq = 0.f; }
    ox = xq; oy = yq; oz = zc;
}

__global__ void prep_kernel(const float* __restrict__ pos, const float* __restrict__ vel,
                            int n, float* __restrict__ pos2, float* __restrict__ fl) {
    int i = blockIdx.x * blockDim.x + threadIdx.x;
    if (i >= n) return;
    float v0 = vel[i * 3 + 0], v1 = vel[i * 3 + 1], v2 = vel[i * 3 + 2];
    float u0 = v0, u1 = v1 + DT_F * (-9.81f), u2 = v2;
    pos2[i * 3 + 0] = pos[i * 3 + 0] + DT_F * (u0 + v0) * 0.5f;
    pos2[i * 3 + 1] = pos[i * 3 + 1] + DT_F * (u1 + v1) * 0.5f;
    pos2[i * 3 + 2] = pos[i * 3 + 2] + DT_F * (u2 + v2) * 0.5f;
    fl[i * 4 + 0] = 1.f;
    fl[i * 4 + 1] = u0;
    fl[i * 4 + 2] = u1;
    fl[i * 4 + 3] = u2;
}

__global__ void row_ptr_kernel(const int* __restrict__ q_idx, int E, int nq,
                               int* __restrict__ row_ptr) {
    int q = blockIdx.x * blockDim.x + threadIdx.x;
    if (q > nq) return;
    int lo = 0, hi = E;
    while (lo < hi) {
        int mid = (lo + hi) >> 1;
        if (q_idx[mid] < q) lo = mid + 1; else hi = mid;
    }
    row_ptr[q] = lo;
}

// Per-edge geometry once; ix clamped to [0,2] => 8 distinct corners (no RMW aliasing).
__global__ void edge_geom_kernel(const float* __restrict__ posq, const float* __restrict__ poss,
                                 const int* __restrict__ q_idx, const int* __restrict__ s_idx,
                                 int E, float* __restrict__ wgt, uint2* __restrict__ cells) {
    int e = blockIdx.x * blockDim.x + threadIdx.x;
    if (e >= E) return;
    int q = q_idx[e], s = s_idx[e];
    float dx = (poss[s * 3 + 0] - posq[q * 3 + 0]) * INV_R;
    float dy = (poss[s * 3 + 1] - posq[q * 3 + 1]) * INV_R;
    float dz = (poss[s * 3 + 2] - posq[q * 3 + 2]) * INV_R;
    float r2 = dx * dx + dy * dy + dz * dz;
    float w1 = 1.f - r2;
    float win = fminf(fmaxf(w1 * w1 * w1, 0.f), 1.f);
    float bx, by, bz;
    ball_to_cube_dev(dx, dy, dz, bx, by, bz);
    float gx = (bx + 1.f) * 1.5f, gy = (by + 1.f) * 1.5f, gz = (bz + 1.f) * 1.5f;
    int ix = min(max((int)floorf(gx), 0), 2);
    int iy = min(max((int)floorf(gy), 0), 2);
    int iz = min(max((int)floorf(gz), 0), 2);
    float fx = gx - (float)ix, fy = gy - (float)iy, fz = gz - (float)iz;
    float wv[8];
    unsigned int cl[8];
#pragma unroll
    for (int c = 0; c < 8; c++) {
        int cbx = (c >> 2) & 1, cby = (c >> 1) & 1, cbz = c & 1;
        int jx = ix + cbx, jy = iy + cby, jz = iz + cbz;
        cl[c] = (unsigned int)((jx * 4 + jy) * 4 + jz);
        wv[c] = win * (cbx ? fx : 1.f - fx) * (cby ? fy : 1.f - fy) * (cbz ? fz : 1.f - fz);
    }
    float4* wp = (float4*)(wgt + (size_t)e * 8);
    wp[0] = make_float4(wv[0], wv[1], wv[2], wv[3]);
    wp[1] = make_float4(wv[4], wv[5], wv[6], wv[7]);
    uint2 cp;
    cp.x = cl[0] | (cl[1] << 8) | (cl[2] << 16) | (cl[3] << 24);
    cp.y = cl[4] | (cl[5] << 8) | (cl[6] << 16) | (cl[7] << 24);
    cells[e] = cp;
}

// a_df = fl @ w_d0 + b_d0 -> x96[:, 64:96]
__global__ void dense0_kernel(const float* __restrict__ fl, const float* __restrict__ w,
                              const float* __restrict__ b, int n, float* __restrict__ x96) {
    int i = blockIdx.x * blockDim.x + threadIdx.x;
    if (i >= n * 32) return;
    int q = i >> 5, o = i & 31;
    float acc = b[o];
#pragma unroll
    for (int c = 0; c < 4; c++) acc += fl[q * 4 + c] * w[c * 32 + o];
    x96[(size_t)q * 96 + 64 + o] = acc;
}

// C[q,o] = bias[o] (+resid[q,o]); zero if bias null (pre-init for atomic split-K).
__global__ void init_out_kernel(float* __restrict__ C, const float* __restrict__ bias,
                                const float* __restrict__ resid, int n, int co, int ldc) {
    int i = blockIdx.x * blockDim.x + threadIdx.x;
    if (i >= n * co) return;
    int q = i / co, o = i - q * co;
    float v = bias ? bias[o] : 0.f;
    if (resid) v += resid[(size_t)q * ldc + o];
    C[(size_t)q * ldc + o] = v;
}

// Wt[n][k] = bf16(W[k][n]) with W = [w_c (64*ci rows) ; w_d (ci rows)], K = 65*ci.
__global__ void wt_kernel(const float* __restrict__ wc, const float* __restrict__ wd,
                          int ci, int co, int K, unsigned short* __restrict__ Wt) {
    int i = blockIdx.x * blockDim.x + threadIdx.x;
    if (i >= co * K) return;
    int n = i / K, k = i - n * K;
    float v = (k < 64 * ci) ? wc[(size_t)k * co + n] : wd[(size_t)(k - 64 * ci) * co + n];
    Wt[i] = f2bf(v);
}

// Small-cin (layer 0) G build: f32 G out [Q][64][cin].
__global__ __launch_bounds__(64) void build_G_small(
    const float* __restrict__ feat, int cin,
    const float* __restrict__ wgt, const uint2* __restrict__ cells,
    const int* __restrict__ s_idx, const int* __restrict__ row_ptr, int q0,
    float* __restrict__ G) {
    __shared__ float Gs[8 * 64 * 8];
    int lq = blockIdx.x, q = q0 + lq, t = threadIdx.x;
    int r = t >> 3, ch = t & 7;
    for (int i = t; i < 4096; i += 64) Gs[i] = 0.f;
    __syncthreads();
    int e0 = row_ptr[q], e1 = row_ptr[q + 1];
    for (int e = e0; e < e1; e++) {
        int s = s_idx[e];
        float w = wgt[(size_t)e * 8 + r];
        uint2 cp = cells[e];
        unsigned int word = (r < 4) ? cp.x : cp.y;
        int cell = (int)((word >> ((r & 3) * 8)) & 255u);
        float fv = (ch < cin) ? feat[(size_t)s * cin + ch] : 0.f;
        Gs[(r * 64 + cell) * 8 + ch] += w * fv;
    }
    __syncthreads();
    size_t base = (size_t)lq * 64 * cin;
    for (int i = t; i < 64 * cin; i += 64) {
        int cell = i / cin, c = i - cell * cin;
        float acc = 0.f;
#pragma unroll
        for (int rr = 0; rr < 8; rr++) acc += Gs[(rr * 64 + cell) * 8 + c];
        G[base + i] = acc;
    }
}

// Big-cin G build -> bf16 G [Q][65][cin]; slot 64 = featq[q]; optional fused ReLU.
__global__ __launch_bounds__(64) void build_G_big(
    const float* __restrict__ feat, int pairs,  // pairs = cin/2
    const float* __restrict__ wgt, const uint2* __restrict__ cells,
    const int* __restrict__ s_idx, const int* __restrict__ row_ptr,
    const float* __restrict__ featq, int q0, int dorelu,
    unsigned short* __restrict__ G) {
    extern __shared__ float2 Gs[];  // [64][pairs]
    int lq = blockIdx.x, q = q0 + lq, t = threadIdx.x;
    int cin = pairs * 2;
    for (int i = t; i < 64 * pairs; i += 64) Gs[i] = make_float2(0.f, 0.f);
    __syncthreads();
    const float2* feat2 = (const float2*)feat;
    bool act = t < pairs;
    int e0 = row_ptr[q], e1 = row_ptr[q + 1];
    for (int e = e0; e < e1; e++) {
        int s = s_idx[e];
        const float4* wp = (const float4*)(wgt + (size_t)e * 8);
        float4 wa = wp[0], wb = wp[1];
        uint2 cp = cells[e];
        if (act) {
            float2 fv = feat2[(size_t)s * pairs + t];
            if (dorelu) { fv.x = fmaxf(fv.x, 0.f); fv.y = fmaxf(fv.y, 0.f); }
            int c0 = (int)(cp.x & 255u), c1 = (int)((cp.x >> 8) & 255u);
            int c2 = (int)((cp.x >> 16) & 255u), c3 = (int)((cp.x >> 24) & 255u);
            int c4 = (int)(cp.y & 255u), c5 = (int)((cp.y >> 8) & 255u);
            int c6 = (int)((cp.y >> 16) & 255u), c7 = (int)((cp.y >> 24) & 255u);
            float2 g0 = Gs[c0 * pairs + t], g1 = Gs[c1 * pairs + t];
            float2 g2 = Gs[c2 * pairs + t], g3 = Gs[c3 * pairs + t];
            float2 g4 = Gs[c4 * pairs + t], g5 = Gs[c5 * pairs + t];
            float2 g6 = Gs[c6 * pairs + t], g7 = Gs[c7 * pairs + t];
            g0.x += wa.x * fv.x; g0.y += wa.x * fv.y;
            g1.x += wa.y * fv.x; g1.y += wa.y * fv.y;
            g2.x += wa.z * fv.x; g2.y += wa.z * fv.y;
            g3.x += wa.w * fv.x; g3.y += wa.w * fv.y;
            g4.x += wb.x * fv.x; g4.y += wb.x * fv.y;
            g5.x += wb.y * fv.x; g5.y += wb.y * fv.y;
            g6.x += wb.z * fv.x; g6.y += wb.z * fv.y;
            g7.x += wb.w * fv.x; g7.y += wb.w * fv.y;
            Gs[c0 * pairs + t] = g0; Gs[c1 * pairs + t] = g1;
            Gs[c2 * pairs + t] = g2; Gs[c3 * pairs + t] = g3;
            Gs[c4 * pairs + t] = g4; Gs[c5 * pairs + t] = g5;
            Gs[c6 * pairs + t] = g6; Gs[c7 * pairs + t] = g7;
        }
    }
    __syncthreads();
    unsigned int* Go = (unsigned int*)(G + (size_t)lq * (size_t)(65 * cin));
    for (int i = t; i < 64 * pairs; i += 64) {
        float2 g = Gs[i];
        Go[i] = (unsigned int)f2bf(g.x) | ((unsigned int)f2bf(g.y) << 16);
    }
    if (act) {
        float2 fq = feat2[(size_t)q * pairs + t];
        if (dorelu) { fq.x = fmaxf(fq.x, 0.f); fq.y = fmaxf(fq.y, 0.f); }
        Go[64 * pairs + t] = (unsigned int)f2bf(fq.x) | ((unsigned int)f2bf(fq.y) << 16);
    }
}

// bf16 MFMA GEMM, split-K atomics. A: [M][K] bf16 row-major; Wt: [64][K] bf16 (n-major).
// grid (M/64, KS); 4 waves; wave w -> n-tile w. mfma_f32_16x16x32_bf16:
//   A frag lane: A[m0+(l&15)][k0+(l>>4)*8+j]; B frag lane: Wt[n0+(l&15)][same k] (both 16B).
//   C/D: col=lane&15, row=(lane>>4)*4+reg.  K must be a multiple of 32.
__global__ __launch_bounds__(256) void gemm_mfma(
    const unsigned short* __restrict__ A, const unsigned short* __restrict__ Wt,
    float* __restrict__ C, int M, int K, int ldc, int kpb) {
    int wave = threadIdx.x >> 6, lane = threadIdx.x & 63;
    int m0 = blockIdx.x * 64;
    int kbeg = blockIdx.y * kpb;
    int kend = min(K, kbeg + kpb);
    int mrow = lane & 15, kq = lane >> 4;
    int n0 = wave * 16;
    const unsigned short* Bp = Wt + (size_t)(n0 + mrow) * K;
    float4v acc[4] = {{0.f, 0.f, 0.f, 0.f}, {0.f, 0.f, 0.f, 0.f},
                      {0.f, 0.f, 0.f, 0.f}, {0.f, 0.f, 0.f, 0.f}};
    int r0 = min(m0 + mrow, M - 1);
    int r1 = min(m0 + 16 + mrow, M - 1);
    int r2 = min(m0 + 32 + mrow, M - 1);
    int r3 = min(m0 + 48 + mrow, M - 1);
    const unsigned short* A0 = A + (size_t)r0 * K;
    const unsigned short* A1 = A + (size_t)r1 * K;
    const unsigned short* A2 = A + (size_t)r2 * K;
    const unsigned short* A3 = A + (size_t)r3 * K;
    for (int k0 = kbeg; k0 < kend; k0 += 32) {
        int kk = k0 + kq * 8;
        short8 b = *(const short8*)(Bp + kk);
        short8 a0 = *(const short8*)(A0 + kk);
        short8 a1 = *(const short8*)(A1 + kk);
        short8 a2 = *(const short8*)(A2 + kk);
        short8 a3 = *(const short8*)(A3 + kk);
        acc[0] = __builtin_amdgcn_mfma_f32_16x16x32_bf16(a0, b, acc[0], 0, 0, 0);
        acc[1] = __builtin_amdgcn_mfma_f32_16x16x32_bf16(a1, b, acc[1], 0, 0, 0);
        acc[2] = __builtin_amdgcn_mfma_f32_16x16x32_bf16(a2, b, acc[2], 0, 0, 0);
        acc[3] = __builtin_amdgcn_mfma_f32_16x16x32_bf16(a3, b, acc[3], 0, 0, 0);
    }
    int col = lane & 15, rq = lane >> 4;
#pragma unroll
    for (int mt = 0; mt < 4; mt++) {
#pragma unroll
        for (int r = 0; r < 4; r++) {
            int m = m0 + mt * 16 + rq * 4 + r;
            if (m < M) atomicAdd(&C[(size_t)m * ldc + n0 + col], acc[mt][r]);
        }
    }
}

// f32 split-K GEMM (layer 0 only, tiny K).
template <int BM, int BN, int BK, int TM, int TN>
__global__ void gemm_atomic(const float* __restrict__ A, const float* __restrict__ B,
                            float* __restrict__ C, int M, int N, int K,
                            int ldc, int coff, int kpb) {
    constexpr int THREADS = (BM / TM) * (BN / TN);
    __shared__ float As[BK][BM + 1];
    __shared__ float Bs[BK][BN + 1];
    int tx = threadIdx.x;
    int tcols = BN / TN;
    int tcol = tx % tcols, trow = tx / tcols;
    int m0 = blockIdx.x * BM;
    int kbeg = blockIdx.y * kpb;
    int kend = min(K, kbeg + kpb);
    float acc[TM][TN];
#pragma unroll
    for (int i = 0; i < TM; i++)
#pragma unroll
        for (int j = 0; j < TN; j++) acc[i][j] = 0.f;
    for (int k0 = kbeg; k0 < kend; k0 += BK) {
        for (int i = tx; i < BM * BK; i += THREADS) {
            int kk = i % BK, mm = i / BK;
            int m = m0 + mm, k = k0 + kk;
            As[kk][mm] = (m < M && k < K) ? A[(size_t)m * K + k] : 0.f;
        }
        for (int i = tx; i < BN * BK; i += THREADS) {
            int nn = i % BN, kk = i / BN;
            int k = k0 + kk;
            Bs[kk][nn] = (k < K && nn < N) ? B[(size_t)k * N + nn] : 0.f;
        }
        __syncthreads();
#pragma unroll
        for (int kk = 0; kk < BK; kk++) {
            float a[TM], b[TN];
#pragma unroll
            for (int i = 0; i < TM; i++) a[i] = As[kk][trow * TM + i];
#pragma unroll
            for (int j = 0; j < TN; j++) b[j] = Bs[kk][tcol * TN + j];
#pragma unroll
            for (int i = 0; i < TM; i++)
#pragma unroll
                for (int j = 0; j < TN; j++) acc[i][j] += a[i] * b[j];
        }
        __syncthreads();
    }
    for (int i = 0; i < TM; i++) {
        int m = m0 + trow * TM + i;
        if (m >= M) continue;
        for (int j = 0; j < TN; j++) {
            int nn = tcol * TN + j;
            if (nn >= N) continue;
            atomicAdd(&C[(size_t)m * ldc + coff + nn], acc[i][j]);
        }
    }
}

// Layer-3: y3[m,0..2] = A(bf16)[m,:] @ B(f32)[:,0..2] + bias.
__global__ void rowdot3_kernel(const unsigned short* __restrict__ A, const float* __restrict__ B,
                               const float* __restrict__ bias, int K, float* __restrict__ C) {
    int m = blockIdx.x;
    int t = threadIdx.x;
    const unsigned short* a = A + (size_t)m * K;
    float a0 = 0.f, a1 = 0.f, a2 = 0.f;
    for (int k = t; k < K; k += 256) {
        float av = bf2f(a[k]);
        a0 += av * B[k * 3 + 0];
        a1 += av * B[k * 3 + 1];
        a2 += av * B[k * 3 + 2];
    }
    __shared__ float red[3][256];
    red[0][t] = a0; red[1][t] = a1; red[2][t] = a2;
    __syncthreads();
    for (int s2 = 128; s2 > 0; s2 >>= 1) {
        if (t < s2) {
            red[0][t] += red[0][t + s2];
            red[1][t] += red[1][t + s2];
            red[2][t] += red[2][t + s2];
        }
        __syncthreads();
    }
    if (t < 3) C[(size_t)m * 3 + t] = red[t][0] + bias[t];
}

__global__ void final_kernel(const float* __restrict__ pos, const float* __restrict__ pos2,
                             const float* __restrict__ y3, int n, float* __restrict__ out) {
    int i = blockIdx.x * blockDim.x + threadIdx.x;
    if (i >= n * 3) return;
    float pn = pos2[i] + y3[i] * (1.f / 128.f);
    out[i] = pn;
    out[n * 3 + i] = (pn - pos[i]) * (1.f / DT_F);
}

extern "C" void kernel_launch(void* const* d_in, const int* in_sizes, int n_in,
                              void* d_out, int out_size, void* d_ws, size_t ws_size,
                              hipStream_t stream) {
    const float* pos       = (const float*)d_in[0];
    const float* vel       = (const float*)d_in[1];
    const float* box       = (const float*)d_in[2];
    const float* box_feats = (const float*)d_in[3];
    const int*   ff_q      = (const int*)d_in[4];
    const int*   ff_s      = (const int*)d_in[5];
    const int*   fo_q      = (const int*)d_in[6];
    const int*   fo_s      = (const int*)d_in[7];
    const float* w_cf0     = (const float*)d_in[8];
    const float* w_co0     = (const float*)d_in[9];
    const float* w_d0      = (const float*)d_in[10];
    const float* b_d0      = (const float*)d_in[11];
    const float* w_c1      = (const float*)d_in[12];
    const float* w_d1      = (const float*)d_in[13];
    const float* b_d1      = (const float*)d_in[14];
    const float* w_c2      = (const float*)d_in[15];
    const float* w_d2      = (const float*)d_in[16];
    const float* b_d2      = (const float*)d_in[17];
    const float* w_c3      = (const float*)d_in[18];
    const float* w_d3      = (const float*)d_in[19];
    const float* b_d3      = (const float*)d_in[20];
    float* out = (float*)d_out;

    int n   = in_sizes[0] / 3;
    int Eff = in_sizes[4];
    int Efo = in_sizes[6];

    float* base = (float*)d_ws;
    size_t off = 0;
    auto alloc = [&](size_t nf) { float* p = base + off; off += (nf + 3) & ~(size_t)3; return p; };
    float* pos2  = alloc((size_t)n * 3);
    float* fl    = alloc((size_t)n * 4);
    float* x96   = alloc((size_t)n * 96);
    float* x64a  = alloc((size_t)n * 64);
    float* x64b  = alloc((size_t)n * 64);
    float* y3    = alloc((size_t)n * 3);
    int* rp_ff   = (int*)alloc((size_t)n + 1);
    int* rp_fo   = (int*)alloc((size_t)n + 1);
    float* Wc    = alloc((size_t)65 * 96 * 64);            // f32 combined W (layer 3)
    unsigned short* Wt = (unsigned short*)alloc((size_t)65 * 96 * 64 / 2);  // bf16 Wt
    float* wgt_ff = alloc((size_t)Eff * 8);
    uint2* cl_ff  = (uint2*)alloc((size_t)Eff * 2);
    float* wgt_fo = alloc((size_t)Efo * 8);
    uint2* cl_fo  = (uint2*)alloc((size_t)Efo * 2);
    float* G = base + off;                                  // f32 view (layer 0)
    unsigned short* Gb = (unsigned short*)G;                // bf16 view (layers 1-3)

    size_t totalF = ws_size / sizeof(float);
    size_t availF = (totalF > off) ? (totalF - off) : 0;
    auto chunkQ = [&](size_t floatsPerQ) {
        long q = (long)(availF / floatsPerQ);
        if (q < 1) q = 1;
        if (q > n) q = n;
        return (int)q;
    };

    // --- prep, CSR, edge geometry (once) ---
    prep_kernel<<<cdiv(n, 256), 256, 0, stream>>>(pos, vel, n, pos2, fl);
    row_ptr_kernel<<<cdiv(n + 1, 256), 256, 0, stream>>>(ff_q, Eff, n, rp_ff);
    row_ptr_kernel<<<cdiv(n + 1, 256), 256, 0, stream>>>(fo_q, Efo, n, rp_fo);
    edge_geom_kernel<<<cdiv(Eff, 256), 256, 0, stream>>>(pos2, pos2, ff_q, ff_s, Eff, wgt_ff, cl_ff);
    edge_geom_kernel<<<cdiv(Efo, 256), 256, 0, stream>>>(pos2, box, fo_q, fo_s, Efo, wgt_fo, cl_fo);

    // --- layer 0 (f32 path, tiny K) ---
    init_out_kernel<<<cdiv(n * 64, 256), 256, 0, stream>>>(x96, nullptr, nullptr, n, 64, 96);
    dense0_kernel<<<cdiv(n * 32, 256), 256, 0, stream>>>(fl, w_d0, b_d0, n, x96);
    {
        int Q = chunkQ(64 * 4);
        for (int q0 = 0; q0 < n; q0 += Q) {
            int mc = std::min(Q, n - q0);
            build_G_small<<<mc, 64, 0, stream>>>(fl, 4, wgt_ff, cl_ff, ff_s, rp_ff, q0, G);
            gemm_atomic<64, 32, 16, 4, 2><<<dim3(cdiv(mc, 64), 2), 256, 0, stream>>>(
                G, w_cf0, x96 + (size_t)q0 * 96, mc, 32, 256, 96, 32, 8 * 16);
        }
    }
    {
        int Q = chunkQ(64 * 3);
        for (int q0 = 0; q0 < n; q0 += Q) {
            int mc = std::min(Q, n - q0);
            build_G_small<<<mc, 64, 0, stream>>>(box_feats, 3, wgt_fo, cl_fo, fo_s, rp_fo, q0, G);
            gemm_atomic<64, 32, 16, 4, 2><<<dim3(cdiv(mc, 64), 2), 256, 0, stream>>>(
                G, w_co0, x96 + (size_t)q0 * 96, mc, 32, 192, 96, 0, 6 * 16);
        }
    }

    // --- layer 1: 96 -> 64, bf16 MFMA (relu fused into build) ---
    {
        const int K = 65 * 96;
        wt_kernel<<<cdiv(64 * K, 256), 256, 0, stream>>>(w_c1, w_d1, 96, 64, K, Wt);
        init_out_kernel<<<cdiv(n * 64, 256), 256, 0, stream>>>(x64a, b_d1, nullptr, n, 64, 64);
        int Q = chunkQ((size_t)K / 2);
        for (int q0 = 0; q0 < n; q0 += Q) {
            int mc = std::min(Q, n - q0);
            build_G_big<<<mc, 64, 64 * 48 * 8, stream>>>(
                x96, 48, wgt_ff, cl_ff, ff_s, rp_ff, x96, q0, 1, Gb);
            gemm_mfma<<<dim3(cdiv(mc, 64), 4), 256, 0, stream>>>(
                Gb, Wt, x64a + (size_t)q0 * 64, mc, K, 64, cdiv(K / 32, 4) * 32);
        }
    }

    // --- layer 2: 64 -> 64, residual, bf16 MFMA ---
    {
        const int K = 65 * 64;
        wt_kernel<<<cdiv(64 * K, 256), 256, 0, stream>>>(w_c2, w_d2, 64, 64, K, Wt);
        init_out_kernel<<<cdiv(n * 64, 256), 256, 0, stream>>>(x64b, b_d2, x64a, n, 64, 64);
        int Q = chunkQ((size_t)K / 2);
        for (int q0 = 0; q0 < n; q0 += Q) {
            int mc = std::min(Q, n - q0);
            build_G_big<<<mc, 64, 64 * 32 * 8, stream>>>(
                x64a, 32, wgt_ff, cl_ff, ff_s, rp_ff, x64a, q0, 1, Gb);
            gemm_mfma<<<dim3(cdiv(mc, 64), 4), 256, 0, stream>>>(
                Gb, Wt, x64b + (size_t)q0 * 64, mc, K, 64, cdiv(K / 32, 4) * 32);
        }
    }

    // --- layer 3: 64 -> 3 ---
    {
        const int K = 65 * 64;
        hipMemcpyAsync(Wc, w_c3, sizeof(float) * 64 * 64 * 3, hipMemcpyDeviceToDevice, stream);
        hipMemcpyAsync(Wc + 64 * 64 * 3, w_d3, sizeof(float) * 64 * 3, hipMemcpyDeviceToDevice, stream);
        int Q = chunkQ((size_t)K / 2);
        for (int q0 = 0; q0 < n; q0 += Q) {
            int mc = std::min(Q, n - q0);
            build_G_big<<<mc, 64, 64 * 32 * 8, stream>>>(
                x64b, 32, wgt_ff, cl_ff, ff_s, rp_ff, x64b, q0, 1, Gb);
            rowdot3_kernel<<<mc, 256, 0, stream>>>(Gb, Wc, b_d3, K, y3 + (size_t)q0 * 3);
        }
    }

    final_kernel<<<cdiv(n * 3, 256), 256, 0, stream>>>(pos, pos2, y3, n, out);
}

// Round 4
// 1539.449 us; speedup vs baseline: 5.8369x; 1.0501x over previous
//
#include <hip/hip_runtime.h>
#include <algorithm>

#define DT_F 0.02f
#define INV_R (1.0f / 0.1125f)

typedef __attribute__((ext_vector_type(8))) short short8;
typedef __attribute__((ext_vector_type(4))) float float4v;

static inline int cdiv(int a, int b) { return (a + b - 1) / b; }

__device__ __forceinline__ float sgnf(float v) {
    return (v > 0.f) ? 1.f : ((v < 0.f) ? -1.f : 0.f);
}

__device__ __forceinline__ unsigned short f2bf(float f) {
    union { float f; unsigned u; } v; v.f = f;
    return (unsigned short)((v.u + 0x7fffu + ((v.u >> 16) & 1u)) >> 16);
}
__device__ __forceinline__ float bf2f(unsigned short h) {
    union { unsigned u; float f; } v; v.u = ((unsigned)h) << 16;
    return v.f;
}

// Exact port of reference ball_to_cube (f32).
__device__ __forceinline__ void ball_to_cube_dev(float x, float y, float z,
                                                 float& ox, float& oy, float& oz) {
    const float eps = 1e-12f;
    float sq = x * x + y * y + z * z;
    float nrm = sqrtf(sq + eps);
    float xy2 = x * x + y * y;
    bool cap = 1.25f * z * z > xy2;
    float s_cap = sqrtf(3.f * nrm / (nrm + fabsf(z) + eps));
    float s_side = nrm / sqrtf(xy2 + eps);
    float s = cap ? s_cap : s_side;
    float xc = x * s, yc = y * s;
    float zc = cap ? sgnf(z) * nrm : 1.5f * z;
    if (!(sq > eps)) { xc = 0.f; yc = 0.f; zc = 0.f; }
    float rxy = sqrtf(xc * xc + yc * yc + eps);
    bool xbig = fabsf(yc) <= fabsf(xc);
    float dx = (fabsf(xc) > eps) ? xc : 1.f;
    float dy = (fabsf(yc) > eps) ? yc : 1.f;
    const float c4pi = 1.27323954473516276f;  // 4/pi
    float tx = sgnf(xc) * rxy, ty = sgnf(yc) * rxy;
    float xq = xbig ? tx : ty * c4pi * atanf(xc / dy);
    float yq = xbig ? tx * c4pi * atanf(yc / dx) : ty;
    if (!(xc * xc + yc * yc > eps)) { xq = 0.f; yq = 0.f; }
    ox = xq; oy = yq; oz = zc;
}

__global__ void prep_kernel(const float* __restrict__ pos, const float* __restrict__ vel,
                            int n, float* __restrict__ pos2, float* __restrict__ fl) {
    int i = blockIdx.x * blockDim.x + threadIdx.x;
    if (i >= n) return;
    float v0 = vel[i * 3 + 0], v1 = vel[i * 3 + 1], v2 = vel[i * 3 + 2];
    float u0 = v0, u1 = v1 + DT_F * (-9.81f), u2 = v2;
    pos2[i * 3 + 0] = pos[i * 3 + 0] + DT_F * (u0 + v0) * 0.5f;
    pos2[i * 3 + 1] = pos[i * 3 + 1] + DT_F * (u1 + v1) * 0.5f;
    pos2[i * 3 + 2] = pos[i * 3 + 2] + DT_F * (u2 + v2) * 0.5f;
    fl[i * 4 + 0] = 1.f;
    fl[i * 4 + 1] = u0;
    fl[i * 4 + 2] = u1;
    fl[i * 4 + 3] = u2;
}

__global__ void row_ptr_kernel(const int* __restrict__ q_idx, int E, int nq,
                               int* __restrict__ row_ptr) {
    int q = blockIdx.x * blockDim.x + threadIdx.x;
    if (q > nq) return;
    int lo = 0, hi = E;
    while (lo < hi) {
        int mid = (lo + hi) >> 1;
        if (q_idx[mid] < q) lo = mid + 1; else hi = mid;
    }
    row_ptr[q] = lo;
}

// Per-edge geometry once; ix clamped to [0,2] => 8 distinct corners (no RMW aliasing).
// Corner c = (cbx<<2)|(cby<<1)|cbz; cells packed as 8 bytes (uint2); wgt 8 floats.
__global__ void edge_geom_kernel(const float* __restrict__ posq, const float* __restrict__ poss,
                                 const int* __restrict__ q_idx, const int* __restrict__ s_idx,
                                 int E, float* __restrict__ wgt, uint2* __restrict__ cells) {
    int e = blockIdx.x * blockDim.x + threadIdx.x;
    if (e >= E) return;
    int q = q_idx[e], s = s_idx[e];
    float dx = (poss[s * 3 + 0] - posq[q * 3 + 0]) * INV_R;
    float dy = (poss[s * 3 + 1] - posq[q * 3 + 1]) * INV_R;
    float dz = (poss[s * 3 + 2] - posq[q * 3 + 2]) * INV_R;
    float r2 = dx * dx + dy * dy + dz * dz;
    float w1 = 1.f - r2;
    float win = fminf(fmaxf(w1 * w1 * w1, 0.f), 1.f);
    float bx, by, bz;
    ball_to_cube_dev(dx, dy, dz, bx, by, bz);
    float gx = (bx + 1.f) * 1.5f, gy = (by + 1.f) * 1.5f, gz = (bz + 1.f) * 1.5f;
    int ix = min(max((int)floorf(gx), 0), 2);
    int iy = min(max((int)floorf(gy), 0), 2);
    int iz = min(max((int)floorf(gz), 0), 2);
    float fx = gx - (float)ix, fy = gy - (float)iy, fz = gz - (float)iz;
    float wv[8];
    unsigned int cl[8];
#pragma unroll
    for (int c = 0; c < 8; c++) {
        int cbx = (c >> 2) & 1, cby = (c >> 1) & 1, cbz = c & 1;
        int jx = ix + cbx, jy = iy + cby, jz = iz + cbz;
        cl[c] = (unsigned int)((jx * 4 + jy) * 4 + jz);
        wv[c] = win * (cbx ? fx : 1.f - fx) * (cby ? fy : 1.f - fy) * (cbz ? fz : 1.f - fz);
    }
    float4* wp = (float4*)(wgt + (size_t)e * 8);
    wp[0] = make_float4(wv[0], wv[1], wv[2], wv[3]);
    wp[1] = make_float4(wv[4], wv[5], wv[6], wv[7]);
    uint2 cp;
    cp.x = cl[0] | (cl[1] << 8) | (cl[2] << 16) | (cl[3] << 24);
    cp.y = cl[4] | (cl[5] << 8) | (cl[6] << 16) | (cl[7] << 24);
    cells[e] = cp;
}

// a_df = fl @ w_d0 + b_d0 -> x96[:, 64:96]
__global__ void dense0_kernel(const float* __restrict__ fl, const float* __restrict__ w,
                              const float* __restrict__ b, int n, float* __restrict__ x96) {
    int i = blockIdx.x * blockDim.x + threadIdx.x;
    if (i >= n * 32) return;
    int q = i >> 5, o = i & 31;
    float acc = b[o];
#pragma unroll
    for (int c = 0; c < 4; c++) acc += fl[q * 4 + c] * w[c * 32 + o];
    x96[(size_t)q * 96 + 64 + o] = acc;
}

// C[q,o] = bias[o] (+resid[q,o]); zero if bias null (pre-init for atomic split-K).
__global__ void init_out_kernel(float* __restrict__ C, const float* __restrict__ bias,
                                const float* __restrict__ resid, int n, int co, int ldc) {
    int i = blockIdx.x * blockDim.x + threadIdx.x;
    if (i >= n * co) return;
    int q = i / co, o = i - q * co;
    float v = bias ? bias[o] : 0.f;
    if (resid) v += resid[(size_t)q * ldc + o];
    C[(size_t)q * ldc + o] = v;
}

// Wt[n][k] = bf16(W[k][n]) with W = [w_c (64*ci rows) ; w_d (ci rows)], K = 65*ci.
__global__ void wt_kernel(const float* __restrict__ wc, const float* __restrict__ wd,
                          int ci, int co, int K, unsigned short* __restrict__ Wt) {
    int i = blockIdx.x * blockDim.x + threadIdx.x;
    if (i >= co * K) return;
    int n = i / K, k = i - n * K;
    float v = (k < 64 * ci) ? wc[(size_t)k * co + n] : wd[(size_t)(k - 64 * ci) * co + n];
    Wt[i] = f2bf(v);
}

// Small-cin (layer 0) G build: f32 G out [Q][64][cin].
__global__ __launch_bounds__(64) void build_G_small(
    const float* __restrict__ feat, int cin,
    const float* __restrict__ wgt, const uint2* __restrict__ cells,
    const int* __restrict__ s_idx, const int* __restrict__ row_ptr, int q0,
    float* __restrict__ G) {
    __shared__ float Gs[8 * 64 * 8];
    int lq = blockIdx.x, q = q0 + lq, t = threadIdx.x;
    int r = t >> 3, ch = t & 7;
    for (int i = t; i < 4096; i += 64) Gs[i] = 0.f;
    __syncthreads();
    int e0 = row_ptr[q], e1 = row_ptr[q + 1];
    for (int e = e0; e < e1; e++) {
        int s = s_idx[e];
        float w = wgt[(size_t)e * 8 + r];
        uint2 cp = cells[e];
        unsigned int word = (r < 4) ? cp.x : cp.y;
        int cell = (int)((word >> ((r & 3) * 8)) & 255u);
        float fv = (ch < cin) ? feat[(size_t)s * cin + ch] : 0.f;
        Gs[(r * 64 + cell) * 8 + ch] += w * fv;
    }
    __syncthreads();
    size_t base = (size_t)lq * 64 * cin;
    for (int i = t; i < 64 * cin; i += 64) {
        int cell = i / cin, c = i - cell * cin;
        float acc = 0.f;
#pragma unroll
        for (int rr = 0; rr < 8; rr++) acc += Gs[(rr * 64 + cell) * 8 + c];
        G[base + i] = acc;
    }
}

// Big-cin G build, 4 waves, parity-partitioned corners.
// The 8 corners of an edge = {ix,ix+1}x{iy,iy+1}x{iz,iz+1}; cell=(jx*4+jy)*4+jz.
// Parity class (jy&1)*2+(jz&1) contains EXACTLY 2 corners per edge (consecutive ints
// alternate parity), and the 4 classes partition the 64 cells disjointly => wave w
// handles class w: 2 LDS RMWs/edge/wave, no cross-wave races even with edge drift.
// G out bf16 [Q][65][cin]; slot 64 = featq[q]; optional fused ReLU.
__global__ __launch_bounds__(256) void build_G_big(
    const float* __restrict__ feat, int pairs,  // pairs = cin/2
    const float* __restrict__ wgt, const uint2* __restrict__ cells,
    const int* __restrict__ s_idx, const int* __restrict__ row_ptr,
    const float* __restrict__ featq, int q0, int dorelu,
    unsigned short* __restrict__ G) {
    extern __shared__ float2 Gs[];  // [64][pairs]
    int lq = blockIdx.x, q = q0 + lq, t = threadIdx.x;
    int wave = t >> 6, lane = t & 63;
    int pa = wave >> 1, pb = wave & 1;  // target (jy&1, jz&1)
    int cin = pairs * 2;
    for (int i = t; i < 64 * pairs; i += 256) Gs[i] = make_float2(0.f, 0.f);
    __syncthreads();
    const float2* feat2 = (const float2*)feat;
    bool act = lane < pairs;
    int e0 = row_ptr[q], e1 = row_ptr[q + 1];
    for (int e = e0; e < e1; e++) {
        int s = s_idx[e];
        uint2 cp = cells[e];
        int cell0 = (int)(cp.x & 255u);           // corner (ix,iy,iz)
        int cby = pa ^ ((cell0 >> 2) & 1);        // pick jy parity == pa
        int cbz = pb ^ (cell0 & 1);               // pick jz parity == pb
        int cA = cby * 2 + cbz;                   // cbx=0 corner (0..3)
        int cellA = (int)((cp.x >> (cA * 8)) & 255u);
        int cellB = (int)((cp.y >> (cA * 8)) & 255u);  // cbx=1 corner (cA+4)
        float wA = wgt[(size_t)e * 8 + cA];
        float wB = wgt[(size_t)e * 8 + cA + 4];
        if (act) {
            float2 fv = feat2[(size_t)s * pairs + lane];
            if (dorelu) { fv.x = fmaxf(fv.x, 0.f); fv.y = fmaxf(fv.y, 0.f); }
            float2 gA = Gs[cellA * pairs + lane];
            float2 gB = Gs[cellB * pairs + lane];
            gA.x += wA * fv.x; gA.y += wA * fv.y;
            gB.x += wB * fv.x; gB.y += wB * fv.y;
            Gs[cellA * pairs + lane] = gA;
            Gs[cellB * pairs + lane] = gB;
        }
    }
    __syncthreads();
    unsigned int* Go = (unsigned int*)(G + (size_t)lq * (size_t)(65 * cin));
    for (int i = t; i < 64 * pairs; i += 256) {
        float2 g = Gs[i];
        Go[i] = (unsigned int)f2bf(g.x) | ((unsigned int)f2bf(g.y) << 16);
    }
    if (wave == 0 && act) {
        float2 fq = feat2[(size_t)q * pairs + lane];
        if (dorelu) { fq.x = fmaxf(fq.x, 0.f); fq.y = fmaxf(fq.y, 0.f); }
        Go[64 * pairs + lane] = (unsigned int)f2bf(fq.x) | ((unsigned int)f2bf(fq.y) << 16);
    }
}

// bf16 MFMA GEMM, split-K atomics. A: [M][K] bf16 row-major; Wt: [64][K] bf16 (n-major).
__global__ __launch_bounds__(256) void gemm_mfma(
    const unsigned short* __restrict__ A, const unsigned short* __restrict__ Wt,
    float* __restrict__ C, int M, int K, int ldc, int kpb) {
    int wave = threadIdx.x >> 6, lane = threadIdx.x & 63;
    int m0 = blockIdx.x * 64;
    int kbeg = blockIdx.y * kpb;
    int kend = min(K, kbeg + kpb);
    int mrow = lane & 15, kq = lane >> 4;
    int n0 = wave * 16;
    const unsigned short* Bp = Wt + (size_t)(n0 + mrow) * K;
    float4v acc[4] = {{0.f, 0.f, 0.f, 0.f}, {0.f, 0.f, 0.f, 0.f},
                      {0.f, 0.f, 0.f, 0.f}, {0.f, 0.f, 0.f, 0.f}};
    int r0 = min(m0 + mrow, M - 1);
    int r1 = min(m0 + 16 + mrow, M - 1);
    int r2 = min(m0 + 32 + mrow, M - 1);
    int r3 = min(m0 + 48 + mrow, M - 1);
    const unsigned short* A0 = A + (size_t)r0 * K;
    const unsigned short* A1 = A + (size_t)r1 * K;
    const unsigned short* A2 = A + (size_t)r2 * K;
    const unsigned short* A3 = A + (size_t)r3 * K;
    for (int k0 = kbeg; k0 < kend; k0 += 32) {
        int kk = k0 + kq * 8;
        short8 b = *(const short8*)(Bp + kk);
        short8 a0 = *(const short8*)(A0 + kk);
        short8 a1 = *(const short8*)(A1 + kk);
        short8 a2 = *(const short8*)(A2 + kk);
        short8 a3 = *(const short8*)(A3 + kk);
        acc[0] = __builtin_amdgcn_mfma_f32_16x16x32_bf16(a0, b, acc[0], 0, 0, 0);
        acc[1] = __builtin_amdgcn_mfma_f32_16x16x32_bf16(a1, b, acc[1], 0, 0, 0);
        acc[2] = __builtin_amdgcn_mfma_f32_16x16x32_bf16(a2, b, acc[2], 0, 0, 0);
        acc[3] = __builtin_amdgcn_mfma_f32_16x16x32_bf16(a3, b, acc[3], 0, 0, 0);
    }
    int col = lane & 15, rq = lane >> 4;
#pragma unroll
    for (int mt = 0; mt < 4; mt++) {
#pragma unroll
        for (int r = 0; r < 4; r++) {
            int m = m0 + mt * 16 + rq * 4 + r;
            if (m < M) atomicAdd(&C[(size_t)m * ldc + n0 + col], acc[mt][r]);
        }
    }
}

// f32 split-K GEMM (layer 0 only, tiny K).
template <int BM, int BN, int BK, int TM, int TN>
__global__ void gemm_atomic(const float* __restrict__ A, const float* __restrict__ B,
                            float* __restrict__ C, int M, int N, int K,
                            int ldc, int coff, int kpb) {
    constexpr int THREADS = (BM / TM) * (BN / TN);
    __shared__ float As[BK][BM + 1];
    __shared__ float Bs[BK][BN + 1];
    int tx = threadIdx.x;
    int tcols = BN / TN;
    int tcol = tx % tcols, trow = tx / tcols;
    int m0 = blockIdx.x * BM;
    int kbeg = blockIdx.y * kpb;
    int kend = min(K, kbeg + kpb);
    float acc[TM][TN];
#pragma unroll
    for (int i = 0; i < TM; i++)
#pragma unroll
        for (int j = 0; j < TN; j++) acc[i][j] = 0.f;
    for (int k0 = kbeg; k0 < kend; k0 += BK) {
        for (int i = tx; i < BM * BK; i += THREADS) {
            int kk = i % BK, mm = i / BK;
            int m = m0 + mm, k = k0 + kk;
            As[kk][mm] = (m < M && k < K) ? A[(size_t)m * K + k] : 0.f;
        }
        for (int i = tx; i < BN * BK; i += THREADS) {
            int nn = i % BN, kk = i / BN;
            int k = k0 + kk;
            Bs[kk][nn] = (k < K && nn < N) ? B[(size_t)k * N + nn] : 0.f;
        }
        __syncthreads();
#pragma unroll
        for (int kk = 0; kk < BK; kk++) {
            float a[TM], b[TN];
#pragma unroll
            for (int i = 0; i < TM; i++) a[i] = As[kk][trow * TM + i];
#pragma unroll
            for (int j = 0; j < TN; j++) b[j] = Bs[kk][tcol * TN + j];
#pragma unroll
            for (int i = 0; i < TM; i++)
#pragma unroll
                for (int j = 0; j < TN; j++) acc[i][j] += a[i] * b[j];
        }
        __syncthreads();
    }
    for (int i = 0; i < TM; i++) {
        int m = m0 + trow * TM + i;
        if (m >= M) continue;
        for (int j = 0; j < TN; j++) {
            int nn = tcol * TN + j;
            if (nn >= N) continue;
            atomicAdd(&C[(size_t)m * ldc + coff + nn], acc[i][j]);
        }
    }
}

// Layer-3: y3[m,0..2] = A(bf16)[m,:] @ B(f32)[:,0..2] + bias.
__global__ void rowdot3_kernel(const unsigned short* __restrict__ A, const float* __restrict__ B,
                               const float* __restrict__ bias, int K, float* __restrict__ C) {
    int m = blockIdx.x;
    int t = threadIdx.x;
    const unsigned short* a = A + (size_t)m * K;
    float a0 = 0.f, a1 = 0.f, a2 = 0.f;
    for (int k = t; k < K; k += 256) {
        float av = bf2f(a[k]);
        a0 += av * B[k * 3 + 0];
        a1 += av * B[k * 3 + 1];
        a2 += av * B[k * 3 + 2];
    }
    __shared__ float red[3][256];
    red[0][t] = a0; red[1][t] = a1; red[2][t] = a2;
    __syncthreads();
    for (int s2 = 128; s2 > 0; s2 >>= 1) {
        if (t < s2) {
            red[0][t] += red[0][t + s2];
            red[1][t] += red[1][t + s2];
            red[2][t] += red[2][t + s2];
        }
        __syncthreads();
    }
    if (t < 3) C[(size_t)m * 3 + t] = red[t][0] + bias[t];
}

__global__ void final_kernel(const float* __restrict__ pos, const float* __restrict__ pos2,
                             const float* __restrict__ y3, int n, float* __restrict__ out) {
    int i = blockIdx.x * blockDim.x + threadIdx.x;
    if (i >= n * 3) return;
    float pn = pos2[i] + y3[i] * (1.f / 128.f);
    out[i] = pn;
    out[n * 3 + i] = (pn - pos[i]) * (1.f / DT_F);
}

extern "C" void kernel_launch(void* const* d_in, const int* in_sizes, int n_in,
                              void* d_out, int out_size, void* d_ws, size_t ws_size,
                              hipStream_t stream) {
    const float* pos       = (const float*)d_in[0];
    const float* vel       = (const float*)d_in[1];
    const float* box       = (const float*)d_in[2];
    const float* box_feats = (const float*)d_in[3];
    const int*   ff_q      = (const int*)d_in[4];
    const int*   ff_s      = (const int*)d_in[5];
    const int*   fo_q      = (const int*)d_in[6];
    const int*   fo_s      = (const int*)d_in[7];
    const float* w_cf0     = (const float*)d_in[8];
    const float* w_co0     = (const float*)d_in[9];
    const float* w_d0      = (const float*)d_in[10];
    const float* b_d0      = (const float*)d_in[11];
    const float* w_c1      = (const float*)d_in[12];
    const float* w_d1      = (const float*)d_in[13];
    const float* b_d1      = (const float*)d_in[14];
    const float* w_c2      = (const float*)d_in[15];
    const float* w_d2      = (const float*)d_in[16];
    const float* b_d2      = (const float*)d_in[17];
    const float* w_c3      = (const float*)d_in[18];
    const float* w_d3      = (const float*)d_in[19];
    const float* b_d3      = (const float*)d_in[20];
    float* out = (float*)d_out;

    int n   = in_sizes[0] / 3;
    int Eff = in_sizes[4];
    int Efo = in_sizes[6];

    float* base = (float*)d_ws;
    size_t off = 0;
    auto alloc = [&](size_t nf) { float* p = base + off; off += (nf + 3) & ~(size_t)3; return p; };
    float* pos2  = alloc((size_t)n * 3);
    float* fl    = alloc((size_t)n * 4);
    float* x96   = alloc((size_t)n * 96);
    float* x64a  = alloc((size_t)n * 64);
    float* x64b  = alloc((size_t)n * 64);
    float* y3    = alloc((size_t)n * 3);
    int* rp_ff   = (int*)alloc((size_t)n + 1);
    int* rp_fo   = (int*)alloc((size_t)n + 1);
    float* Wc    = alloc((size_t)65 * 96 * 64);            // f32 combined W (layer 3)
    unsigned short* Wt = (unsigned short*)alloc((size_t)65 * 96 * 64 / 2);  // bf16 Wt
    float* wgt_ff = alloc((size_t)Eff * 8);
    uint2* cl_ff  = (uint2*)alloc((size_t)Eff * 2);
    float* wgt_fo = alloc((size_t)Efo * 8);
    uint2* cl_fo  = (uint2*)alloc((size_t)Efo * 2);
    float* G = base + off;                                  // f32 view (layer 0)
    unsigned short* Gb = (unsigned short*)G;                // bf16 view (layers 1-3)

    size_t totalF = ws_size / sizeof(float);
    size_t availF = (totalF > off) ? (totalF - off) : 0;
    auto chunkQ = [&](size_t floatsPerQ) {
        long q = (long)(availF / floatsPerQ);
        if (q < 1) q = 1;
        if (q > n) q = n;
        return (int)q;
    };

    // --- prep, CSR, edge geometry (once) ---
    prep_kernel<<<cdiv(n, 256), 256, 0, stream>>>(pos, vel, n, pos2, fl);
    row_ptr_kernel<<<cdiv(n + 1, 256), 256, 0, stream>>>(ff_q, Eff, n, rp_ff);
    row_ptr_kernel<<<cdiv(n + 1, 256), 256, 0, stream>>>(fo_q, Efo, n, rp_fo);
    edge_geom_kernel<<<cdiv(Eff, 256), 256, 0, stream>>>(pos2, pos2, ff_q, ff_s, Eff, wgt_ff, cl_ff);
    edge_geom_kernel<<<cdiv(Efo, 256), 256, 0, stream>>>(pos2, box, fo_q, fo_s, Efo, wgt_fo, cl_fo);

    // --- layer 0 (f32 path, tiny K) ---
    init_out_kernel<<<cdiv(n * 64, 256), 256, 0, stream>>>(x96, nullptr, nullptr, n, 64, 96);
    dense0_kernel<<<cdiv(n * 32, 256), 256, 0, stream>>>(fl, w_d0, b_d0, n, x96);
    {
        int Q = chunkQ(64 * 4);
        for (int q0 = 0; q0 < n; q0 += Q) {
            int mc = std::min(Q, n - q0);
            build_G_small<<<mc, 64, 0, stream>>>(fl, 4, wgt_ff, cl_ff, ff_s, rp_ff, q0, G);
            gemm_atomic<64, 32, 16, 4, 2><<<dim3(cdiv(mc, 64), 2), 256, 0, stream>>>(
                G, w_cf0, x96 + (size_t)q0 * 96, mc, 32, 256, 96, 32, 8 * 16);
        }
    }
    {
        int Q = chunkQ(64 * 3);
        for (int q0 = 0; q0 < n; q0 += Q) {
            int mc = std::min(Q, n - q0);
            build_G_small<<<mc, 64, 0, stream>>>(box_feats, 3, wgt_fo, cl_fo, fo_s, rp_fo, q0, G);
            gemm_atomic<64, 32, 16, 4, 2><<<dim3(cdiv(mc, 64), 2), 256, 0, stream>>>(
                G, w_co0, x96 + (size_t)q0 * 96, mc, 32, 192, 96, 0, 6 * 16);
        }
    }

    // --- layer 1: 96 -> 64, bf16 MFMA (relu fused into build) ---
    {
        const int K = 65 * 96;
        wt_kernel<<<cdiv(64 * K, 256), 256, 0, stream>>>(w_c1, w_d1, 96, 64, K, Wt);
        init_out_kernel<<<cdiv(n * 64, 256), 256, 0, stream>>>(x64a, b_d1, nullptr, n, 64, 64);
        int Q = chunkQ((size_t)K / 2);
        for (int q0 = 0; q0 < n; q0 += Q) {
            int mc = std::min(Q, n - q0);
            build_G_big<<<mc, 256, 64 * 48 * 8, stream>>>(
                x96, 48, wgt_ff, cl_ff, ff_s, rp_ff, x96, q0, 1, Gb);
            gemm_mfma<<<dim3(cdiv(mc, 64), 4), 256, 0, stream>>>(
                Gb, Wt, x64a + (size_t)q0 * 64, mc, K, 64, cdiv(K / 32, 4) * 32);
        }
    }

    // --- layer 2: 64 -> 64, residual, bf16 MFMA ---
    {
        const int K = 65 * 64;
        wt_kernel<<<cdiv(64 * K, 256), 256, 0, stream>>>(w_c2, w_d2, 64, 64, K, Wt);
        init_out_kernel<<<cdiv(n * 64, 256), 256, 0, stream>>>(x64b, b_d2, x64a, n, 64, 64);
        int Q = chunkQ((size_t)K / 2);
        for (int q0 = 0; q0 < n; q0 += Q) {
            int mc = std::min(Q, n - q0);
            build_G_big<<<mc, 256, 64 * 32 * 8, stream>>>(
                x64a, 32, wgt_ff, cl_ff, ff_s, rp_ff, x64a, q0, 1, Gb);
            gemm_mfma<<<dim3(cdiv(mc, 64), 4), 256, 0, stream>>>(
                Gb, Wt, x64b + (size_t)q0 * 64, mc, K, 64, cdiv(K / 32, 4) * 32);
        }
    }

    // --- layer 3: 64 -> 3 ---
    {
        const int K = 65 * 64;
        hipMemcpyAsync(Wc, w_c3, sizeof(float) * 64 * 64 * 3, hipMemcpyDeviceToDevice, stream);
        hipMemcpyAsync(Wc + 64 * 64 * 3, w_d3, sizeof(float) * 64 * 3, hipMemcpyDeviceToDevice, stream);
        int Q = chunkQ((size_t)K / 2);
        for (int q0 = 0; q0 < n; q0 += Q) {
            int mc = std::min(Q, n - q0);
            build_G_big<<<mc, 256, 64 * 32 * 8, stream>>>(
                x64b, 32, wgt_ff, cl_ff, ff_s, rp_ff, x64b, q0, 1, Gb);
            rowdot3_kernel<<<mc, 256, 0, stream>>>(Gb, Wc, b_d3, K, y3 + (size_t)q0 * 3);
        }
    }

    final_kernel<<<cdiv(n * 3, 256), 256, 0, stream>>>(pos, pos2, y3, n, out);
}

// Round 5
// 1533.372 us; speedup vs baseline: 5.8600x; 1.0040x over previous
//
#include <hip/hip_runtime.h>
#include <algorithm>

#define DT_F 0.02f
#define INV_R (1.0f / 0.1125f)

typedef __attribute__((ext_vector_type(8))) short short8;
typedef __attribute__((ext_vector_type(4))) float float4v;

static inline int cdiv(int a, int b) { return (a + b - 1) / b; }

__device__ __forceinline__ float sgnf(float v) {
    return (v > 0.f) ? 1.f : ((v < 0.f) ? -1.f : 0.f);
}

__device__ __forceinline__ unsigned short f2bf(float f) {
    union { float f; unsigned u; } v; v.f = f;
    return (unsigned short)((v.u + 0x7fffu + ((v.u >> 16) & 1u)) >> 16);
}
__device__ __forceinline__ float bf2f(unsigned short h) {
    union { unsigned u; float f; } v; v.u = ((unsigned)h) << 16;
    return v.f;
}

// Exact port of reference ball_to_cube (f32).
__device__ __forceinline__ void ball_to_cube_dev(float x, float y, float z,
                                                 float& ox, float& oy, float& oz) {
    const float eps = 1e-12f;
    float sq = x * x + y * y + z * z;
    float nrm = sqrtf(sq + eps);
    float xy2 = x * x + y * y;
    bool cap = 1.25f * z * z > xy2;
    float s_cap = sqrtf(3.f * nrm / (nrm + fabsf(z) + eps));
    float s_side = nrm / sqrtf(xy2 + eps);
    float s = cap ? s_cap : s_side;
    float xc = x * s, yc = y * s;
    float zc = cap ? sgnf(z) * nrm : 1.5f * z;
    if (!(sq > eps)) { xc = 0.f; yc = 0.f; zc = 0.f; }
    float rxy = sqrtf(xc * xc + yc * yc + eps);
    bool xbig = fabsf(yc) <= fabsf(xc);
    float dx = (fabsf(xc) > eps) ? xc : 1.f;
    float dy = (fabsf(yc) > eps) ? yc : 1.f;
    const float c4pi = 1.27323954473516276f;  // 4/pi
    float tx = sgnf(xc) * rxy, ty = sgnf(yc) * rxy;
    float xq = xbig ? tx : ty * c4pi * atanf(xc / dy);
    float yq = xbig ? tx * c4pi * atanf(yc / dx) : ty;
    if (!(xc * xc + yc * yc > eps)) { xq = 0.f; yq = 0.f; }
    ox = xq; oy = yq; oz = zc;
}

__global__ void prep_kernel(const float* __restrict__ pos, const float* __restrict__ vel,
                            int n, float* __restrict__ pos2, float* __restrict__ fl) {
    int i = blockIdx.x * blockDim.x + threadIdx.x;
    if (i >= n) return;
    float v0 = vel[i * 3 + 0], v1 = vel[i * 3 + 1], v2 = vel[i * 3 + 2];
    float u0 = v0, u1 = v1 + DT_F * (-9.81f), u2 = v2;
    pos2[i * 3 + 0] = pos[i * 3 + 0] + DT_F * (u0 + v0) * 0.5f;
    pos2[i * 3 + 1] = pos[i * 3 + 1] + DT_F * (u1 + v1) * 0.5f;
    pos2[i * 3 + 2] = pos[i * 3 + 2] + DT_F * (u2 + v2) * 0.5f;
    fl[i * 4 + 0] = 1.f;
    fl[i * 4 + 1] = u0;
    fl[i * 4 + 2] = u1;
    fl[i * 4 + 3] = u2;
}

__global__ void row_ptr_kernel(const int* __restrict__ q_idx, int E, int nq,
                               int* __restrict__ row_ptr) {
    int q = blockIdx.x * blockDim.x + threadIdx.x;
    if (q > nq) return;
    int lo = 0, hi = E;
    while (lo < hi) {
        int mid = (lo + hi) >> 1;
        if (q_idx[mid] < q) lo = mid + 1; else hi = mid;
    }
    row_ptr[q] = lo;
}

// Per-edge geometry once; ix clamped to [0,2] => 8 distinct corners (no RMW aliasing).
// Outputs: wgt[e][8], cells[e] (8 packed bytes), and (optional, ff only) per-parity-class
// records edata[class][e] = {wA, wB, cellA|cellB<<8, s} so the build loop is pure loads.
__global__ void edge_geom_kernel(const float* __restrict__ posq, const float* __restrict__ poss,
                                 const int* __restrict__ q_idx, const int* __restrict__ s_idx,
                                 int E, float* __restrict__ wgt, uint2* __restrict__ cells,
                                 uint4* __restrict__ edata) {
    int e = blockIdx.x * blockDim.x + threadIdx.x;
    if (e >= E) return;
    int q = q_idx[e], s = s_idx[e];
    float dx = (poss[s * 3 + 0] - posq[q * 3 + 0]) * INV_R;
    float dy = (poss[s * 3 + 1] - posq[q * 3 + 1]) * INV_R;
    float dz = (poss[s * 3 + 2] - posq[q * 3 + 2]) * INV_R;
    float r2 = dx * dx + dy * dy + dz * dz;
    float w1 = 1.f - r2;
    float win = fminf(fmaxf(w1 * w1 * w1, 0.f), 1.f);
    float bx, by, bz;
    ball_to_cube_dev(dx, dy, dz, bx, by, bz);
    float gx = (bx + 1.f) * 1.5f, gy = (by + 1.f) * 1.5f, gz = (bz + 1.f) * 1.5f;
    int ix = min(max((int)floorf(gx), 0), 2);
    int iy = min(max((int)floorf(gy), 0), 2);
    int iz = min(max((int)floorf(gz), 0), 2);
    float fx = gx - (float)ix, fy = gy - (float)iy, fz = gz - (float)iz;
    float wv[8];
    unsigned int cl[8];
#pragma unroll
    for (int c = 0; c < 8; c++) {
        int cbx = (c >> 2) & 1, cby = (c >> 1) & 1, cbz = c & 1;
        int jx = ix + cbx, jy = iy + cby, jz = iz + cbz;
        cl[c] = (unsigned int)((jx * 4 + jy) * 4 + jz);
        wv[c] = win * (cbx ? fx : 1.f - fx) * (cby ? fy : 1.f - fy) * (cbz ? fz : 1.f - fz);
    }
    float4* wp = (float4*)(wgt + (size_t)e * 8);
    wp[0] = make_float4(wv[0], wv[1], wv[2], wv[3]);
    wp[1] = make_float4(wv[4], wv[5], wv[6], wv[7]);
    uint2 cp;
    cp.x = cl[0] | (cl[1] << 8) | (cl[2] << 16) | (cl[3] << 24);
    cp.y = cl[4] | (cl[5] << 8) | (cl[6] << 16) | (cl[7] << 24);
    cells[e] = cp;
    if (edata) {
#pragma unroll
        for (int w = 0; w < 4; w++) {
            int pa = w >> 1, pb = w & 1;
            int cby = pa ^ (iy & 1), cbz = pb ^ (iz & 1);
            int cA = cby * 2 + cbz;
            uint4 d;
            d.x = __float_as_uint(wv[cA]);
            d.y = __float_as_uint(wv[cA + 4]);
            d.z = cl[cA] | (cl[cA + 4] << 8);
            d.w = (unsigned)s;
            edata[(size_t)w * E + e] = d;
        }
    }
}

// a_df = fl @ w_d0 + b_d0 -> x96[:, 64:96]
__global__ void dense0_kernel(const float* __restrict__ fl, const float* __restrict__ w,
                              const float* __restrict__ b, int n, float* __restrict__ x96) {
    int i = blockIdx.x * blockDim.x + threadIdx.x;
    if (i >= n * 32) return;
    int q = i >> 5, o = i & 31;
    float acc = b[o];
#pragma unroll
    for (int c = 0; c < 4; c++) acc += fl[q * 4 + c] * w[c * 32 + o];
    x96[(size_t)q * 96 + 64 + o] = acc;
}

// C[q,o] = bias[o] (+resid[q,o]); zero if bias null (pre-init for atomic split-K).
__global__ void init_out_kernel(float* __restrict__ C, const float* __restrict__ bias,
                                const float* __restrict__ resid, int n, int co, int ldc) {
    int i = blockIdx.x * blockDim.x + threadIdx.x;
    if (i >= n * co) return;
    int q = i / co, o = i - q * co;
    float v = bias ? bias[o] : 0.f;
    if (resid) v += resid[(size_t)q * ldc + o];
    C[(size_t)q * ldc + o] = v;
}

// Wt[n][k] = bf16(W[k][n]) with W = [w_c (64*ci rows) ; w_d (ci rows)], K = 65*ci.
__global__ void wt_kernel(const float* __restrict__ wc, const float* __restrict__ wd,
                          int ci, int co, int K, unsigned short* __restrict__ Wt) {
    int i = blockIdx.x * blockDim.x + threadIdx.x;
    if (i >= co * K) return;
    int n = i / K, k = i - n * K;
    float v = (k < 64 * ci) ? wc[(size_t)k * co + n] : wd[(size_t)(k - 64 * ci) * co + n];
    Wt[i] = f2bf(v);
}

// Wt3[j=cell*3+o][k] = bf16(w_c3[cell][k][o]); 192 rows x 64 cols.
__global__ void wt3_kernel(const float* __restrict__ wc, unsigned short* __restrict__ Wt) {
    int i = blockIdx.x * blockDim.x + threadIdx.x;
    if (i >= 192 * 64) return;
    int j = i >> 6, k = i & 63;
    int cell = j / 3, o = j - cell * 3;
    Wt[i] = f2bf(wc[((size_t)cell * 64 + k) * 3 + o]);
}

// h = bf16(relu(x)), flat n elems.
__global__ void relu_bf16_kernel(const float* __restrict__ x, int n,
                                 unsigned short* __restrict__ h) {
    int i = blockIdx.x * blockDim.x + threadIdx.x;
    if (i < n) h[i] = f2bf(fmaxf(x[i], 0.f));
}

// Small-cin (layer 0) G build: f32 G out [Q][64][cin].
__global__ __launch_bounds__(64) void build_G_small(
    const float* __restrict__ feat, int cin,
    const float* __restrict__ wgt, const uint2* __restrict__ cells,
    const int* __restrict__ s_idx, const int* __restrict__ row_ptr, int q0,
    float* __restrict__ G) {
    __shared__ float Gs[8 * 64 * 8];
    int lq = blockIdx.x, q = q0 + lq, t = threadIdx.x;
    int r = t >> 3, ch = t & 7;
    for (int i = t; i < 4096; i += 64) Gs[i] = 0.f;
    __syncthreads();
    int e0 = row_ptr[q], e1 = row_ptr[q + 1];
    for (int e = e0; e < e1; e++) {
        int s = s_idx[e];
        float w = wgt[(size_t)e * 8 + r];
        uint2 cp = cells[e];
        unsigned int word = (r < 4) ? cp.x : cp.y;
        int cell = (int)((word >> ((r & 3) * 8)) & 255u);
        float fv = (ch < cin) ? feat[(size_t)s * cin + ch] : 0.f;
        Gs[(r * 64 + cell) * 8 + ch] += w * fv;
    }
    __syncthreads();
    size_t base = (size_t)lq * 64 * cin;
    for (int i = t; i < 64 * cin; i += 64) {
        int cell = i / cin, c = i - cell * cin;
        float acc = 0.f;
#pragma unroll
        for (int rr = 0; rr < 8; rr++) acc += Gs[(rr * 64 + cell) * 8 + c];
        G[base + i] = acc;
    }
}

// Big-cin G build, 4 waves, parity-partitioned corners (class = (jy&1)*2+(jz&1):
// exactly 2 corners/edge/class, classes partition the 64 cells => no cross-wave races).
// Inner loop consumes precomputed per-class records: {wA,wB,cells,s} = 1 uniform 16B load.
// G out bf16 [Q][65][cin]; slot 64 = featq[q]; optional fused ReLU.
__global__ __launch_bounds__(256) void build_G_big(
    const float* __restrict__ feat, int pairs,  // pairs = cin/2
    const uint4* __restrict__ edata, int E,
    const int* __restrict__ row_ptr,
    const float* __restrict__ featq, int q0, int dorelu,
    unsigned short* __restrict__ G) {
    extern __shared__ float2 Gs[];  // [64][pairs]
    int lq = blockIdx.x, q = q0 + lq, t = threadIdx.x;
    int wave = t >> 6, lane = t & 63;
    int cin = pairs * 2;
    for (int i = t; i < 64 * pairs; i += 256) Gs[i] = make_float2(0.f, 0.f);
    __syncthreads();
    const float2* feat2 = (const float2*)feat;
    bool act = lane < pairs;
    int e0 = row_ptr[q], e1 = row_ptr[q + 1];
    const uint4* ed = edata + (size_t)wave * E;
    for (int e = e0; e < e1; e++) {
        uint4 d = ed[e];
        if (act) {
            float wA = __uint_as_float(d.x), wB = __uint_as_float(d.y);
            int cellA = (int)(d.z & 255u), cellB = (int)((d.z >> 8) & 255u);
            float2 fv = feat2[(size_t)d.w * pairs + lane];
            if (dorelu) { fv.x = fmaxf(fv.x, 0.f); fv.y = fmaxf(fv.y, 0.f); }
            float2 gA = Gs[cellA * pairs + lane];
            float2 gB = Gs[cellB * pairs + lane];
            gA.x += wA * fv.x; gA.y += wA * fv.y;
            gB.x += wB * fv.x; gB.y += wB * fv.y;
            Gs[cellA * pairs + lane] = gA;
            Gs[cellB * pairs + lane] = gB;
        }
    }
    __syncthreads();
    unsigned int* Go = (unsigned int*)(G + (size_t)lq * (size_t)(65 * cin));
    for (int i = t; i < 64 * pairs; i += 256) {
        float2 g = Gs[i];
        Go[i] = (unsigned int)f2bf(g.x) | ((unsigned int)f2bf(g.y) << 16);
    }
    if (wave == 0 && act) {
        float2 fq = feat2[(size_t)q * pairs + lane];
        if (dorelu) { fq.x = fmaxf(fq.x, 0.f); fq.y = fmaxf(fq.y, 0.f); }
        Go[64 * pairs + lane] = (unsigned int)f2bf(fq.x) | ((unsigned int)f2bf(fq.y) << 16);
    }
}

// bf16 MFMA GEMM, split-K atomics. A: [M][K] bf16 row-major; Wt: [64][K] bf16 (n-major).
__global__ __launch_bounds__(256) void gemm_mfma(
    const unsigned short* __restrict__ A, const unsigned short* __restrict__ Wt,
    float* __restrict__ C, int M, int K, int ldc, int kpb) {
    int wave = threadIdx.x >> 6, lane = threadIdx.x & 63;
    int m0 = blockIdx.x * 64;
    int kbeg = blockIdx.y * kpb;
    int kend = min(K, kbeg + kpb);
    int mrow = lane & 15, kq = lane >> 4;
    int n0 = wave * 16;
    const unsigned short* Bp = Wt + (size_t)(n0 + mrow) * K;
    float4v acc[4] = {{0.f, 0.f, 0.f, 0.f}, {0.f, 0.f, 0.f, 0.f},
                      {0.f, 0.f, 0.f, 0.f}, {0.f, 0.f, 0.f, 0.f}};
    int r0 = min(m0 + mrow, M - 1);
    int r1 = min(m0 + 16 + mrow, M - 1);
    int r2 = min(m0 + 32 + mrow, M - 1);
    int r3 = min(m0 + 48 + mrow, M - 1);
    const unsigned short* A0 = A + (size_t)r0 * K;
    const unsigned short* A1 = A + (size_t)r1 * K;
    const unsigned short* A2 = A + (size_t)r2 * K;
    const unsigned short* A3 = A + (size_t)r3 * K;
    for (int k0 = kbeg; k0 < kend; k0 += 32) {
        int kk = k0 + kq * 8;
        short8 b = *(const short8*)(Bp + kk);
        short8 a0 = *(const short8*)(A0 + kk);
        short8 a1 = *(const short8*)(A1 + kk);
        short8 a2 = *(const short8*)(A2 + kk);
        short8 a3 = *(const short8*)(A3 + kk);
        acc[0] = __builtin_amdgcn_mfma_f32_16x16x32_bf16(a0, b, acc[0], 0, 0, 0);
        acc[1] = __builtin_amdgcn_mfma_f32_16x16x32_bf16(a1, b, acc[1], 0, 0, 0);
        acc[2] = __builtin_amdgcn_mfma_f32_16x16x32_bf16(a2, b, acc[2], 0, 0, 0);
        acc[3] = __builtin_amdgcn_mfma_f32_16x16x32_bf16(a3, b, acc[3], 0, 0, 0);
    }
    int col = lane & 15, rq = lane >> 4;
#pragma unroll
    for (int mt = 0; mt < 4; mt++) {
#pragma unroll
        for (int r = 0; r < 4; r++) {
            int m = m0 + mt * 16 + rq * 4 + r;
            if (m < M) atomicAdd(&C[(size_t)m * ldc + n0 + col], acc[mt][r]);
        }
    }
}

// bf16 MFMA GEMM, direct store, N-tiled via blockIdx.y (64 outputs per tile), full K.
__global__ __launch_bounds__(256) void gemm_mfma_store(
    const unsigned short* __restrict__ A, const unsigned short* __restrict__ Wt,
    float* __restrict__ C, int M, int K, int ldc) {
    int wave = threadIdx.x >> 6, lane = threadIdx.x & 63;
    int m0 = blockIdx.x * 64;
    int n0 = blockIdx.y * 64 + wave * 16;
    int mrow = lane & 15, kq = lane >> 4;
    const unsigned short* Bp = Wt + (size_t)(n0 + mrow) * K;
    float4v acc[4] = {{0.f, 0.f, 0.f, 0.f}, {0.f, 0.f, 0.f, 0.f},
                      {0.f, 0.f, 0.f, 0.f}, {0.f, 0.f, 0.f, 0.f}};
    int r0 = min(m0 + mrow, M - 1);
    int r1 = min(m0 + 16 + mrow, M - 1);
    int r2 = min(m0 + 32 + mrow, M - 1);
    int r3 = min(m0 + 48 + mrow, M - 1);
    const unsigned short* A0 = A + (size_t)r0 * K;
    const unsigned short* A1 = A + (size_t)r1 * K;
    const unsigned short* A2 = A + (size_t)r2 * K;
    const unsigned short* A3 = A + (size_t)r3 * K;
    for (int k0 = 0; k0 < K; k0 += 32) {
        int kk = k0 + kq * 8;
        short8 b = *(const short8*)(Bp + kk);
        short8 a0 = *(const short8*)(A0 + kk);
        short8 a1 = *(const short8*)(A1 + kk);
        short8 a2 = *(const short8*)(A2 + kk);
        short8 a3 = *(const short8*)(A3 + kk);
        acc[0] = __builtin_amdgcn_mfma_f32_16x16x32_bf16(a0, b, acc[0], 0, 0, 0);
        acc[1] = __builtin_amdgcn_mfma_f32_16x16x32_bf16(a1, b, acc[1], 0, 0, 0);
        acc[2] = __builtin_amdgcn_mfma_f32_16x16x32_bf16(a2, b, acc[2], 0, 0, 0);
        acc[3] = __builtin_amdgcn_mfma_f32_16x16x32_bf16(a3, b, acc[3], 0, 0, 0);
    }
    int col = lane & 15, rq = lane >> 4;
#pragma unroll
    for (int mt = 0; mt < 4; mt++) {
#pragma unroll
        for (int r = 0; r < 4; r++) {
            int m = m0 + mt * 16 + rq * 4 + r;
            if (m < M) C[(size_t)m * ldc + n0 + col] = acc[mt][r];
        }
    }
}

// Layer 3: y3[q] = sum_edges sum_corners w * P[s][cell*3+o] + relu(x64b[q])@w_d3 + b_d3.
// One wave per query, lane-per-edge; P: [n][192] f32.
__global__ __launch_bounds__(256) void conv3_reduce(
    const float* __restrict__ P,
    const float* __restrict__ wgt, const uint2* __restrict__ cells,
    const int* __restrict__ s_idx, const int* __restrict__ row_ptr,
    const unsigned short* __restrict__ hq, const float* __restrict__ wd3,
    const float* __restrict__ b3, int n, float* __restrict__ y3) {
    int wave = threadIdx.x >> 6, lane = threadIdx.x & 63;
    int q = blockIdx.x * 4 + wave;
    if (q >= n) return;
    float a0 = 0.f, a1 = 0.f, a2 = 0.f;
    int e0 = row_ptr[q], e1 = row_ptr[q + 1];
    for (int e = e0 + lane; e < e1; e += 64) {
        int s = s_idx[e];
        uint2 cp = cells[e];
        const float4* wp = (const float4*)(wgt + (size_t)e * 8);
        float4 wa = wp[0], wb = wp[1];
        const float* Ps = P + (size_t)s * 192;
        float wv[8] = {wa.x, wa.y, wa.z, wa.w, wb.x, wb.y, wb.z, wb.w};
#pragma unroll
        for (int c = 0; c < 8; c++) {
            unsigned word = (c < 4) ? cp.x : cp.y;
            int cell = (int)((word >> ((c & 3) * 8)) & 255u);
            const float* pc = Ps + cell * 3;
            a0 += wv[c] * pc[0];
            a1 += wv[c] * pc[1];
            a2 += wv[c] * pc[2];
        }
    }
    // dense term: lane = channel
    float hv = bf2f(hq[(size_t)q * 64 + lane]);
    a0 += hv * wd3[lane * 3 + 0];
    a1 += hv * wd3[lane * 3 + 1];
    a2 += hv * wd3[lane * 3 + 2];
#pragma unroll
    for (int off = 32; off > 0; off >>= 1) {
        a0 += __shfl_xor(a0, off);
        a1 += __shfl_xor(a1, off);
        a2 += __shfl_xor(a2, off);
    }
    if (lane == 0) {
        y3[(size_t)q * 3 + 0] = a0 + b3[0];
        y3[(size_t)q * 3 + 1] = a1 + b3[1];
        y3[(size_t)q * 3 + 2] = a2 + b3[2];
    }
}

// f32 split-K GEMM (layer 0 only, tiny K).
template <int BM, int BN, int BK, int TM, int TN>
__global__ void gemm_atomic(const float* __restrict__ A, const float* __restrict__ B,
                            float* __restrict__ C, int M, int N, int K,
                            int ldc, int coff, int kpb) {
    constexpr int THREADS = (BM / TM) * (BN / TN);
    __shared__ float As[BK][BM + 1];
    __shared__ float Bs[BK][BN + 1];
    int tx = threadIdx.x;
    int tcols = BN / TN;
    int tcol = tx % tcols, trow = tx / tcols;
    int m0 = blockIdx.x * BM;
    int kbeg = blockIdx.y * kpb;
    int kend = min(K, kbeg + kpb);
    float acc[TM][TN];
#pragma unroll
    for (int i = 0; i < TM; i++)
#pragma unroll
        for (int j = 0; j < TN; j++) acc[i][j] = 0.f;
    for (int k0 = kbeg; k0 < kend; k0 += BK) {
        for (int i = tx; i < BM * BK; i += THREADS) {
            int kk = i % BK, mm = i / BK;
            int m = m0 + mm, k = k0 + kk;
            As[kk][mm] = (m < M && k < K) ? A[(size_t)m * K + k] : 0.f;
        }
        for (int i = tx; i < BN * BK; i += THREADS) {
            int nn = i % BN, kk = i / BN;
            int k = k0 + kk;
            Bs[kk][nn] = (k < K && nn < N) ? B[(size_t)k * N + nn] : 0.f;
        }
        __syncthreads();
#pragma unroll
        for (int kk = 0; kk < BK; kk++) {
            float a[TM], b[TN];
#pragma unroll
            for (int i = 0; i < TM; i++) a[i] = As[kk][trow * TM + i];
#pragma unroll
            for (int j = 0; j < TN; j++) b[j] = Bs[kk][tcol * TN + j];
#pragma unroll
            for (int i = 0; i < TM; i++)
#pragma unroll
                for (int j = 0; j < TN; j++) acc[i][j] += a[i] * b[j];
        }
        __syncthreads();
    }
    for (int i = 0; i < TM; i++) {
        int m = m0 + trow * TM + i;
        if (m >= M) continue;
        for (int j = 0; j < TN; j++) {
            int nn = tcol * TN + j;
            if (nn >= N) continue;
            atomicAdd(&C[(size_t)m * ldc + coff + nn], acc[i][j]);
        }
    }
}

__global__ void final_kernel(const float* __restrict__ pos, const float* __restrict__ pos2,
                             const float* __restrict__ y3, int n, float* __restrict__ out) {
    int i = blockIdx.x * blockDim.x + threadIdx.x;
    if (i >= n * 3) return;
    float pn = pos2[i] + y3[i] * (1.f / 128.f);
    out[i] = pn;
    out[n * 3 + i] = (pn - pos[i]) * (1.f / DT_F);
}

extern "C" void kernel_launch(void* const* d_in, const int* in_sizes, int n_in,
                              void* d_out, int out_size, void* d_ws, size_t ws_size,
                              hipStream_t stream) {
    const float* pos       = (const float*)d_in[0];
    const float* vel       = (const float*)d_in[1];
    const float* box       = (const float*)d_in[2];
    const float* box_feats = (const float*)d_in[3];
    const int*   ff_q      = (const int*)d_in[4];
    const int*   ff_s      = (const int*)d_in[5];
    const int*   fo_q      = (const int*)d_in[6];
    const int*   fo_s      = (const int*)d_in[7];
    const float* w_cf0     = (const float*)d_in[8];
    const float* w_co0     = (const float*)d_in[9];
    const float* w_d0      = (const float*)d_in[10];
    const float* b_d0      = (const float*)d_in[11];
    const float* w_c1      = (const float*)d_in[12];
    const float* w_d1      = (const float*)d_in[13];
    const float* b_d1      = (const float*)d_in[14];
    const float* w_c2      = (const float*)d_in[15];
    const float* w_d2      = (const float*)d_in[16];
    const float* b_d2      = (const float*)d_in[17];
    const float* w_c3      = (const float*)d_in[18];
    const float* w_d3      = (const float*)d_in[19];
    const float* b_d3      = (const float*)d_in[20];
    float* out = (float*)d_out;

    int n   = in_sizes[0] / 3;
    int Eff = in_sizes[4];
    int Efo = in_sizes[6];

    float* base = (float*)d_ws;
    size_t off = 0;
    auto alloc = [&](size_t nf) { float* p = base + off; off += (nf + 3) & ~(size_t)3; return p; };
    float* pos2  = alloc((size_t)n * 3);
    float* fl    = alloc((size_t)n * 4);
    float* x96   = alloc((size_t)n * 96);
    float* x64a  = alloc((size_t)n * 64);
    float* x64b  = alloc((size_t)n * 64);
    float* y3    = alloc((size_t)n * 3);
    int* rp_ff   = (int*)alloc((size_t)n + 1);
    int* rp_fo   = (int*)alloc((size_t)n + 1);
    unsigned short* Wt  = (unsigned short*)alloc((size_t)65 * 96 * 64 / 2);
    unsigned short* Wt3 = (unsigned short*)alloc((size_t)192 * 64 / 2);
    unsigned short* xbr = (unsigned short*)alloc((size_t)n * 64 / 2);
    float* P     = alloc((size_t)n * 192);
    float* wgt_ff = alloc((size_t)Eff * 8);
    uint2* cl_ff  = (uint2*)alloc((size_t)Eff * 2);
    float* wgt_fo = alloc((size_t)Efo * 8);
    uint2* cl_fo  = (uint2*)alloc((size_t)Efo * 2);
    uint4* ed_ff  = (uint4*)alloc((size_t)Eff * 16);
    float* G = base + off;                                  // f32 view (layer 0)
    unsigned short* Gb = (unsigned short*)G;                // bf16 view (layers 1-2)

    size_t totalF = ws_size / sizeof(float);
    size_t availF = (totalF > off) ? (totalF - off) : 0;
    auto chunkQ = [&](size_t floatsPerQ) {
        long q = (long)(availF / floatsPerQ);
        if (q < 1) q = 1;
        if (q > n) q = n;
        return (int)q;
    };

    // --- prep, CSR, edge geometry (once) ---
    prep_kernel<<<cdiv(n, 256), 256, 0, stream>>>(pos, vel, n, pos2, fl);
    row_ptr_kernel<<<cdiv(n + 1, 256), 256, 0, stream>>>(ff_q, Eff, n, rp_ff);
    row_ptr_kernel<<<cdiv(n + 1, 256), 256, 0, stream>>>(fo_q, Efo, n, rp_fo);
    edge_geom_kernel<<<cdiv(Eff, 256), 256, 0, stream>>>(pos2, pos2, ff_q, ff_s, Eff, wgt_ff, cl_ff, ed_ff);
    edge_geom_kernel<<<cdiv(Efo, 256), 256, 0, stream>>>(pos2, box, fo_q, fo_s, Efo, wgt_fo, cl_fo, nullptr);

    // --- layer 0 (f32 path, tiny K) ---
    init_out_kernel<<<cdiv(n * 64, 256), 256, 0, stream>>>(x96, nullptr, nullptr, n, 64, 96);
    dense0_kernel<<<cdiv(n * 32, 256), 256, 0, stream>>>(fl, w_d0, b_d0, n, x96);
    {
        int Q = chunkQ(64 * 4);
        for (int q0 = 0; q0 < n; q0 += Q) {
            int mc = std::min(Q, n - q0);
            build_G_small<<<mc, 64, 0, stream>>>(fl, 4, wgt_ff, cl_ff, ff_s, rp_ff, q0, G);
            gemm_atomic<64, 32, 16, 4, 2><<<dim3(cdiv(mc, 64), 2), 256, 0, stream>>>(
                G, w_cf0, x96 + (size_t)q0 * 96, mc, 32, 256, 96, 32, 8 * 16);
        }
    }
    {
        int Q = chunkQ(64 * 3);
        for (int q0 = 0; q0 < n; q0 += Q) {
            int mc = std::min(Q, n - q0);
            build_G_small<<<mc, 64, 0, stream>>>(box_feats, 3, wgt_fo, cl_fo, fo_s, rp_fo, q0, G);
            gemm_atomic<64, 32, 16, 4, 2><<<dim3(cdiv(mc, 64), 2), 256, 0, stream>>>(
                G, w_co0, x96 + (size_t)q0 * 96, mc, 32, 192, 96, 0, 6 * 16);
        }
    }

    // --- layer 1: 96 -> 64, bf16 MFMA (relu fused into build) ---
    {
        const int K = 65 * 96;
        wt_kernel<<<cdiv(64 * K, 256), 256, 0, stream>>>(w_c1, w_d1, 96, 64, K, Wt);
        init_out_kernel<<<cdiv(n * 64, 256), 256, 0, stream>>>(x64a, b_d1, nullptr, n, 64, 64);
        int Q = chunkQ((size_t)K / 2);
        for (int q0 = 0; q0 < n; q0 += Q) {
            int mc = std::min(Q, n - q0);
            build_G_big<<<mc, 256, 64 * 48 * 8, stream>>>(
                x96, 48, ed_ff, Eff, rp_ff, x96, q0, 1, Gb);
            gemm_mfma<<<dim3(cdiv(mc, 64), 4), 256, 0, stream>>>(
                Gb, Wt, x64a + (size_t)q0 * 64, mc, K, 64, cdiv(K / 32, 4) * 32);
        }
    }

    // --- layer 2: 64 -> 64, residual, bf16 MFMA ---
    {
        const int K = 65 * 64;
        wt_kernel<<<cdiv(64 * K, 256), 256, 0, stream>>>(w_c2, w_d2, 64, 64, K, Wt);
        init_out_kernel<<<cdiv(n * 64, 256), 256, 0, stream>>>(x64b, b_d2, x64a, n, 64, 64);
        int Q = chunkQ((size_t)K / 2);
        for (int q0 = 0; q0 < n; q0 += Q) {
            int mc = std::min(Q, n - q0);
            build_G_big<<<mc, 256, 64 * 32 * 8, stream>>>(
                x64a, 32, ed_ff, Eff, rp_ff, x64a, q0, 1, Gb);
            gemm_mfma<<<dim3(cdiv(mc, 64), 4), 256, 0, stream>>>(
                Gb, Wt, x64b + (size_t)q0 * 64, mc, K, 64, cdiv(K / 32, 4) * 32);
        }
    }

    // --- layer 3: 64 -> 3 via P-trick (no G build) ---
    {
        relu_bf16_kernel<<<cdiv(n * 64, 256), 256, 0, stream>>>(x64b, n * 64, xbr);
        wt3_kernel<<<cdiv(192 * 64, 256), 256, 0, stream>>>(w_c3, Wt3);
        gemm_mfma_store<<<dim3(cdiv(n, 64), 3), 256, 0, stream>>>(xbr, Wt3, P, n, 64, 192);
        conv3_reduce<<<cdiv(n, 4), 256, 0, stream>>>(
            P, wgt_ff, cl_ff, ff_s, rp_ff, xbr, w_d3, b_d3, n, y3);
    }

    final_kernel<<<cdiv(n * 3, 256), 256, 0, stream>>>(pos, pos2, y3, n, out);
}

// Round 6
// 1210.026 us; speedup vs baseline: 7.4260x; 1.2672x over previous
//
#include <hip/hip_runtime.h>
#include <algorithm>

#define DT_F 0.02f
#define INV_R (1.0f / 0.1125f)

typedef __attribute__((ext_vector_type(8))) short short8;
typedef __attribute__((ext_vector_type(4))) float float4v;

static inline int cdiv(int a, int b) { return (a + b - 1) / b; }

__device__ __forceinline__ float sgnf(float v) {
    return (v > 0.f) ? 1.f : ((v < 0.f) ? -1.f : 0.f);
}

__device__ __forceinline__ unsigned short f2bf(float f) {
    union { float f; unsigned u; } v; v.f = f;
    return (unsigned short)((v.u + 0x7fffu + ((v.u >> 16) & 1u)) >> 16);
}
__device__ __forceinline__ float bf2f(unsigned short h) {
    union { unsigned u; float f; } v; v.u = ((unsigned)h) << 16;
    return v.f;
}

// Exact port of reference ball_to_cube (f32).
__device__ __forceinline__ void ball_to_cube_dev(float x, float y, float z,
                                                 float& ox, float& oy, float& oz) {
    const float eps = 1e-12f;
    float sq = x * x + y * y + z * z;
    float nrm = sqrtf(sq + eps);
    float xy2 = x * x + y * y;
    bool cap = 1.25f * z * z > xy2;
    float s_cap = sqrtf(3.f * nrm / (nrm + fabsf(z) + eps));
    float s_side = nrm / sqrtf(xy2 + eps);
    float s = cap ? s_cap : s_side;
    float xc = x * s, yc = y * s;
    float zc = cap ? sgnf(z) * nrm : 1.5f * z;
    if (!(sq > eps)) { xc = 0.f; yc = 0.f; zc = 0.f; }
    float rxy = sqrtf(xc * xc + yc * yc + eps);
    bool xbig = fabsf(yc) <= fabsf(xc);
    float dx = (fabsf(xc) > eps) ? xc : 1.f;
    float dy = (fabsf(yc) > eps) ? yc : 1.f;
    const float c4pi = 1.27323954473516276f;  // 4/pi
    float tx = sgnf(xc) * rxy, ty = sgnf(yc) * rxy;
    float xq = xbig ? tx : ty * c4pi * atanf(xc / dy);
    float yq = xbig ? tx * c4pi * atanf(yc / dx) : ty;
    if (!(xc * xc + yc * yc > eps)) { xq = 0.f; yq = 0.f; }
    ox = xq; oy = yq; oz = zc;
}

__global__ void prep_kernel(const float* __restrict__ pos, const float* __restrict__ vel,
                            int n, float* __restrict__ pos2, float* __restrict__ fl) {
    int i = blockIdx.x * blockDim.x + threadIdx.x;
    if (i >= n) return;
    float v0 = vel[i * 3 + 0], v1 = vel[i * 3 + 1], v2 = vel[i * 3 + 2];
    float u0 = v0, u1 = v1 + DT_F * (-9.81f), u2 = v2;
    pos2[i * 3 + 0] = pos[i * 3 + 0] + DT_F * (u0 + v0) * 0.5f;
    pos2[i * 3 + 1] = pos[i * 3 + 1] + DT_F * (u1 + v1) * 0.5f;
    pos2[i * 3 + 2] = pos[i * 3 + 2] + DT_F * (u2 + v2) * 0.5f;
    fl[i * 4 + 0] = 1.f;
    fl[i * 4 + 1] = u0;
    fl[i * 4 + 2] = u1;
    fl[i * 4 + 3] = u2;
}

__global__ void row_ptr_kernel(const int* __restrict__ q_idx, int E, int nq,
                               int* __restrict__ row_ptr) {
    int q = blockIdx.x * blockDim.x + threadIdx.x;
    if (q > nq) return;
    int lo = 0, hi = E;
    while (lo < hi) {
        int mid = (lo + hi) >> 1;
        if (q_idx[mid] < q) lo = mid + 1; else hi = mid;
    }
    row_ptr[q] = lo;
}

// Per-edge geometry once; ix clamped to [0,2] => 8 distinct corners (no RMW aliasing).
// Outputs: wgt[e][8], cells[e] (8 packed bytes), and (ff only) per-parity-class
// records edata[class][e] = {wA, wB, cellA|cellB<<8, s} so the build loop is pure loads.
__global__ void edge_geom_kernel(const float* __restrict__ posq, const float* __restrict__ poss,
                                 const int* __restrict__ q_idx, const int* __restrict__ s_idx,
                                 int E, float* __restrict__ wgt, uint2* __restrict__ cells,
                                 uint4* __restrict__ edata) {
    int e = blockIdx.x * blockDim.x + threadIdx.x;
    if (e >= E) return;
    int q = q_idx[e], s = s_idx[e];
    float dx = (poss[s * 3 + 0] - posq[q * 3 + 0]) * INV_R;
    float dy = (poss[s * 3 + 1] - posq[q * 3 + 1]) * INV_R;
    float dz = (poss[s * 3 + 2] - posq[q * 3 + 2]) * INV_R;
    float r2 = dx * dx + dy * dy + dz * dz;
    float w1 = 1.f - r2;
    float win = fminf(fmaxf(w1 * w1 * w1, 0.f), 1.f);
    float bx, by, bz;
    ball_to_cube_dev(dx, dy, dz, bx, by, bz);
    float gx = (bx + 1.f) * 1.5f, gy = (by + 1.f) * 1.5f, gz = (bz + 1.f) * 1.5f;
    int ix = min(max((int)floorf(gx), 0), 2);
    int iy = min(max((int)floorf(gy), 0), 2);
    int iz = min(max((int)floorf(gz), 0), 2);
    float fx = gx - (float)ix, fy = gy - (float)iy, fz = gz - (float)iz;
    float wv[8];
    unsigned int cl[8];
#pragma unroll
    for (int c = 0; c < 8; c++) {
        int cbx = (c >> 2) & 1, cby = (c >> 1) & 1, cbz = c & 1;
        int jx = ix + cbx, jy = iy + cby, jz = iz + cbz;
        cl[c] = (unsigned int)((jx * 4 + jy) * 4 + jz);
        wv[c] = win * (cbx ? fx : 1.f - fx) * (cby ? fy : 1.f - fy) * (cbz ? fz : 1.f - fz);
    }
    float4* wp = (float4*)(wgt + (size_t)e * 8);
    wp[0] = make_float4(wv[0], wv[1], wv[2], wv[3]);
    wp[1] = make_float4(wv[4], wv[5], wv[6], wv[7]);
    uint2 cp;
    cp.x = cl[0] | (cl[1] << 8) | (cl[2] << 16) | (cl[3] << 24);
    cp.y = cl[4] | (cl[5] << 8) | (cl[6] << 16) | (cl[7] << 24);
    cells[e] = cp;
    if (edata) {
#pragma unroll
        for (int w = 0; w < 4; w++) {
            int pa = w >> 1, pb = w & 1;
            int cby = pa ^ (iy & 1), cbz = pb ^ (iz & 1);
            int cA = cby * 2 + cbz;
            uint4 d;
            d.x = __float_as_uint(wv[cA]);
            d.y = __float_as_uint(wv[cA + 4]);
            d.z = cl[cA] | (cl[cA + 4] << 8);
            d.w = (unsigned)s;
            edata[(size_t)w * E + e] = d;
        }
    }
}

// a_df = fl @ w_d0 + b_d0 -> x96[:, 64:96]
__global__ void dense0_kernel(const float* __restrict__ fl, const float* __restrict__ w,
                              const float* __restrict__ b, int n, float* __restrict__ x96) {
    int i = blockIdx.x * blockDim.x + threadIdx.x;
    if (i >= n * 32) return;
    int q = i >> 5, o = i & 31;
    float acc = b[o];
#pragma unroll
    for (int c = 0; c < 4; c++) acc += fl[q * 4 + c] * w[c * 32 + o];
    x96[(size_t)q * 96 + 64 + o] = acc;
}

// C[q,o] = bias[o] (+resid[q,o]); zero if bias null (pre-init for atomic split-K).
__global__ void init_out_kernel(float* __restrict__ C, const float* __restrict__ bias,
                                const float* __restrict__ resid, int n, int co, int ldc) {
    int i = blockIdx.x * blockDim.x + threadIdx.x;
    if (i >= n * co) return;
    int q = i / co, o = i - q * co;
    float v = bias ? bias[o] : 0.f;
    if (resid) v += resid[(size_t)q * ldc + o];
    C[(size_t)q * ldc + o] = v;
}

// Wt[n][k] = bf16(W[k][n]) with W = [w_c (64*ci rows) ; w_d (ci rows)], K = 65*ci.
__global__ void wt_kernel(const float* __restrict__ wc, const float* __restrict__ wd,
                          int ci, int co, int K, unsigned short* __restrict__ Wt) {
    int i = blockIdx.x * blockDim.x + threadIdx.x;
    if (i >= co * K) return;
    int n = i / K, k = i - n * K;
    float v = (k < 64 * ci) ? wc[(size_t)k * co + n] : wd[(size_t)(k - 64 * ci) * co + n];
    Wt[i] = f2bf(v);
}

// Wt3[j=cell*3+o][k] = bf16(w_c3[cell][k][o]); 192 rows x 64 cols.
__global__ void wt3_kernel(const float* __restrict__ wc, unsigned short* __restrict__ Wt) {
    int i = blockIdx.x * blockDim.x + threadIdx.x;
    if (i >= 192 * 64) return;
    int j = i >> 6, k = i & 63;
    int cell = j / 3, o = j - cell * 3;
    Wt[i] = f2bf(wc[((size_t)cell * 64 + k) * 3 + o]);
}

// h = bf16(relu(x)), flat n elems.
__global__ void relu_bf16_kernel(const float* __restrict__ x, int n,
                                 unsigned short* __restrict__ h) {
    int i = blockIdx.x * blockDim.x + threadIdx.x;
    if (i < n) h[i] = f2bf(fmaxf(x[i], 0.f));
}

// Small-cin (layer 0) G build with software-pipelined prefetch. f32 G out [Q][64][cin].
__global__ __launch_bounds__(64) void build_G_small(
    const float* __restrict__ feat, int cin,
    const float* __restrict__ wgt, const uint2* __restrict__ cells,
    const int* __restrict__ s_idx, const int* __restrict__ row_ptr, int q0,
    float* __restrict__ G) {
    __shared__ float Gs[8 * 64 * 8];
    int lq = blockIdx.x, q = q0 + lq, t = threadIdx.x;
    int r = t >> 3, ch = t & 7;
    for (int i = t; i < 4096; i += 64) Gs[i] = 0.f;
    __syncthreads();
    int e0 = row_ptr[q], e1 = row_ptr[q + 1];
    int cnt = e1 - e0;
    if (cnt > 0) {
        int last = e1 - 1;
        int sA = s_idx[e0];
        uint2 cpA = cells[e0];
        float wA = wgt[(size_t)e0 * 8 + r];
        int eB = min(e0 + 1, last);
        int sB = s_idx[eB];
        uint2 cpB = cells[eB];
        float wB = wgt[(size_t)eB * 8 + r];
        float fA = (ch < cin) ? feat[(size_t)sA * cin + ch] : 0.f;
        for (int i = 0; i < cnt; i++) {
            float fB = (ch < cin) ? feat[(size_t)sB * cin + ch] : 0.f;
            int eC = min(e0 + i + 2, last);
            int sC = s_idx[eC];
            uint2 cpC = cells[eC];
            float wC = wgt[(size_t)eC * 8 + r];
            unsigned word = (r < 4) ? cpA.x : cpA.y;
            int cell = (int)((word >> ((r & 3) * 8)) & 255u);
            Gs[(r * 64 + cell) * 8 + ch] += wA * fA;
            sA = sB; cpA = cpB; wA = wB; fA = fB;
            sB = sC; cpB = cpC; wB = wC;
        }
    }
    __syncthreads();
    size_t base = (size_t)lq * 64 * cin;
    for (int i = t; i < 64 * cin; i += 64) {
        int cell = i / cin, c = i - cell * cin;
        float acc = 0.f;
#pragma unroll
        for (int rr = 0; rr < 8; rr++) acc += Gs[(rr * 64 + cell) * 8 + c];
        G[base + i] = acc;
    }
}

// Big-cin G build: 4 waves, parity-partitioned corners (class = (jy&1)*2+(jz&1):
// exactly 2 corners/edge/class; classes partition the 64 cells => no cross-wave races).
// Software-pipelined: 2-deep prefetch on edata, 1-deep on the feature row.
// DUAL=1 (PAIRS<=32): half-waves process edges e / e+1 into separate LDS replicas
// (all 64 lanes busy, serial edge count halved), merged at drain.
// G out bf16 [Q][65][cin]; slot 64 = featq[q]; optional fused ReLU.
template <int PAIRS, int DUAL>
__global__ __launch_bounds__(256) void build_G_bigT(
    const float* __restrict__ feat,
    const uint4* __restrict__ edata, int E,
    const int* __restrict__ row_ptr,
    const float* __restrict__ featq, int q0, int dorelu,
    unsigned short* __restrict__ G) {
    constexpr int REP = DUAL ? 2 : 1;
    constexpr int CIN = PAIRS * 2;
    __shared__ float2 Gs[64 * PAIRS * REP];
    int lq = blockIdx.x, q = q0 + lq, t = threadIdx.x;
    int wave = t >> 6, lane = t & 63;
    for (int i = t; i < 64 * PAIRS * REP; i += 256) Gs[i] = make_float2(0.f, 0.f);
    __syncthreads();
    const float2* feat2 = (const float2*)feat;
    int e0 = row_ptr[q], e1 = row_ptr[q + 1];
    int cnt = e1 - e0;
    const uint4* ed = edata + (size_t)wave * E;
    if (cnt > 0) {
        int last = e1 - 1;
        if (DUAL) {
            int half = lane >> 5;
            int p = lane & 31;  // PAIRS <= 32
            float2* Gr = Gs + half * (64 * PAIRS);
            int nIt = (cnt + 1) >> 1;
            uint4 dA = ed[min(e0 + half, last)];
            uint4 dB = ed[min(e0 + 2 + half, last)];
            float2 fA = feat2[(size_t)dA.w * PAIRS + p];
            for (int i = 0; i < nIt; i++) {
                uint4 dC = ed[min(e0 + 2 * i + 4 + half, last)];
                float2 fB = feat2[(size_t)dB.w * PAIRS + p];
                int e = e0 + 2 * i + half;
                bool v = e < e1;
                float wA = v ? __uint_as_float(dA.x) : 0.f;
                float wB = v ? __uint_as_float(dA.y) : 0.f;
                int cellA = (int)(dA.z & 255u), cellB = (int)((dA.z >> 8) & 255u);
                float2 fv = fA;
                if (dorelu) { fv.x = fmaxf(fv.x, 0.f); fv.y = fmaxf(fv.y, 0.f); }
                float2 gA = Gr[cellA * PAIRS + p];
                float2 gB = Gr[cellB * PAIRS + p];
                gA.x += wA * fv.x; gA.y += wA * fv.y;
                gB.x += wB * fv.x; gB.y += wB * fv.y;
                Gr[cellA * PAIRS + p] = gA;
                Gr[cellB * PAIRS + p] = gB;
                dA = dB; dB = dC; fA = fB;
            }
        } else {
            bool act = lane < PAIRS;
            int p = act ? lane : 0;
            uint4 dA = ed[e0];
            uint4 dB = ed[min(e0 + 1, last)];
            float2 fA = feat2[(size_t)dA.w * PAIRS + p];
            for (int i = 0; i < cnt; i++) {
                uint4 dC = ed[min(e0 + i + 2, last)];
                float2 fB = feat2[(size_t)dB.w * PAIRS + p];
                if (act) {
                    float wA = __uint_as_float(dA.x), wB = __uint_as_float(dA.y);
                    int cellA = (int)(dA.z & 255u), cellB = (int)((dA.z >> 8) & 255u);
                    float2 fv = fA;
                    if (dorelu) { fv.x = fmaxf(fv.x, 0.f); fv.y = fmaxf(fv.y, 0.f); }
                    float2 gA = Gs[cellA * PAIRS + p];
                    float2 gB = Gs[cellB * PAIRS + p];
                    gA.x += wA * fv.x; gA.y += wA * fv.y;
                    gB.x += wB * fv.x; gB.y += wB * fv.y;
                    Gs[cellA * PAIRS + p] = gA;
                    Gs[cellB * PAIRS + p] = gB;
                }
                dA = dB; dB = dC; fA = fB;
            }
        }
    }
    __syncthreads();
    unsigned int* Go = (unsigned int*)(G + (size_t)lq * (size_t)(65 * CIN));
    for (int i = t; i < 64 * PAIRS; i += 256) {
        float2 g = Gs[i];
        if (DUAL) { float2 g2 = Gs[i + 64 * PAIRS]; g.x += g2.x; g.y += g2.y; }
        Go[i] = (unsigned int)f2bf(g.x) | ((unsigned int)f2bf(g.y) << 16);
    }
    if (wave == 0 && lane < PAIRS) {
        float2 fq = feat2[(size_t)q * PAIRS + lane];
        if (dorelu) { fq.x = fmaxf(fq.x, 0.f); fq.y = fmaxf(fq.y, 0.f); }
        Go[64 * PAIRS + lane] = (unsigned int)f2bf(fq.x) | ((unsigned int)f2bf(fq.y) << 16);
    }
}

// bf16 MFMA GEMM, split-K atomics. A: [M][K] bf16 row-major; Wt: [64][K] bf16 (n-major).
__global__ __launch_bounds__(256) void gemm_mfma(
    const unsigned short* __restrict__ A, const unsigned short* __restrict__ Wt,
    float* __restrict__ C, int M, int K, int ldc, int kpb) {
    int wave = threadIdx.x >> 6, lane = threadIdx.x & 63;
    int m0 = blockIdx.x * 64;
    int kbeg = blockIdx.y * kpb;
    int kend = min(K, kbeg + kpb);
    int mrow = lane & 15, kq = lane >> 4;
    int n0 = wave * 16;
    const unsigned short* Bp = Wt + (size_t)(n0 + mrow) * K;
    float4v acc[4] = {{0.f, 0.f, 0.f, 0.f}, {0.f, 0.f, 0.f, 0.f},
                      {0.f, 0.f, 0.f, 0.f}, {0.f, 0.f, 0.f, 0.f}};
    int r0 = min(m0 + mrow, M - 1);
    int r1 = min(m0 + 16 + mrow, M - 1);
    int r2 = min(m0 + 32 + mrow, M - 1);
    int r3 = min(m0 + 48 + mrow, M - 1);
    const unsigned short* A0 = A + (size_t)r0 * K;
    const unsigned short* A1 = A + (size_t)r1 * K;
    const unsigned short* A2 = A + (size_t)r2 * K;
    const unsigned short* A3 = A + (size_t)r3 * K;
    for (int k0 = kbeg; k0 < kend; k0 += 32) {
        int kk = k0 + kq * 8;
        short8 b = *(const short8*)(Bp + kk);
        short8 a0 = *(const short8*)(A0 + kk);
        short8 a1 = *(const short8*)(A1 + kk);
        short8 a2 = *(const short8*)(A2 + kk);
        short8 a3 = *(const short8*)(A3 + kk);
        acc[0] = __builtin_amdgcn_mfma_f32_16x16x32_bf16(a0, b, acc[0], 0, 0, 0);
        acc[1] = __builtin_amdgcn_mfma_f32_16x16x32_bf16(a1, b, acc[1], 0, 0, 0);
        acc[2] = __builtin_amdgcn_mfma_f32_16x16x32_bf16(a2, b, acc[2], 0, 0, 0);
        acc[3] = __builtin_amdgcn_mfma_f32_16x16x32_bf16(a3, b, acc[3], 0, 0, 0);
    }
    int col = lane & 15, rq = lane >> 4;
#pragma unroll
    for (int mt = 0; mt < 4; mt++) {
#pragma unroll
        for (int r = 0; r < 4; r++) {
            int m = m0 + mt * 16 + rq * 4 + r;
            if (m < M) atomicAdd(&C[(size_t)m * ldc + n0 + col], acc[mt][r]);
        }
    }
}

// bf16 MFMA GEMM, direct store, N-tiled via blockIdx.y (64 outputs per tile), full K.
__global__ __launch_bounds__(256) void gemm_mfma_store(
    const unsigned short* __restrict__ A, const unsigned short* __restrict__ Wt,
    float* __restrict__ C, int M, int K, int ldc) {
    int wave = threadIdx.x >> 6, lane = threadIdx.x & 63;
    int m0 = blockIdx.x * 64;
    int n0 = blockIdx.y * 64 + wave * 16;
    int mrow = lane & 15, kq = lane >> 4;
    const unsigned short* Bp = Wt + (size_t)(n0 + mrow) * K;
    float4v acc[4] = {{0.f, 0.f, 0.f, 0.f}, {0.f, 0.f, 0.f, 0.f},
                      {0.f, 0.f, 0.f, 0.f}, {0.f, 0.f, 0.f, 0.f}};
    int r0 = min(m0 + mrow, M - 1);
    int r1 = min(m0 + 16 + mrow, M - 1);
    int r2 = min(m0 + 32 + mrow, M - 1);
    int r3 = min(m0 + 48 + mrow, M - 1);
    const unsigned short* A0 = A + (size_t)r0 * K;
    const unsigned short* A1 = A + (size_t)r1 * K;
    const unsigned short* A2 = A + (size_t)r2 * K;
    const unsigned short* A3 = A + (size_t)r3 * K;
    for (int k0 = 0; k0 < K; k0 += 32) {
        int kk = k0 + kq * 8;
        short8 b = *(const short8*)(Bp + kk);
        short8 a0 = *(const short8*)(A0 + kk);
        short8 a1 = *(const short8*)(A1 + kk);
        short8 a2 = *(const short8*)(A2 + kk);
        short8 a3 = *(const short8*)(A3 + kk);
        acc[0] = __builtin_amdgcn_mfma_f32_16x16x32_bf16(a0, b, acc[0], 0, 0, 0);
        acc[1] = __builtin_amdgcn_mfma_f32_16x16x32_bf16(a1, b, acc[1], 0, 0, 0);
        acc[2] = __builtin_amdgcn_mfma_f32_16x16x32_bf16(a2, b, acc[2], 0, 0, 0);
        acc[3] = __builtin_amdgcn_mfma_f32_16x16x32_bf16(a3, b, acc[3], 0, 0, 0);
    }
    int col = lane & 15, rq = lane >> 4;
#pragma unroll
    for (int mt = 0; mt < 4; mt++) {
#pragma unroll
        for (int r = 0; r < 4; r++) {
            int m = m0 + mt * 16 + rq * 4 + r;
            if (m < M) C[(size_t)m * ldc + n0 + col] = acc[mt][r];
        }
    }
}

// Layer 3: y3[q] = sum_edges sum_corners w * P[s][cell*3+o] + relu(x64b[q])@w_d3 + b_d3.
// One wave per query, lane-per-edge; P: [n][192] f32.
__global__ __launch_bounds__(256) void conv3_reduce(
    const float* __restrict__ P,
    const float* __restrict__ wgt, const uint2* __restrict__ cells,
    const int* __restrict__ s_idx, const int* __restrict__ row_ptr,
    const unsigned short* __restrict__ hq, const float* __restrict__ wd3,
    const float* __restrict__ b3, int n, float* __restrict__ y3) {
    int wave = threadIdx.x >> 6, lane = threadIdx.x & 63;
    int q = blockIdx.x * 4 + wave;
    if (q >= n) return;
    float a0 = 0.f, a1 = 0.f, a2 = 0.f;
    int e0 = row_ptr[q], e1 = row_ptr[q + 1];
    for (int e = e0 + lane; e < e1; e += 64) {
        int s = s_idx[e];
        uint2 cp = cells[e];
        const float4* wp = (const float4*)(wgt + (size_t)e * 8);
        float4 wa = wp[0], wb = wp[1];
        const float* Ps = P + (size_t)s * 192;
        float wv[8] = {wa.x, wa.y, wa.z, wa.w, wb.x, wb.y, wb.z, wb.w};
#pragma unroll
        for (int c = 0; c < 8; c++) {
            unsigned word = (c < 4) ? cp.x : cp.y;
            int cell = (int)((word >> ((c & 3) * 8)) & 255u);
            const float* pc = Ps + cell * 3;
            a0 += wv[c] * pc[0];
            a1 += wv[c] * pc[1];
            a2 += wv[c] * pc[2];
        }
    }
    // dense term: lane = channel
    float hv = bf2f(hq[(size_t)q * 64 + lane]);
    a0 += hv * wd3[lane * 3 + 0];
    a1 += hv * wd3[lane * 3 + 1];
    a2 += hv * wd3[lane * 3 + 2];
#pragma unroll
    for (int off = 32; off > 0; off >>= 1) {
        a0 += __shfl_xor(a0, off);
        a1 += __shfl_xor(a1, off);
        a2 += __shfl_xor(a2, off);
    }
    if (lane == 0) {
        y3[(size_t)q * 3 + 0] = a0 + b3[0];
        y3[(size_t)q * 3 + 1] = a1 + b3[1];
        y3[(size_t)q * 3 + 2] = a2 + b3[2];
    }
}

// f32 split-K GEMM (layer 0 only, tiny K).
template <int BM, int BN, int BK, int TM, int TN>
__global__ void gemm_atomic(const float* __restrict__ A, const float* __restrict__ B,
                            float* __restrict__ C, int M, int N, int K,
                            int ldc, int coff, int kpb) {
    constexpr int THREADS = (BM / TM) * (BN / TN);
    __shared__ float As[BK][BM + 1];
    __shared__ float Bs[BK][BN + 1];
    int tx = threadIdx.x;
    int tcols = BN / TN;
    int tcol = tx % tcols, trow = tx / tcols;
    int m0 = blockIdx.x * BM;
    int kbeg = blockIdx.y * kpb;
    int kend = min(K, kbeg + kpb);
    float acc[TM][TN];
#pragma unroll
    for (int i = 0; i < TM; i++)
#pragma unroll
        for (int j = 0; j < TN; j++) acc[i][j] = 0.f;
    for (int k0 = kbeg; k0 < kend; k0 += BK) {
        for (int i = tx; i < BM * BK; i += THREADS) {
            int kk = i % BK, mm = i / BK;
            int m = m0 + mm, k = k0 + kk;
            As[kk][mm] = (m < M && k < K) ? A[(size_t)m * K + k] : 0.f;
        }
        for (int i = tx; i < BN * BK; i += THREADS) {
            int nn = i % BN, kk = i / BN;
            int k = k0 + kk;
            Bs[kk][nn] = (k < K && nn < N) ? B[(size_t)k * N + nn] : 0.f;
        }
        __syncthreads();
#pragma unroll
        for (int kk = 0; kk < BK; kk++) {
            float a[TM], b[TN];
#pragma unroll
            for (int i = 0; i < TM; i++) a[i] = As[kk][trow * TM + i];
#pragma unroll
            for (int j = 0; j < TN; j++) b[j] = Bs[kk][tcol * TN + j];
#pragma unroll
            for (int i = 0; i < TM; i++)
#pragma unroll
                for (int j = 0; j < TN; j++) acc[i][j] += a[i] * b[j];
        }
        __syncthreads();
    }
    for (int i = 0; i < TM; i++) {
        int m = m0 + trow * TM + i;
        if (m >= M) continue;
        for (int j = 0; j < TN; j++) {
            int nn = tcol * TN + j;
            if (nn >= N) continue;
            atomicAdd(&C[(size_t)m * ldc + coff + nn], acc[i][j]);
        }
    }
}

__global__ void final_kernel(const float* __restrict__ pos, const float* __restrict__ pos2,
                             const float* __restrict__ y3, int n, float* __restrict__ out) {
    int i = blockIdx.x * blockDim.x + threadIdx.x;
    if (i >= n * 3) return;
    float pn = pos2[i] + y3[i] * (1.f / 128.f);
    out[i] = pn;
    out[n * 3 + i] = (pn - pos[i]) * (1.f / DT_F);
}

extern "C" void kernel_launch(void* const* d_in, const int* in_sizes, int n_in,
                              void* d_out, int out_size, void* d_ws, size_t ws_size,
                              hipStream_t stream) {
    const float* pos       = (const float*)d_in[0];
    const float* vel       = (const float*)d_in[1];
    const float* box       = (const float*)d_in[2];
    const float* box_feats = (const float*)d_in[3];
    const int*   ff_q      = (const int*)d_in[4];
    const int*   ff_s      = (const int*)d_in[5];
    const int*   fo_q      = (const int*)d_in[6];
    const int*   fo_s      = (const int*)d_in[7];
    const float* w_cf0     = (const float*)d_in[8];
    const float* w_co0     = (const float*)d_in[9];
    const float* w_d0      = (const float*)d_in[10];
    const float* b_d0      = (const float*)d_in[11];
    const float* w_c1      = (const float*)d_in[12];
    const float* w_d1      = (const float*)d_in[13];
    const float* b_d1      = (const float*)d_in[14];
    const float* w_c2      = (const float*)d_in[15];
    const float* w_d2      = (const float*)d_in[16];
    const float* b_d2      = (const float*)d_in[17];
    const float* w_c3      = (const float*)d_in[18];
    const float* w_d3      = (const float*)d_in[19];
    const float* b_d3      = (const float*)d_in[20];
    float* out = (float*)d_out;

    int n   = in_sizes[0] / 3;
    int Eff = in_sizes[4];
    int Efo = in_sizes[6];

    float* base = (float*)d_ws;
    size_t off = 0;
    auto alloc = [&](size_t nf) { float* p = base + off; off += (nf + 3) & ~(size_t)3; return p; };
    float* pos2  = alloc((size_t)n * 3);
    float* fl    = alloc((size_t)n * 4);
    float* x96   = alloc((size_t)n * 96);
    float* x64a  = alloc((size_t)n * 64);
    float* x64b  = alloc((size_t)n * 64);
    float* y3    = alloc((size_t)n * 3);
    int* rp_ff   = (int*)alloc((size_t)n + 1);
    int* rp_fo   = (int*)alloc((size_t)n + 1);
    unsigned short* Wt  = (unsigned short*)alloc((size_t)65 * 96 * 64 / 2);
    unsigned short* Wt3 = (unsigned short*)alloc((size_t)192 * 64 / 2);
    unsigned short* xbr = (unsigned short*)alloc((size_t)n * 64 / 2);
    float* P     = alloc((size_t)n * 192);
    float* wgt_ff = alloc((size_t)Eff * 8);
    uint2* cl_ff  = (uint2*)alloc((size_t)Eff * 2);
    float* wgt_fo = alloc((size_t)Efo * 8);
    uint2* cl_fo  = (uint2*)alloc((size_t)Efo * 2);
    uint4* ed_ff  = (uint4*)alloc((size_t)Eff * 16);
    float* G = base + off;                                  // f32 view (layer 0)
    unsigned short* Gb = (unsigned short*)G;                // bf16 view (layers 1-2)

    size_t totalF = ws_size / sizeof(float);
    size_t availF = (totalF > off) ? (totalF - off) : 0;
    auto chunkQ = [&](size_t floatsPerQ) {
        long q = (long)(availF / floatsPerQ);
        if (q < 1) q = 1;
        if (q > n) q = n;
        return (int)q;
    };

    // --- prep, CSR, edge geometry (once) ---
    prep_kernel<<<cdiv(n, 256), 256, 0, stream>>>(pos, vel, n, pos2, fl);
    row_ptr_kernel<<<cdiv(n + 1, 256), 256, 0, stream>>>(ff_q, Eff, n, rp_ff);
    row_ptr_kernel<<<cdiv(n + 1, 256), 256, 0, stream>>>(fo_q, Efo, n, rp_fo);
    edge_geom_kernel<<<cdiv(Eff, 256), 256, 0, stream>>>(pos2, pos2, ff_q, ff_s, Eff, wgt_ff, cl_ff, ed_ff);
    edge_geom_kernel<<<cdiv(Efo, 256), 256, 0, stream>>>(pos2, box, fo_q, fo_s, Efo, wgt_fo, cl_fo, nullptr);

    // --- layer 0 (f32 path, tiny K) ---
    init_out_kernel<<<cdiv(n * 64, 256), 256, 0, stream>>>(x96, nullptr, nullptr, n, 64, 96);
    dense0_kernel<<<cdiv(n * 32, 256), 256, 0, stream>>>(fl, w_d0, b_d0, n, x96);
    {
        int Q = chunkQ(64 * 4);
        for (int q0 = 0; q0 < n; q0 += Q) {
            int mc = std::min(Q, n - q0);
            build_G_small<<<mc, 64, 0, stream>>>(fl, 4, wgt_ff, cl_ff, ff_s, rp_ff, q0, G);
            gemm_atomic<64, 32, 16, 4, 2><<<dim3(cdiv(mc, 64), 2), 256, 0, stream>>>(
                G, w_cf0, x96 + (size_t)q0 * 96, mc, 32, 256, 96, 32, 8 * 16);
        }
    }
    {
        int Q = chunkQ(64 * 3);
        for (int q0 = 0; q0 < n; q0 += Q) {
            int mc = std::min(Q, n - q0);
            build_G_small<<<mc, 64, 0, stream>>>(box_feats, 3, wgt_fo, cl_fo, fo_s, rp_fo, q0, G);
            gemm_atomic<64, 32, 16, 4, 2><<<dim3(cdiv(mc, 64), 2), 256, 0, stream>>>(
                G, w_co0, x96 + (size_t)q0 * 96, mc, 32, 192, 96, 0, 6 * 16);
        }
    }

    // --- layer 1: 96 -> 64, bf16 MFMA (relu fused into build) ---
    {
        const int K = 65 * 96;
        wt_kernel<<<cdiv(64 * K, 256), 256, 0, stream>>>(w_c1, w_d1, 96, 64, K, Wt);
        init_out_kernel<<<cdiv(n * 64, 256), 256, 0, stream>>>(x64a, b_d1, nullptr, n, 64, 64);
        int Q = chunkQ((size_t)K / 2);
        for (int q0 = 0; q0 < n; q0 += Q) {
            int mc = std::min(Q, n - q0);
            build_G_bigT<48, 0><<<mc, 256, 0, stream>>>(
                x96, ed_ff, Eff, rp_ff, x96, q0, 1, Gb);
            gemm_mfma<<<dim3(cdiv(mc, 64), 4), 256, 0, stream>>>(
                Gb, Wt, x64a + (size_t)q0 * 64, mc, K, 64, cdiv(K / 32, 4) * 32);
        }
    }

    // --- layer 2: 64 -> 64, residual, bf16 MFMA (dual-edge build) ---
    {
        const int K = 65 * 64;
        wt_kernel<<<cdiv(64 * K, 256), 256, 0, stream>>>(w_c2, w_d2, 64, 64, K, Wt);
        init_out_kernel<<<cdiv(n * 64, 256), 256, 0, stream>>>(x64b, b_d2, x64a, n, 64, 64);
        int Q = chunkQ((size_t)K / 2);
        for (int q0 = 0; q0 < n; q0 += Q) {
            int mc = std::min(Q, n - q0);
            build_G_bigT<32, 1><<<mc, 256, 0, stream>>>(
                x64a, ed_ff, Eff, rp_ff, x64a, q0, 1, Gb);
            gemm_mfma<<<dim3(cdiv(mc, 64), 4), 256, 0, stream>>>(
                Gb, Wt, x64b + (size_t)q0 * 64, mc, K, 64, cdiv(K / 32, 4) * 32);
        }
    }

    // --- layer 3: 64 -> 3 via P-trick (no G build) ---
    {
        relu_bf16_kernel<<<cdiv(n * 64, 256), 256, 0, stream>>>(x64b, n * 64, xbr);
        wt3_kernel<<<cdiv(192 * 64, 256), 256, 0, stream>>>(w_c3, Wt3);
        gemm_mfma_store<<<dim3(cdiv(n, 64), 3), 256, 0, stream>>>(xbr, Wt3, P, n, 64, 192);
        conv3_reduce<<<cdiv(n, 4), 256, 0, stream>>>(
            P, wgt_ff, cl_ff, ff_s, rp_ff, xbr, w_d3, b_d3, n, y3);
    }

    final_kernel<<<cdiv(n * 3, 256), 256, 0, stream>>>(pos, pos2, y3, n, out);
}

// Round 7
// 1177.955 us; speedup vs baseline: 7.6281x; 1.0272x over previous
//
#include <hip/hip_runtime.h>
#include <algorithm>

#define DT_F 0.02f
#define INV_R (1.0f / 0.1125f)

typedef __attribute__((ext_vector_type(8))) short short8;
typedef __attribute__((ext_vector_type(4))) float float4v;

static inline int cdiv(int a, int b) { return (a + b - 1) / b; }

__device__ __forceinline__ float sgnf(float v) {
    return (v > 0.f) ? 1.f : ((v < 0.f) ? -1.f : 0.f);
}

__device__ __forceinline__ unsigned short f2bf(float f) {
    union { float f; unsigned u; } v; v.f = f;
    return (unsigned short)((v.u + 0x7fffu + ((v.u >> 16) & 1u)) >> 16);
}
__device__ __forceinline__ float bf2f(unsigned short h) {
    union { unsigned u; float f; } v; v.u = ((unsigned)h) << 16;
    return v.f;
}

// Exact port of reference ball_to_cube (f32).
__device__ __forceinline__ void ball_to_cube_dev(float x, float y, float z,
                                                 float& ox, float& oy, float& oz) {
    const float eps = 1e-12f;
    float sq = x * x + y * y + z * z;
    float nrm = sqrtf(sq + eps);
    float xy2 = x * x + y * y;
    bool cap = 1.25f * z * z > xy2;
    float s_cap = sqrtf(3.f * nrm / (nrm + fabsf(z) + eps));
    float s_side = nrm / sqrtf(xy2 + eps);
    float s = cap ? s_cap : s_side;
    float xc = x * s, yc = y * s;
    float zc = cap ? sgnf(z) * nrm : 1.5f * z;
    if (!(sq > eps)) { xc = 0.f; yc = 0.f; zc = 0.f; }
    float rxy = sqrtf(xc * xc + yc * yc + eps);
    bool xbig = fabsf(yc) <= fabsf(xc);
    float dx = (fabsf(xc) > eps) ? xc : 1.f;
    float dy = (fabsf(yc) > eps) ? yc : 1.f;
    const float c4pi = 1.27323954473516276f;  // 4/pi
    float tx = sgnf(xc) * rxy, ty = sgnf(yc) * rxy;
    float xq = xbig ? tx : ty * c4pi * atanf(xc / dy);
    float yq = xbig ? tx * c4pi * atanf(yc / dx) : ty;
    if (!(xc * xc + yc * yc > eps)) { xq = 0.f; yq = 0.f; }
    ox = xq; oy = yq; oz = zc;
}

__global__ void prep_kernel(const float* __restrict__ pos, const float* __restrict__ vel,
                            int n, float* __restrict__ pos2, float* __restrict__ fl) {
    int i = blockIdx.x * blockDim.x + threadIdx.x;
    if (i >= n) return;
    float v0 = vel[i * 3 + 0], v1 = vel[i * 3 + 1], v2 = vel[i * 3 + 2];
    float u0 = v0, u1 = v1 + DT_F * (-9.81f), u2 = v2;
    pos2[i * 3 + 0] = pos[i * 3 + 0] + DT_F * (u0 + v0) * 0.5f;
    pos2[i * 3 + 1] = pos[i * 3 + 1] + DT_F * (u1 + v1) * 0.5f;
    pos2[i * 3 + 2] = pos[i * 3 + 2] + DT_F * (u2 + v2) * 0.5f;
    fl[i * 4 + 0] = 1.f;
    fl[i * 4 + 1] = u0;
    fl[i * 4 + 2] = u1;
    fl[i * 4 + 3] = u2;
}

__global__ void row_ptr_kernel(const int* __restrict__ q_idx, int E, int nq,
                               int* __restrict__ row_ptr) {
    int q = blockIdx.x * blockDim.x + threadIdx.x;
    if (q > nq) return;
    int lo = 0, hi = E;
    while (lo < hi) {
        int mid = (lo + hi) >> 1;
        if (q_idx[mid] < q) lo = mid + 1; else hi = mid;
    }
    row_ptr[q] = lo;
}

// Per-edge geometry once; ix clamped to [0,2] => 8 distinct corners (no RMW aliasing).
// Outputs: wgt[e][8], cells[e] (8 packed bytes), and per-parity-class records
// edata[class][e] = {wA, wB, cellA|cellB<<8, s} so build loops are pure loads.
__global__ void edge_geom_kernel(const float* __restrict__ posq, const float* __restrict__ poss,
                                 const int* __restrict__ q_idx, const int* __restrict__ s_idx,
                                 int E, float* __restrict__ wgt, uint2* __restrict__ cells,
                                 uint4* __restrict__ edata) {
    int e = blockIdx.x * blockDim.x + threadIdx.x;
    if (e >= E) return;
    int q = q_idx[e], s = s_idx[e];
    float dx = (poss[s * 3 + 0] - posq[q * 3 + 0]) * INV_R;
    float dy = (poss[s * 3 + 1] - posq[q * 3 + 1]) * INV_R;
    float dz = (poss[s * 3 + 2] - posq[q * 3 + 2]) * INV_R;
    float r2 = dx * dx + dy * dy + dz * dz;
    float w1 = 1.f - r2;
    float win = fminf(fmaxf(w1 * w1 * w1, 0.f), 1.f);
    float bx, by, bz;
    ball_to_cube_dev(dx, dy, dz, bx, by, bz);
    float gx = (bx + 1.f) * 1.5f, gy = (by + 1.f) * 1.5f, gz = (bz + 1.f) * 1.5f;
    int ix = min(max((int)floorf(gx), 0), 2);
    int iy = min(max((int)floorf(gy), 0), 2);
    int iz = min(max((int)floorf(gz), 0), 2);
    float fx = gx - (float)ix, fy = gy - (float)iy, fz = gz - (float)iz;
    float wv[8];
    unsigned int cl[8];
#pragma unroll
    for (int c = 0; c < 8; c++) {
        int cbx = (c >> 2) & 1, cby = (c >> 1) & 1, cbz = c & 1;
        int jx = ix + cbx, jy = iy + cby, jz = iz + cbz;
        cl[c] = (unsigned int)((jx * 4 + jy) * 4 + jz);
        wv[c] = win * (cbx ? fx : 1.f - fx) * (cby ? fy : 1.f - fy) * (cbz ? fz : 1.f - fz);
    }
    float4* wp = (float4*)(wgt + (size_t)e * 8);
    wp[0] = make_float4(wv[0], wv[1], wv[2], wv[3]);
    wp[1] = make_float4(wv[4], wv[5], wv[6], wv[7]);
    uint2 cp;
    cp.x = cl[0] | (cl[1] << 8) | (cl[2] << 16) | (cl[3] << 24);
    cp.y = cl[4] | (cl[5] << 8) | (cl[6] << 16) | (cl[7] << 24);
    cells[e] = cp;
#pragma unroll
    for (int w = 0; w < 4; w++) {
        int pa = w >> 1, pb = w & 1;
        int cby = pa ^ (iy & 1), cbz = pb ^ (iz & 1);
        int cA = cby * 2 + cbz;
        uint4 d;
        d.x = __float_as_uint(wv[cA]);
        d.y = __float_as_uint(wv[cA + 4]);
        d.z = cl[cA] | (cl[cA + 4] << 8);
        d.w = (unsigned)s;
        edata[(size_t)w * E + e] = d;
    }
}

// a_df = fl @ w_d0 + b_d0 -> x96[:, 64:96]
__global__ void dense0_kernel(const float* __restrict__ fl, const float* __restrict__ w,
                              const float* __restrict__ b, int n, float* __restrict__ x96) {
    int i = blockIdx.x * blockDim.x + threadIdx.x;
    if (i >= n * 32) return;
    int q = i >> 5, o = i & 31;
    float acc = b[o];
#pragma unroll
    for (int c = 0; c < 4; c++) acc += fl[q * 4 + c] * w[c * 32 + o];
    x96[(size_t)q * 96 + 64 + o] = acc;
}

// C[q,o] = bias[o] (+resid[q,o]); zero if bias null (pre-init for atomic split-K).
__global__ void init_out_kernel(float* __restrict__ C, const float* __restrict__ bias,
                                const float* __restrict__ resid, int n, int co, int ldc) {
    int i = blockIdx.x * blockDim.x + threadIdx.x;
    if (i >= n * co) return;
    int q = i / co, o = i - q * co;
    float v = bias ? bias[o] : 0.f;
    if (resid) v += resid[(size_t)q * ldc + o];
    C[(size_t)q * ldc + o] = v;
}

// Wt[n][k] = bf16(W[k][n]) with W = [w_c (64*ci rows) ; w_d (ci rows)], K = 65*ci.
__global__ void wt_kernel(const float* __restrict__ wc, const float* __restrict__ wd,
                          int ci, int co, int K, unsigned short* __restrict__ Wt) {
    int i = blockIdx.x * blockDim.x + threadIdx.x;
    if (i >= co * K) return;
    int n = i / K, k = i - n * K;
    float v = (k < 64 * ci) ? wc[(size_t)k * co + n] : wd[(size_t)(k - 64 * ci) * co + n];
    Wt[i] = f2bf(v);
}

// Wt3[j=cell*3+o][k] = bf16(w_c3[cell][k][o]); 192 rows x 64 cols.
__global__ void wt3_kernel(const float* __restrict__ wc, unsigned short* __restrict__ Wt) {
    int i = blockIdx.x * blockDim.x + threadIdx.x;
    if (i >= 192 * 64) return;
    int j = i >> 6, k = i & 63;
    int cell = j / 3, o = j - cell * 3;
    Wt[i] = f2bf(wc[((size_t)cell * 64 + k) * 3 + o]);
}

// h = bf16(relu(x)), flat n elems.
__global__ void relu_bf16_kernel(const float* __restrict__ x, int n,
                                 unsigned short* __restrict__ h) {
    int i = blockIdx.x * blockDim.x + threadIdx.x;
    if (i < n) h[i] = f2bf(fmaxf(x[i], 0.f));
}

// Layer-0 G build, parity-partitioned, 4 edges per block-iteration.
// 256 thr = 4 waves (parity classes); lane = edge-slot j(4) x corner k(2) x ch(8).
// Replica per edge-slot (4 x 64cells x 8ch floats = 8 KB); classes partition cells.
// G out f32 [Q][64][CIN].
template <int CIN>
__global__ __launch_bounds__(256) void build_G0_par(
    const float* __restrict__ feat, const uint4* __restrict__ edata, int E,
    const int* __restrict__ row_ptr, int q0, float* __restrict__ G) {
    __shared__ float Gs[4 * 64 * 8];  // [replica j][cell][ch]
    int lq = blockIdx.x, q = q0 + lq, t = threadIdx.x;
    int wave = t >> 6, lane = t & 63;
    int j = lane >> 4, k = (lane >> 3) & 1, ch = lane & 7;
    for (int i = t; i < 2048; i += 256) Gs[i] = 0.f;
    __syncthreads();
    int e0 = row_ptr[q], e1 = row_ptr[q + 1];
    int cnt = e1 - e0;
    if (cnt > 0) {
        int last = e1 - 1;
        const uint4* ed = edata + (size_t)wave * E;
        int nIt = (cnt + 3) >> 2;
        uint4 dA = ed[min(e0 + j, last)];
        uint4 dB = ed[min(e0 + 4 + j, last)];
        float fA = (ch < CIN) ? feat[(size_t)dA.w * CIN + ch] : 0.f;
        float* Gr = Gs + j * 512;
        for (int i = 0; i < nIt; i++) {
            uint4 dC = ed[min(e0 + (i + 2) * 4 + j, last)];
            float fB = (ch < CIN) ? feat[(size_t)dB.w * CIN + ch] : 0.f;
            bool v = (e0 + i * 4 + j) < e1;
            float w = v ? (k ? __uint_as_float(dA.y) : __uint_as_float(dA.x)) : 0.f;
            int cell = (int)((dA.z >> (k * 8)) & 255u);
            Gr[cell * 8 + ch] += w * fA;
            dA = dB; dB = dC; fA = fB;
        }
    }
    __syncthreads();
    size_t base = (size_t)lq * 64 * CIN;
    for (int i = t; i < 64 * CIN; i += 256) {
        int cell = i / CIN, c = i - cell * CIN;
        int o = cell * 8 + c;
        G[base + i] = Gs[o] + Gs[512 + o] + Gs[1024 + o] + Gs[1536 + o];
    }
}

// Big-cin G build: 4*EG waves; wave = (edge-group g, parity class). Parity class
// (jy&1)*2+(jz&1) has exactly 2 corners/edge and classes partition the 64 cells
// => no cross-class races; edge-groups (and DUAL sub-halves) use separate LDS
// replicas => no cross-group races. 2-deep prefetch on edata, 1-deep on features.
// G out bf16 [Q][65][CIN]; slot 64 = featq[q]; optional fused ReLU.
template <int PAIRS, int EG, int DUAL>
__global__ __launch_bounds__(256 * EG) void build_G_bigT(
    const float* __restrict__ feat,
    const uint4* __restrict__ edata, int E,
    const int* __restrict__ row_ptr,
    const float* __restrict__ featq, int q0, int dorelu,
    unsigned short* __restrict__ G) {
    constexpr int SUB = DUAL ? 2 : 1;
    constexpr int REP = EG * SUB;
    constexpr int STRIDE = EG * SUB;
    constexpr int THREADS = 256 * EG;
    constexpr int CIN = PAIRS * 2;
    __shared__ float2 Gs[REP * 64 * PAIRS];
    int lq = blockIdx.x, q = q0 + lq, t = threadIdx.x;
    int wave = t >> 6, lane = t & 63;
    int g = wave >> 2, cls = wave & 3;
    for (int i = t; i < REP * 64 * PAIRS; i += THREADS) Gs[i] = make_float2(0.f, 0.f);
    __syncthreads();
    const float2* feat2 = (const float2*)feat;
    int e0 = row_ptr[q], e1 = row_ptr[q + 1];
    int cnt = e1 - e0;
    if (cnt > 0) {
        int last = e1 - 1;
        const uint4* ed = edata + (size_t)cls * E;
        int sub = DUAL ? (lane >> 5) : 0;
        int off = g * SUB + sub;
        bool act = DUAL ? true : (lane < PAIRS);
        int p = DUAL ? (lane & 31) : (act ? lane : 0);
        float2* Gr = Gs + (size_t)off * (64 * PAIRS);
        int nIt = (cnt + STRIDE - 1) / STRIDE;
        uint4 dA = ed[min(e0 + off, last)];
        uint4 dB = ed[min(e0 + STRIDE + off, last)];
        float2 fA = feat2[(size_t)dA.w * PAIRS + p];
        for (int i = 0; i < nIt; i++) {
            uint4 dC = ed[min(e0 + (i + 2) * STRIDE + off, last)];
            float2 fB = feat2[(size_t)dB.w * PAIRS + p];
            bool v = act && (e0 + i * STRIDE + off) < e1;
            if (v) {
                float wA = __uint_as_float(dA.x), wB = __uint_as_float(dA.y);
                int cellA = (int)(dA.z & 255u), cellB = (int)((dA.z >> 8) & 255u);
                float2 fv = fA;
                if (dorelu) { fv.x = fmaxf(fv.x, 0.f); fv.y = fmaxf(fv.y, 0.f); }
                float2 gA = Gr[cellA * PAIRS + p];
                float2 gB = Gr[cellB * PAIRS + p];
                gA.x += wA * fv.x; gA.y += wA * fv.y;
                gB.x += wB * fv.x; gB.y += wB * fv.y;
                Gr[cellA * PAIRS + p] = gA;
                Gr[cellB * PAIRS + p] = gB;
            }
            dA = dB; dB = dC; fA = fB;
        }
    }
    __syncthreads();
    unsigned int* Go = (unsigned int*)(G + (size_t)lq * (size_t)(65 * CIN));
    for (int i = t; i < 64 * PAIRS; i += THREADS) {
        float2 a = Gs[i];
#pragma unroll
        for (int r = 1; r < REP; r++) {
            float2 b = Gs[r * 64 * PAIRS + i];
            a.x += b.x; a.y += b.y;
        }
        Go[i] = (unsigned int)f2bf(a.x) | ((unsigned int)f2bf(a.y) << 16);
    }
    if (wave == 0 && lane < PAIRS) {
        float2 fq = feat2[(size_t)q * PAIRS + lane];
        if (dorelu) { fq.x = fmaxf(fq.x, 0.f); fq.y = fmaxf(fq.y, 0.f); }
        Go[64 * PAIRS + lane] = (unsigned int)f2bf(fq.x) | ((unsigned int)f2bf(fq.y) << 16);
    }
}

// bf16 MFMA GEMM, split-K atomics. A: [M][K] bf16 row-major; Wt: [64][K] bf16 (n-major).
__global__ __launch_bounds__(256) void gemm_mfma(
    const unsigned short* __restrict__ A, const unsigned short* __restrict__ Wt,
    float* __restrict__ C, int M, int K, int ldc, int kpb) {
    int wave = threadIdx.x >> 6, lane = threadIdx.x & 63;
    int m0 = blockIdx.x * 64;
    int kbeg = blockIdx.y * kpb;
    int kend = min(K, kbeg + kpb);
    int mrow = lane & 15, kq = lane >> 4;
    int n0 = wave * 16;
    const unsigned short* Bp = Wt + (size_t)(n0 + mrow) * K;
    float4v acc[4] = {{0.f, 0.f, 0.f, 0.f}, {0.f, 0.f, 0.f, 0.f},
                      {0.f, 0.f, 0.f, 0.f}, {0.f, 0.f, 0.f, 0.f}};
    int r0 = min(m0 + mrow, M - 1);
    int r1 = min(m0 + 16 + mrow, M - 1);
    int r2 = min(m0 + 32 + mrow, M - 1);
    int r3 = min(m0 + 48 + mrow, M - 1);
    const unsigned short* A0 = A + (size_t)r0 * K;
    const unsigned short* A1 = A + (size_t)r1 * K;
    const unsigned short* A2 = A + (size_t)r2 * K;
    const unsigned short* A3 = A + (size_t)r3 * K;
    for (int k0 = kbeg; k0 < kend; k0 += 32) {
        int kk = k0 + kq * 8;
        short8 b = *(const short8*)(Bp + kk);
        short8 a0 = *(const short8*)(A0 + kk);
        short8 a1 = *(const short8*)(A1 + kk);
        short8 a2 = *(const short8*)(A2 + kk);
        short8 a3 = *(const short8*)(A3 + kk);
        acc[0] = __builtin_amdgcn_mfma_f32_16x16x32_bf16(a0, b, acc[0], 0, 0, 0);
        acc[1] = __builtin_amdgcn_mfma_f32_16x16x32_bf16(a1, b, acc[1], 0, 0, 0);
        acc[2] = __builtin_amdgcn_mfma_f32_16x16x32_bf16(a2, b, acc[2], 0, 0, 0);
        acc[3] = __builtin_amdgcn_mfma_f32_16x16x32_bf16(a3, b, acc[3], 0, 0, 0);
    }
    int col = lane & 15, rq = lane >> 4;
#pragma unroll
    for (int mt = 0; mt < 4; mt++) {
#pragma unroll
        for (int r = 0; r < 4; r++) {
            int m = m0 + mt * 16 + rq * 4 + r;
            if (m < M) atomicAdd(&C[(size_t)m * ldc + n0 + col], acc[mt][r]);
        }
    }
}

// bf16 MFMA GEMM, direct store, N-tiled via blockIdx.y (64 outputs per tile), full K.
__global__ __launch_bounds__(256) void gemm_mfma_store(
    const unsigned short* __restrict__ A, const unsigned short* __restrict__ Wt,
    float* __restrict__ C, int M, int K, int ldc) {
    int wave = threadIdx.x >> 6, lane = threadIdx.x & 63;
    int m0 = blockIdx.x * 64;
    int n0 = blockIdx.y * 64 + wave * 16;
    int mrow = lane & 15, kq = lane >> 4;
    const unsigned short* Bp = Wt + (size_t)(n0 + mrow) * K;
    float4v acc[4] = {{0.f, 0.f, 0.f, 0.f}, {0.f, 0.f, 0.f, 0.f},
                      {0.f, 0.f, 0.f, 0.f}, {0.f, 0.f, 0.f, 0.f}};
    int r0 = min(m0 + mrow, M - 1);
    int r1 = min(m0 + 16 + mrow, M - 1);
    int r2 = min(m0 + 32 + mrow, M - 1);
    int r3 = min(m0 + 48 + mrow, M - 1);
    const unsigned short* A0 = A + (size_t)r0 * K;
    const unsigned short* A1 = A + (size_t)r1 * K;
    const unsigned short* A2 = A + (size_t)r2 * K;
    const unsigned short* A3 = A + (size_t)r3 * K;
    for (int k0 = 0; k0 < K; k0 += 32) {
        int kk = k0 + kq * 8;
        short8 b = *(const short8*)(Bp + kk);
        short8 a0 = *(const short8*)(A0 + kk);
        short8 a1 = *(const short8*)(A1 + kk);
        short8 a2 = *(const short8*)(A2 + kk);
        short8 a3 = *(const short8*)(A3 + kk);
        acc[0] = __builtin_amdgcn_mfma_f32_16x16x32_bf16(a0, b, acc[0], 0, 0, 0);
        acc[1] = __builtin_amdgcn_mfma_f32_16x16x32_bf16(a1, b, acc[1], 0, 0, 0);
        acc[2] = __builtin_amdgcn_mfma_f32_16x16x32_bf16(a2, b, acc[2], 0, 0, 0);
        acc[3] = __builtin_amdgcn_mfma_f32_16x16x32_bf16(a3, b, acc[3], 0, 0, 0);
    }
    int col = lane & 15, rq = lane >> 4;
#pragma unroll
    for (int mt = 0; mt < 4; mt++) {
#pragma unroll
        for (int r = 0; r < 4; r++) {
            int m = m0 + mt * 16 + rq * 4 + r;
            if (m < M) C[(size_t)m * ldc + n0 + col] = acc[mt][r];
        }
    }
}

// Layer 3: y3[q] = sum_edges sum_corners w * P[s][cell*3+o] + relu(x64b[q])@w_d3 + b_d3.
// One wave per query, lane-per-edge; P: [n][192] f32.
__global__ __launch_bounds__(256) void conv3_reduce(
    const float* __restrict__ P,
    const float* __restrict__ wgt, const uint2* __restrict__ cells,
    const int* __restrict__ s_idx, const int* __restrict__ row_ptr,
    const unsigned short* __restrict__ hq, const float* __restrict__ wd3,
    const float* __restrict__ b3, int n, float* __restrict__ y3) {
    int wave = threadIdx.x >> 6, lane = threadIdx.x & 63;
    int q = blockIdx.x * 4 + wave;
    if (q >= n) return;
    float a0 = 0.f, a1 = 0.f, a2 = 0.f;
    int e0 = row_ptr[q], e1 = row_ptr[q + 1];
    for (int e = e0 + lane; e < e1; e += 64) {
        int s = s_idx[e];
        uint2 cp = cells[e];
        const float4* wp = (const float4*)(wgt + (size_t)e * 8);
        float4 wa = wp[0], wb = wp[1];
        const float* Ps = P + (size_t)s * 192;
        float wv[8] = {wa.x, wa.y, wa.z, wa.w, wb.x, wb.y, wb.z, wb.w};
#pragma unroll
        for (int c = 0; c < 8; c++) {
            unsigned word = (c < 4) ? cp.x : cp.y;
            int cell = (int)((word >> ((c & 3) * 8)) & 255u);
            const float* pc = Ps + cell * 3;
            a0 += wv[c] * pc[0];
            a1 += wv[c] * pc[1];
            a2 += wv[c] * pc[2];
        }
    }
    float hv = bf2f(hq[(size_t)q * 64 + lane]);
    a0 += hv * wd3[lane * 3 + 0];
    a1 += hv * wd3[lane * 3 + 1];
    a2 += hv * wd3[lane * 3 + 2];
#pragma unroll
    for (int off = 32; off > 0; off >>= 1) {
        a0 += __shfl_xor(a0, off);
        a1 += __shfl_xor(a1, off);
        a2 += __shfl_xor(a2, off);
    }
    if (lane == 0) {
        y3[(size_t)q * 3 + 0] = a0 + b3[0];
        y3[(size_t)q * 3 + 1] = a1 + b3[1];
        y3[(size_t)q * 3 + 2] = a2 + b3[2];
    }
}

// f32 split-K GEMM (layer 0 only, tiny K).
template <int BM, int BN, int BK, int TM, int TN>
__global__ void gemm_atomic(const float* __restrict__ A, const float* __restrict__ B,
                            float* __restrict__ C, int M, int N, int K,
                            int ldc, int coff, int kpb) {
    constexpr int THREADS = (BM / TM) * (BN / TN);
    __shared__ float As[BK][BM + 1];
    __shared__ float Bs[BK][BN + 1];
    int tx = threadIdx.x;
    int tcols = BN / TN;
    int tcol = tx % tcols, trow = tx / tcols;
    int m0 = blockIdx.x * BM;
    int kbeg = blockIdx.y * kpb;
    int kend = min(K, kbeg + kpb);
    float acc[TM][TN];
#pragma unroll
    for (int i = 0; i < TM; i++)
#pragma unroll
        for (int j = 0; j < TN; j++) acc[i][j] = 0.f;
    for (int k0 = kbeg; k0 < kend; k0 += BK) {
        for (int i = tx; i < BM * BK; i += THREADS) {
            int kk = i % BK, mm = i / BK;
            int m = m0 + mm, k = k0 + kk;
            As[kk][mm] = (m < M && k < K) ? A[(size_t)m * K + k] : 0.f;
        }
        for (int i = tx; i < BN * BK; i += THREADS) {
            int nn = i % BN, kk = i / BN;
            int k = k0 + kk;
            Bs[kk][nn] = (k < K && nn < N) ? B[(size_t)k * N + nn] : 0.f;
        }
        __syncthreads();
#pragma unroll
        for (int kk = 0; kk < BK; kk++) {
            float a[TM], b[TN];
#pragma unroll
            for (int i = 0; i < TM; i++) a[i] = As[kk][trow * TM + i];
#pragma unroll
            for (int j = 0; j < TN; j++) b[j] = Bs[kk][tcol * TN + j];
#pragma unroll
            for (int i = 0; i < TM; i++)
#pragma unroll
                for (int j = 0; j < TN; j++) acc[i][j] += a[i] * b[j];
        }
        __syncthreads();
    }
    for (int i = 0; i < TM; i++) {
        int m = m0 + trow * TM + i;
        if (m >= M) continue;
        for (int j = 0; j < TN; j++) {
            int nn = tcol * TN + j;
            if (nn >= N) continue;
            atomicAdd(&C[(size_t)m * ldc + coff + nn], acc[i][j]);
        }
    }
}

__global__ void final_kernel(const float* __restrict__ pos, const float* __restrict__ pos2,
                             const float* __restrict__ y3, int n, float* __restrict__ out) {
    int i = blockIdx.x * blockDim.x + threadIdx.x;
    if (i >= n * 3) return;
    float pn = pos2[i] + y3[i] * (1.f / 128.f);
    out[i] = pn;
    out[n * 3 + i] = (pn - pos[i]) * (1.f / DT_F);
}

extern "C" void kernel_launch(void* const* d_in, const int* in_sizes, int n_in,
                              void* d_out, int out_size, void* d_ws, size_t ws_size,
                              hipStream_t stream) {
    const float* pos       = (const float*)d_in[0];
    const float* vel       = (const float*)d_in[1];
    const float* box       = (const float*)d_in[2];
    const float* box_feats = (const float*)d_in[3];
    const int*   ff_q      = (const int*)d_in[4];
    const int*   ff_s      = (const int*)d_in[5];
    const int*   fo_q      = (const int*)d_in[6];
    const int*   fo_s      = (const int*)d_in[7];
    const float* w_cf0     = (const float*)d_in[8];
    const float* w_co0     = (const float*)d_in[9];
    const float* w_d0      = (const float*)d_in[10];
    const float* b_d0      = (const float*)d_in[11];
    const float* w_c1      = (const float*)d_in[12];
    const float* w_d1      = (const float*)d_in[13];
    const float* b_d1      = (const float*)d_in[14];
    const float* w_c2      = (const float*)d_in[15];
    const float* w_d2      = (const float*)d_in[16];
    const float* b_d2      = (const float*)d_in[17];
    const float* w_c3      = (const float*)d_in[18];
    const float* w_d3      = (const float*)d_in[19];
    const float* b_d3      = (const float*)d_in[20];
    float* out = (float*)d_out;

    int n   = in_sizes[0] / 3;
    int Eff = in_sizes[4];
    int Efo = in_sizes[6];

    float* base = (float*)d_ws;
    size_t off = 0;
    auto alloc = [&](size_t nf) { float* p = base + off; off += (nf + 3) & ~(size_t)3; return p; };
    float* pos2  = alloc((size_t)n * 3);
    float* fl    = alloc((size_t)n * 4);
    float* x96   = alloc((size_t)n * 96);
    float* x64a  = alloc((size_t)n * 64);
    float* x64b  = alloc((size_t)n * 64);
    float* y3    = alloc((size_t)n * 3);
    int* rp_ff   = (int*)alloc((size_t)n + 1);
    int* rp_fo   = (int*)alloc((size_t)n + 1);
    unsigned short* Wt  = (unsigned short*)alloc((size_t)65 * 96 * 64 / 2);
    unsigned short* Wt3 = (unsigned short*)alloc((size_t)192 * 64 / 2);
    unsigned short* xbr = (unsigned short*)alloc((size_t)n * 64 / 2);
    float* P     = alloc((size_t)n * 192);
    float* wgt_ff = alloc((size_t)Eff * 8);
    uint2* cl_ff  = (uint2*)alloc((size_t)Eff * 2);
    float* wgt_fo = alloc((size_t)Efo * 8);
    uint2* cl_fo  = (uint2*)alloc((size_t)Efo * 2);
    uint4* ed_ff  = (uint4*)alloc((size_t)Eff * 16);
    uint4* ed_fo  = (uint4*)alloc((size_t)Efo * 16);
    float* G = base + off;                                  // f32 view (layer 0)
    unsigned short* Gb = (unsigned short*)G;                // bf16 view (layers 1-2)

    size_t totalF = ws_size / sizeof(float);
    size_t availF = (totalF > off) ? (totalF - off) : 0;
    auto chunkQ = [&](size_t floatsPerQ) {
        long q = (long)(availF / floatsPerQ);
        if (q < 1) q = 1;
        if (q > n) q = n;
        return (int)q;
    };

    // --- prep, CSR, edge geometry (once) ---
    prep_kernel<<<cdiv(n, 256), 256, 0, stream>>>(pos, vel, n, pos2, fl);
    row_ptr_kernel<<<cdiv(n + 1, 256), 256, 0, stream>>>(ff_q, Eff, n, rp_ff);
    row_ptr_kernel<<<cdiv(n + 1, 256), 256, 0, stream>>>(fo_q, Efo, n, rp_fo);
    edge_geom_kernel<<<cdiv(Eff, 256), 256, 0, stream>>>(pos2, pos2, ff_q, ff_s, Eff, wgt_ff, cl_ff, ed_ff);
    edge_geom_kernel<<<cdiv(Efo, 256), 256, 0, stream>>>(pos2, box, fo_q, fo_s, Efo, wgt_fo, cl_fo, ed_fo);

    // --- layer 0 (f32 path, tiny K) ---
    init_out_kernel<<<cdiv(n * 64, 256), 256, 0, stream>>>(x96, nullptr, nullptr, n, 64, 96);
    dense0_kernel<<<cdiv(n * 32, 256), 256, 0, stream>>>(fl, w_d0, b_d0, n, x96);
    {
        int Q = chunkQ(64 * 4);
        for (int q0 = 0; q0 < n; q0 += Q) {
            int mc = std::min(Q, n - q0);
            build_G0_par<4><<<mc, 256, 0, stream>>>(fl, ed_ff, Eff, rp_ff, q0, G);
            gemm_atomic<64, 32, 16, 4, 2><<<dim3(cdiv(mc, 64), 2), 256, 0, stream>>>(
                G, w_cf0, x96 + (size_t)q0 * 96, mc, 32, 256, 96, 32, 8 * 16);
        }
    }
    {
        int Q = chunkQ(64 * 3);
        for (int q0 = 0; q0 < n; q0 += Q) {
            int mc = std::min(Q, n - q0);
            build_G0_par<3><<<mc, 256, 0, stream>>>(box_feats, ed_fo, Efo, rp_fo, q0, G);
            gemm_atomic<64, 32, 16, 4, 2><<<dim3(cdiv(mc, 64), 2), 256, 0, stream>>>(
                G, w_co0, x96 + (size_t)q0 * 96, mc, 32, 192, 96, 0, 6 * 16);
        }
    }

    // --- layer 1: 96 -> 64, bf16 MFMA (relu fused into build), 8-wave build ---
    {
        const int K = 65 * 96;
        wt_kernel<<<cdiv(64 * K, 256), 256, 0, stream>>>(w_c1, w_d1, 96, 64, K, Wt);
        init_out_kernel<<<cdiv(n * 64, 256), 256, 0, stream>>>(x64a, b_d1, nullptr, n, 64, 64);
        int Q = chunkQ((size_t)K / 2);
        for (int q0 = 0; q0 < n; q0 += Q) {
            int mc = std::min(Q, n - q0);
            build_G_bigT<48, 2, 0><<<mc, 512, 0, stream>>>(
                x96, ed_ff, Eff, rp_ff, x96, q0, 1, Gb);
            gemm_mfma<<<dim3(cdiv(mc, 64), 4), 256, 0, stream>>>(
                Gb, Wt, x64a + (size_t)q0 * 64, mc, K, 64, cdiv(K / 32, 4) * 32);
        }
    }

    // --- layer 2: 64 -> 64, residual, bf16 MFMA, 8-wave dual build (4-way edges) ---
    {
        const int K = 65 * 64;
        wt_kernel<<<cdiv(64 * K, 256), 256, 0, stream>>>(w_c2, w_d2, 64, 64, K, Wt);
        init_out_kernel<<<cdiv(n * 64, 256), 256, 0, stream>>>(x64b, b_d2, x64a, n, 64, 64);
        int Q = chunkQ((size_t)K / 2);
        for (int q0 = 0; q0 < n; q0 += Q) {
            int mc = std::min(Q, n - q0);
            build_G_bigT<32, 2, 1><<<mc, 512, 0, stream>>>(
                x64a, ed_ff, Eff, rp_ff, x64a, q0, 1, Gb);
            gemm_mfma<<<dim3(cdiv(mc, 64), 4), 256, 0, stream>>>(
                Gb, Wt, x64b + (size_t)q0 * 64, mc, K, 64, cdiv(K / 32, 4) * 32);
        }
    }

    // --- layer 3: 64 -> 3 via P-trick (no G build) ---
    {
        relu_bf16_kernel<<<cdiv(n * 64, 256), 256, 0, stream>>>(x64b, n * 64, xbr);
        wt3_kernel<<<cdiv(192 * 64, 256), 256, 0, stream>>>(w_c3, Wt3);
        gemm_mfma_store<<<dim3(cdiv(n, 64), 3), 256, 0, stream>>>(xbr, Wt3, P, n, 64, 192);
        conv3_reduce<<<cdiv(n, 4), 256, 0, stream>>>(
            P, wgt_ff, cl_ff, ff_s, rp_ff, xbr, w_d3, b_d3, n, y3);
    }

    final_kernel<<<cdiv(n * 3, 256), 256, 0, stream>>>(pos, pos2, y3, n, out);
}